// Round 3
// baseline (2996.630 us; speedup 1.0000x reference)
//
#include <hip/hip_runtime.h>

#define DI __device__ __forceinline__

typedef __attribute__((ext_vector_type(8))) short v8s;
typedef __attribute__((ext_vector_type(4))) short v4s;
typedef __attribute__((ext_vector_type(4))) float v4f;

constexpr int BB = 16, NN = 4096, CH = 64, SS = 1024, KK = 32, DD = 128;
constexpr int LDW = 136;                 // LDS row stride in shorts (pad: 16B-aligned rows, <=2-way banks)
constexpr int GPC = 2;                   // groups per chunk in gemm passes
constexpr int NCHUNK = (BB * SS) / GPC;  // 8192
constexpr int GGRID = 512;

// ---- ws layout (bytes) ----
constexpr size_t OFF_FPSIDX = 0;         // int[16384]
constexpr size_t OFF_KNN    = 65536;     // int[524288]
constexpr size_t OFF_MEAN   = 2162688;   // float[1048576]
constexpr size_t OFF_VARB   = 6356992;   // float[1024]
constexpr size_t OFF_BINS1  = 6361088;   // float[16384]  [64][128][2]
constexpr size_t OFF_BINS2  = 6426624;   // float[16384]
constexpr size_t OFF_RSTD   = 6492160;   // float[16]
constexpr size_t OFF_COEF1  = 6492224;   // float[256]
constexpr size_t OFF_COEF2  = 6493248;   // float[256]
constexpr size_t OFF_W1BF   = 6494272;   // short[16384]
constexpr size_t OFF_W2BF   = 6527040;   // short[16384]
constexpr size_t OFF_XYZT   = 6559808;   // float[196608]  [B][3][N]
constexpr size_t MEMSET_OFF = OFF_VARB;
constexpr size_t MEMSET_LEN = 4096 + 65536 + 65536;

DI short f2bf(float f) {
  unsigned u = __float_as_uint(f);
  u = (u + 0x7fffu + ((u >> 16) & 1u)) >> 16;
  return (short)u;
}
DI float bf2f(short s) { return __uint_as_float(((unsigned)(unsigned short)s) << 16); }

// ---------------- xyz transpose: [B][N][3] -> [B][3][N] ----------------
__global__ void xpose_kernel(const float* __restrict__ xyz, float* __restrict__ xyzT) {
  int i = blockIdx.x * 256 + threadIdx.x;  // < B*N
  int b = i >> 12, n = i & 4095;
  const float* s = xyz + (size_t)i * 3;
  float* d = xyzT + (size_t)b * 3 * NN + n;
  d[0] = s[0]; d[NN] = s[1]; d[2 * NN] = s[2];
}

// ---------------- weight f32 -> bf16 ----------------
__global__ void cvtw_kernel(const float* __restrict__ w1, const float* __restrict__ w2,
                            short* __restrict__ w1b, short* __restrict__ w2b) {
  int i = blockIdx.x * 256 + threadIdx.x;  // < 16384
  w1b[i] = f2bf(w1[i]);
  w2b[i] = f2bf(w2[i]);
}

// DPP-based (value,index) max step: partner = lane ^ {1,2,7,15} within a row of 16.
// Masks {1,2,7,15} generate the full 16-lane group, so 4 stages give row max.
template <int CTRL>
DI void dpp_max_stage(float& v, int& i) {
  float ov = __int_as_float(__builtin_amdgcn_update_dpp(0, __float_as_int(v), CTRL, 0xf, 0xf, true));
  int oi = __builtin_amdgcn_update_dpp(0, i, CTRL, 0xf, 0xf, true);
  if (ov > v) { v = ov; i = oi; }
}

constexpr float FPS_SLACK = 2e-4f;  // abs slack on f32 gate; f32 dot-form err <= ~3e-5 for this data

// ---------------- FPS v3: DPP argmax, LDS-minimal round loop ----------------
// 16 blocks x 256 threads (4 waves), 16 points/lane (pt k -> global k*256+tid).
// Exact f64 min-dist chain lives in LDS (s_m64), updated only when the f32 gate
// fires (slack covers all f32 error). Argmax: f32 per-lane top1 -> 4 DPP stages
// -> readlane cross-row -> 1 LDS partial exchange across 4 waves. Winner is
// f64-exact iff unique at f32 (ballot tie detection); else exact f64 fallback.
// No global stores inside the round loop (barrier drains lgkm only).
__global__ __launch_bounds__(256) void fps_kernel(const float* __restrict__ xyzT,
                                                  int* __restrict__ fps_idx,
                                                  float* __restrict__ out_xyz) {
  int b = blockIdx.x, tid = threadIdx.x;
  int wave = tid >> 6, lane = tid & 63;
  const float* bx = xyzT + (size_t)b * 3 * NN;
  const float* by = bx + NN;
  const float* bz = bx + 2 * NN;
  __shared__ float4 s_xyzw[NN];   // 64 KB: coords broadcast
  __shared__ double s_m64[NN];    // 32 KB: exact min-dist chain
  __shared__ int s_fidx[SS];      // 4 KB: selected indices
  __shared__ float4 s_part[2][4]; // per-wave partials (val, idx-bits, tie, pad), dbuf by round parity
  __shared__ double s_ed[4];
  __shared__ int s_ei[4];

  float px[16], py[16], pz[16], pp[16], mind32[16], base[16];
#pragma unroll
  for (int k = 0; k < 16; ++k) {
    int gi = k * 256 + tid;
    float x = bx[gi], y = by[gi], z = bz[gi];
    px[k] = x; py[k] = y; pz[k] = z;
    pp[k] = fmaf(x, x, fmaf(y, y, z * z));
    s_xyzw[gi] = make_float4(x, y, z, 0.f);
    s_m64[gi] = 1e10;
    mind32[k] = 1e10f;
    base[k] = pp[k] - 1e10f - FPS_SLACK;
  }
  if (tid == 0) s_fidx[0] = 0;
  __syncthreads();
  float4 c4 = s_xyzw[0];
  float cx = c4.x, cy = c4.y, cz = c4.z;
  float v1 = 1e10f; int i1 = tid; int cnt1 = 16;

  for (int j = 1; j < SS; ++j) {
    // ---- phase A: f32 gate, dot-form: d - mind - slack = dot + (cc + base) ----
    float cx2 = -2.f * cx, cy2 = -2.f * cy, cz2 = -2.f * cz;
    float cc = fmaf(cx, cx, fmaf(cy, cy, cz * cz));
    int mask = 0;
#pragma unroll
    for (int k = 0; k < 16; ++k) {
      float s = fmaf(px[k], cx2, fmaf(py[k], cy2, fmaf(pz[k], cz2, cc + base[k])));
      mask |= (s < 0.f) ? (1 << k) : 0;
    }
    // ---- gated exact f64 updates ----
    bool rescan = false;
    if (mask) {
      double c64x = (double)cx, c64y = (double)cy, c64z = (double)cz;
#pragma unroll
      for (int k = 0; k < 16; ++k)
        if (mask & (1 << k)) {
          int gi = k * 256 + tid;
          double dx = (double)px[k] - c64x;
          double dy = (double)py[k] - c64y;
          double dz = (double)pz[k] - c64z;
          double d64 = fma(dx, dx, fma(dy, dy, dz * dz));
          double m = s_m64[gi];
          if (d64 < m) {
            s_m64[gi] = d64;
            float old = mind32[k];
            float nm = (float)d64;
            mind32[k] = nm;
            base[k] = pp[k] - nm - FPS_SLACK;
            if (old == v1) rescan = true;  // lane's top point changed -> rescan
          }
        }
    }
    if (rescan) {
      v1 = -1.f; i1 = 0; cnt1 = 0;
#pragma unroll
      for (int k = 0; k < 16; ++k) {
        float v = mind32[k];
        if (v > v1) { v1 = v; i1 = k * 256 + tid; cnt1 = 1; }
        else if (v == v1) ++cnt1;
      }
    }
    // ---- wave argmax: 4 DPP stages (row of 16) + readlane cross-row ----
    float wv = v1; int wi = i1;
    dpp_max_stage<0xB1>(wv, wi);   // quad_perm [1,0,3,2]  : xor 1
    dpp_max_stage<0x4E>(wv, wi);   // quad_perm [2,3,0,1]  : xor 2
    dpp_max_stage<0x141>(wv, wi);  // ROW_HALF_MIRROR      : xor 7
    dpp_max_stage<0x140>(wv, wi);  // ROW_MIRROR           : xor 15
    int vb = __float_as_int(wv);
    float r0 = __int_as_float(__builtin_amdgcn_readlane(vb, 0));
    float r1 = __int_as_float(__builtin_amdgcn_readlane(vb, 16));
    float r2 = __int_as_float(__builtin_amdgcn_readlane(vb, 32));
    float r3 = __int_as_float(__builtin_amdgcn_readlane(vb, 48));
    int q0 = __builtin_amdgcn_readlane(wi, 0);
    int q1 = __builtin_amdgcn_readlane(wi, 16);
    int q2 = __builtin_amdgcn_readlane(wi, 32);
    int q3 = __builtin_amdgcn_readlane(wi, 48);
    float fvw = r0; int fiw = q0;
    if (r1 > fvw) { fvw = r1; fiw = q1; }
    if (r2 > fvw) { fvw = r2; fiw = q2; }
    if (r3 > fvw) { fvw = r3; fiw = q3; }
    // tie detection (wave level): >1 lane at max, or the holder lane has a dup
    unsigned long long b1 = __ballot(v1 == fvw);
    unsigned long long b2 = __ballot(v1 == fvw && cnt1 > 1);
    float tw = (__popcll(b1) > 1 || b2 != 0ull) ? 1.f : 0.f;
    if (lane == 0) s_part[j & 1][wave] = make_float4(fvw, __int_as_float(fiw), tw, 0.f);
    __syncthreads();
    // ---- cross-wave: scan 4 partials (uniform) ----
    float fv = -1.f, tie = 0.f; int fi = 0;
#pragma unroll
    for (int w = 0; w < 4; ++w) {
      float4 p = s_part[j & 1][w];
      if (p.x > fv) { fv = p.x; fi = __float_as_int(p.y); tie = p.z; }
      else if (p.x == fv) tie = 1.f;
    }
    if (tie != 0.f) {
      // exact f64 argmax fallback (block-uniform, ~never taken)
      double bv = -1.0; int bi = 1 << 30;
#pragma unroll
      for (int k = 0; k < 16; ++k) {
        int gi = k * 256 + tid;
        double m = s_m64[gi];
        if (m > bv || (m == bv && gi < bi)) { bv = m; bi = gi; }
      }
#pragma unroll
      for (int m2 = 1; m2 < 64; m2 <<= 1) {
        double ov = __shfl_xor(bv, m2, 64);
        int oi = __shfl_xor(bi, m2, 64);
        if (ov > bv || (ov == bv && oi < bi)) { bv = ov; bi = oi; }
      }
      if (lane == 0) { s_ed[wave] = bv; s_ei[wave] = bi; }
      __syncthreads();
      double fbv = s_ed[0]; int fbi = s_ei[0];
#pragma unroll
      for (int w = 1; w < 4; ++w) {
        double v = s_ed[w]; int ii = s_ei[w];
        if (v > fbv || (v == fbv && ii < fbi)) { fbv = v; fbi = ii; }
      }
      fi = fbi;
    }
    float4 cw = s_xyzw[fi];  // uniform-address LDS broadcast
    cx = cw.x; cy = cw.y; cz = cw.z;
    if (tid == 0) s_fidx[j] = fi;
  }
  __syncthreads();
  // ---- write out fps_idx + new_xyz (once, after the serial loop) ----
  for (int t = tid; t < SS; t += 256) {
    int idx = s_fidx[t];
    fps_idx[b * SS + t] = idx;
    float4 p = s_xyzw[idx];
    out_xyz[((size_t)b * SS + t) * 3 + 0] = p.x;
    out_xyz[((size_t)b * SS + t) * 3 + 1] = p.y;
    out_xyz[((size_t)b * SS + t) * 3 + 2] = p.z;
  }
}

// ---------------- kNN: one wave per query ----------------
// f32 bulk distances -> threshold (32nd smallest of per-lane minima, inflated) ->
// compact candidates to LDS with exact f64 distances -> 32 rounds exact argmin.
__global__ __launch_bounds__(256) void knn_kernel(const float* __restrict__ xyzT,
                                                  const int* __restrict__ fps_idx,
                                                  int* __restrict__ knn_idx) {
  int wave = threadIdx.x >> 6, lane = threadIdx.x & 63;
  int q = blockIdx.x * 4 + wave, b = q >> 10;
  const float* bx = xyzT + (size_t)b * 3 * NN;
  const float* by = bx + NN;
  const float* bz = bx + 2 * NN;
  int qi = fps_idx[q];
  float qx = bx[qi], qy = by[qi], qz = bz[qi];
  float d[64];
  float lmin = 1e30f;
#pragma unroll
  for (int j = 0; j < 64; ++j) {
    int n = j * 64 + lane;
    float dx = bx[n] - qx, dy = by[n] - qy, dz = bz[n] - qz;
    d[j] = fmaf(dx, dx, fmaf(dy, dy, dz * dz));
    lmin = fminf(lmin, d[j]);
  }
  // bitonic sort of per-lane minima across the wave (ascending)
  float v = lmin;
#pragma unroll
  for (int size = 2; size <= 64; size <<= 1) {
#pragma unroll
    for (int stride = size >> 1; stride > 0; stride >>= 1) {
      float o = __shfl_xor(v, stride, 64);
      bool keepmin = (((lane & size) == 0) == ((lane & stride) == 0));
      v = keepmin ? fminf(v, o) : fmaxf(v, o);
    }
  }
  float tau = __shfl(v, 31, 64) * 1.00001f + 1e-20f;  // >= true 32nd smallest, with margin

  __shared__ double cd[4][512];
  __shared__ int ci[4][512];
  int cnt = 0;
#pragma unroll
  for (int j = 0; j < 64; ++j) {
    bool pred = (d[j] <= tau);
    unsigned long long mask = __ballot(pred);
    if (pred) {
      int pos = cnt + __popcll(mask & ((1ull << lane) - 1ull));
      if (pos < 512) {
        int n = j * 64 + lane;
        double dx = (double)bx[n] - (double)qx;
        double dy = (double)by[n] - (double)qy;
        double dz = (double)bz[n] - (double)qz;
        cd[wave][pos] = fma(dx, dx, fma(dy, dy, dz * dz));
        ci[wave][pos] = n;
      }
    }
    cnt += __popcll(mask);
  }
  if (cnt > 512) cnt = 512;
  // 32 exact selection rounds (candidates are stored in ascending-n order; ties -> smaller pos = smaller n)
  for (int r = 0; r < 32; ++r) {
    double bv = 1e300; int bp = 1 << 30;
    for (int p = lane; p < cnt; p += 64) {
      double vv = cd[wave][p];
      if (vv < bv) { bv = vv; bp = p; }
    }
#pragma unroll
    for (int m = 1; m < 64; m <<= 1) {
      double ov = __shfl_xor(bv, m, 64);
      int op = __shfl_xor(bp, m, 64);
      if (ov < bv || (ov == bv && op < bp)) { bv = ov; bp = op; }
    }
    if (bp < (1 << 30) && (bp & 63) == lane) {
      knn_idx[(size_t)q * KK + r] = ci[wave][bp];
      cd[wave][bp] = 1e300;
    }
  }
}

// ---------------- per-group mean over K + per-batch sum of diff^2 ----------------
__global__ __launch_bounds__(256) void meanvar_kernel(const float* __restrict__ points,
                                                      const int* __restrict__ kidx,
                                                      float* __restrict__ mean_out,
                                                      float* __restrict__ var_bins) {
  int wave = threadIdx.x >> 6, lane = threadIdx.x & 63;
  int g = blockIdx.x * 4 + wave;  // global group
  int b = g >> 10;
  const float* pb = points + (size_t)b * NN * CH;
  const int* idx = kidx + (size_t)g * KK;
  float s1 = 0.f, s2 = 0.f;
#pragma unroll
  for (int k = 0; k < KK; ++k) {
    float x = pb[(size_t)idx[k] * CH + lane];
    s1 += x;
    s2 = fmaf(x, x, s2);
  }
  float m = s1 * (1.0f / 32.0f);
  mean_out[(size_t)g * CH + lane] = m;
  float part = s2 - s1 * m;  // sum_k (x-m)^2 (exact algebra: 32*m == s1)
#pragma unroll
  for (int mm = 1; mm < 64; mm <<= 1) part += __shfl_xor(part, mm, 64);
  if (lane == 0) atomicAdd(&var_bins[b * 64 + (g & 63)], part);
}

__global__ void fin_std_kernel(const float* __restrict__ bins, float* __restrict__ rstd) {
  int t = threadIdx.x;
  if (t < BB) {
    float s = 0.f;
    for (int i = 0; i < 64; ++i) s += bins[t * 64 + i];
    float var = s / (float)(SS * KK * CH - 1);
    rstd[t] = 1.0f / (sqrtf(var) + 1e-5f);
  }
}

__global__ void fin_bn_kernel(const float* __restrict__ bins, const float* __restrict__ g,
                              const float* __restrict__ be, float* __restrict__ coef) {
  int o = threadIdx.x;  // < 128
  float s = 0.f, qq = 0.f;
  for (int bin = 0; bin < 64; ++bin) {
    s += bins[(bin * 128 + o) * 2 + 0];
    qq += bins[(bin * 128 + o) * 2 + 1];
  }
  constexpr float invM = 1.0f / (float)(BB * SS * KK);
  float mean = s * invM;
  float var = qq * invM - mean * mean;
  if (var < 0.f) var = 0.f;
  float sc = g[o] / sqrtf(var + 1e-5f);
  coef[2 * o] = sc;
  coef[2 * o + 1] = be[o] - mean * sc;
}

// ---------------- GEMM passes ----------------
// PASS 0: X->h1, accumulate BN1 stats.
// PASS 1: X->h1->P->h2, accumulate BN2 stats.
// PASS 2: X->h1->P->h2, BN2 + residual + lrelu + maxpool -> out.
template <int PASS>
__global__ __launch_bounds__(256, 2) void gemm_pass(
    const float* __restrict__ points, const int* __restrict__ kidx, const int* __restrict__ fidx,
    const float* __restrict__ mean, const float* __restrict__ rstd,
    const float* __restrict__ alpha, const float* __restrict__ beta,
    const short* __restrict__ w1bf, const short* __restrict__ w2bf,
    const float* __restrict__ coef1, const float* __restrict__ coef2,
    float* __restrict__ bins_out, float* __restrict__ out_pooled) {
  __shared__ short Xs[GPC * 32 * LDW];
  __shared__ short Ps[(PASS >= 1) ? (GPC * 32 * LDW) : 8];
  __shared__ float sAlpha[64], sBeta[64];
  __shared__ float sCoef1[256], sCoef2[256];
  __shared__ float bnS[128], bnQ[128];

  int tid = threadIdx.x;
  int wave = tid >> 6, lane = tid & 63;
  int q4 = lane >> 4, l15 = lane & 15;
  int ohalf = wave & 1, gsel = wave >> 1;

  // W fragments -> registers
  v8s wf1[4][4];
  v8s wf2[4][4];
#pragma unroll
  for (int ot = 0; ot < 4; ++ot) {
    int row = ohalf * 64 + ot * 16 + l15;
#pragma unroll
    for (int cs = 0; cs < 4; ++cs) {
      wf1[ot][cs] = *(const v8s*)(w1bf + row * 128 + cs * 32 + q4 * 8);
      if constexpr (PASS >= 1) wf2[ot][cs] = *(const v8s*)(w2bf + row * 128 + cs * 32 + q4 * 8);
    }
  }
  if (tid < 64) { sAlpha[tid] = alpha[tid]; sBeta[tid] = beta[tid]; }
  if constexpr (PASS >= 1) sCoef1[tid] = coef1[tid];
  if constexpr (PASS == 2) sCoef2[tid] = coef2[tid];
  if constexpr (PASS <= 1) {
    if (tid < 128) { bnS[tid] = 0.f; bnQ[tid] = 0.f; }
  }
  __syncthreads();

  for (int chunk = blockIdx.x; chunk < NCHUNK; chunk += GGRID) {
    int g0 = chunk * GPC;
    // ---- stage Xs: [g][k][0:64]=normalized grouped, [64:128]=new_pts ----
    {
      int sg = tid >> 7;
      int sk = (tid >> 2) & 31;
      int qr = tid & 3;
      int ggl = g0 + sg;
      int b = ggl >> 10;
      const float* pb = points + (size_t)b * NN * CH;
      int row = (qr < 2) ? kidx[(size_t)ggl * KK + sk] : fidx[ggl];
      int ch0 = (qr & 1) * 32;
      const float* src = pb + (size_t)row * CH + ch0;
      const float* mrow = mean + (size_t)ggl * CH + ch0;
      float rs = rstd[b];
      bool norm = (qr < 2);
      v8s pack[4];
#pragma unroll
      for (int cc = 0; cc < 32; cc += 4) {
        float4 vv = *(const float4*)(src + cc);
        if (norm) {
          float4 mv = *(const float4*)(mrow + cc);
          vv.x = fmaf((vv.x - mv.x) * rs, sAlpha[ch0 + cc + 0], sBeta[ch0 + cc + 0]);
          vv.y = fmaf((vv.y - mv.y) * rs, sAlpha[ch0 + cc + 1], sBeta[ch0 + cc + 1]);
          vv.z = fmaf((vv.z - mv.z) * rs, sAlpha[ch0 + cc + 2], sBeta[ch0 + cc + 2]);
          vv.w = fmaf((vv.w - mv.w) * rs, sAlpha[ch0 + cc + 3], sBeta[ch0 + cc + 3]);
        }
        pack[cc >> 3][(cc & 7) + 0] = f2bf(vv.x);
        pack[cc >> 3][(cc & 7) + 1] = f2bf(vv.y);
        pack[cc >> 3][(cc & 7) + 2] = f2bf(vv.z);
        pack[cc >> 3][(cc & 7) + 3] = f2bf(vv.w);
      }
      short* dst = &Xs[(sg * 32 + sk) * LDW + qr * 32];
#pragma unroll
      for (int p2 = 0; p2 < 4; ++p2) *(v8s*)(dst + p2 * 8) = pack[p2];
    }
    __syncthreads();

    // ---- GEMM1: h1 = W1 * X ----
    v4f acc[4][2] = {};
#pragma unroll
    for (int cs = 0; cs < 4; ++cs) {
      v8s bfr[2];
#pragma unroll
      for (int kt = 0; kt < 2; ++kt)
        bfr[kt] = *(const v8s*)&Xs[(gsel * 32 + kt * 16 + l15) * LDW + cs * 32 + q4 * 8];
#pragma unroll
      for (int ot = 0; ot < 4; ++ot)
#pragma unroll
        for (int kt = 0; kt < 2; ++kt)
          acc[ot][kt] = __builtin_amdgcn_mfma_f32_16x16x32_bf16(wf1[ot][cs], bfr[kt], acc[ot][kt], 0, 0, 0);
    }

    if constexpr (PASS == 0) {
      // BN1 stats of h1
#pragma unroll
      for (int ot = 0; ot < 4; ++ot) {
        float sv[4], sq[4];
#pragma unroll
        for (int r = 0; r < 4; ++r) {
          float a0 = acc[ot][0][r], a1 = acc[ot][1][r];
          sv[r] = a0 + a1;
          sq[r] = fmaf(a0, a0, a1 * a1);
        }
#pragma unroll
        for (int m = 1; m < 16; m <<= 1)
#pragma unroll
          for (int r = 0; r < 4; ++r) {
            sv[r] += __shfl_xor(sv[r], m, 64);
            sq[r] += __shfl_xor(sq[r], m, 64);
          }
        if (l15 == 0) {
          int o0 = ohalf * 64 + ot * 16 + q4 * 4;
#pragma unroll
          for (int r = 0; r < 4; ++r) {
            atomicAdd(&bnS[o0 + r], sv[r]);
            atomicAdd(&bnQ[o0 + r], sq[r]);
          }
        }
      }
    } else {
      // ---- P = lrelu(bn1(h1)) -> Ps ----
#pragma unroll
      for (int ot = 0; ot < 4; ++ot) {
        int o0 = ohalf * 64 + ot * 16 + q4 * 4;
#pragma unroll
        for (int kt = 0; kt < 2; ++kt) {
          v4s pk;
#pragma unroll
          for (int r = 0; r < 4; ++r) {
            float h = fmaf(acc[ot][kt][r], sCoef1[2 * (o0 + r)], sCoef1[2 * (o0 + r) + 1]);
            h = (h >= 0.f) ? h : 0.01f * h;
            pk[r] = f2bf(h);
          }
          *(v4s*)&Ps[(gsel * 32 + kt * 16 + l15) * LDW + o0] = pk;
        }
      }
      __syncthreads();

      // ---- GEMM2: h2 = W2 * P ----
      v4f acc2[4][2] = {};
#pragma unroll
      for (int cs = 0; cs < 4; ++cs) {
        v8s pfr[2];
#pragma unroll
        for (int kt = 0; kt < 2; ++kt)
          pfr[kt] = *(const v8s*)&Ps[(gsel * 32 + kt * 16 + l15) * LDW + cs * 32 + q4 * 8];
#pragma unroll
        for (int ot = 0; ot < 4; ++ot)
#pragma unroll
          for (int kt = 0; kt < 2; ++kt)
            acc2[ot][kt] = __builtin_amdgcn_mfma_f32_16x16x32_bf16(wf2[ot][cs], pfr[kt], acc2[ot][kt], 0, 0, 0);
      }

      if constexpr (PASS == 1) {
        // BN2 stats of h2
#pragma unroll
        for (int ot = 0; ot < 4; ++ot) {
          float sv[4], sq[4];
#pragma unroll
          for (int r = 0; r < 4; ++r) {
            float a0 = acc2[ot][0][r], a1 = acc2[ot][1][r];
            sv[r] = a0 + a1;
            sq[r] = fmaf(a0, a0, a1 * a1);
          }
#pragma unroll
          for (int m = 1; m < 16; m <<= 1)
#pragma unroll
            for (int r = 0; r < 4; ++r) {
              sv[r] += __shfl_xor(sv[r], m, 64);
              sq[r] += __shfl_xor(sq[r], m, 64);
            }
          if (l15 == 0) {
            int o0 = ohalf * 64 + ot * 16 + q4 * 4;
#pragma unroll
            for (int r = 0; r < 4; ++r) {
              atomicAdd(&bnS[o0 + r], sv[r]);
              atomicAdd(&bnQ[o0 + r], sq[r]);
            }
          }
        }
      } else {
        // ---- epilogue: lrelu(bn2(h2) + X) , max over k, store ----
#pragma unroll
        for (int ot = 0; ot < 4; ++ot) {
          int o0 = ohalf * 64 + ot * 16 + q4 * 4;
          float mx[4] = {-1e30f, -1e30f, -1e30f, -1e30f};
#pragma unroll
          for (int kt = 0; kt < 2; ++kt) {
            v4s xv = *(const v4s*)&Xs[(gsel * 32 + kt * 16 + l15) * LDW + o0];
#pragma unroll
            for (int r = 0; r < 4; ++r) {
              float h = fmaf(acc2[ot][kt][r], sCoef2[2 * (o0 + r)], sCoef2[2 * (o0 + r) + 1]);
              float val = h + bf2f(xv[r]);
              val = (val >= 0.f) ? val : 0.01f * val;
              mx[r] = fmaxf(mx[r], val);
            }
          }
#pragma unroll
          for (int m = 1; m < 16; m <<= 1)
#pragma unroll
            for (int r = 0; r < 4; ++r) mx[r] = fmaxf(mx[r], __shfl_xor(mx[r], m, 64));
          if (l15 == 0) {
            float4 o4;
            o4.x = mx[0]; o4.y = mx[1]; o4.z = mx[2]; o4.w = mx[3];
            *(float4*)(out_pooled + (size_t)(g0 + gsel) * DD + o0) = o4;
          }
        }
      }
    }
    __syncthreads();
  }

  if constexpr (PASS <= 1) {
    if (tid < 128) {
      float* bb = bins_out + (((blockIdx.x & 63) * 128 + tid) << 1);
      atomicAdd(bb, bnS[tid]);
      atomicAdd(bb + 1, bnQ[tid]);
    }
  }
}

extern "C" void kernel_launch(void* const* d_in, const int* in_sizes, int n_in,
                              void* d_out, int out_size, void* d_ws, size_t ws_size,
                              hipStream_t stream) {
  const float* xyz    = (const float*)d_in[0];
  const float* points = (const float*)d_in[1];
  const float* alpha  = (const float*)d_in[2];
  const float* beta   = (const float*)d_in[3];
  const float* w1     = (const float*)d_in[4];
  const float* g1     = (const float*)d_in[6];
  const float* be1    = (const float*)d_in[7];
  const float* w2     = (const float*)d_in[8];
  const float* g2     = (const float*)d_in[10];
  const float* be2    = (const float*)d_in[11];
  float* out = (float*)d_out;

  char* w = (char*)d_ws;
  int* fps_i   = (int*)(w + OFF_FPSIDX);
  int* knn_i   = (int*)(w + OFF_KNN);
  float* meanp = (float*)(w + OFF_MEAN);
  float* varb  = (float*)(w + OFF_VARB);
  float* bins1 = (float*)(w + OFF_BINS1);
  float* bins2 = (float*)(w + OFF_BINS2);
  float* rstdp = (float*)(w + OFF_RSTD);
  float* coef1 = (float*)(w + OFF_COEF1);
  float* coef2 = (float*)(w + OFF_COEF2);
  short* w1b   = (short*)(w + OFF_W1BF);
  short* w2b   = (short*)(w + OFF_W2BF);
  float* xyzT  = (float*)(w + OFF_XYZT);

  hipMemsetAsync(w + MEMSET_OFF, 0, MEMSET_LEN, stream);
  xpose_kernel<<<256, 256, 0, stream>>>(xyz, xyzT);
  cvtw_kernel<<<64, 256, 0, stream>>>(w1, w2, w1b, w2b);
  fps_kernel<<<BB, 256, 0, stream>>>(xyzT, fps_i, out);
  knn_kernel<<<(BB * SS) / 4, 256, 0, stream>>>(xyzT, fps_i, knn_i);
  meanvar_kernel<<<(BB * SS) / 4, 256, 0, stream>>>(points, knn_i, meanp, varb);
  fin_std_kernel<<<1, 64, 0, stream>>>(varb, rstdp);
  gemm_pass<0><<<GGRID, 256, 0, stream>>>(points, knn_i, fps_i, meanp, rstdp, alpha, beta,
                                          w1b, w2b, coef1, coef2, bins1, nullptr);
  fin_bn_kernel<<<1, 128, 0, stream>>>(bins1, g1, be1, coef1);
  gemm_pass<1><<<GGRID, 256, 0, stream>>>(points, knn_i, fps_i, meanp, rstdp, alpha, beta,
                                          w1b, w2b, coef1, coef2, bins2, nullptr);
  fin_bn_kernel<<<1, 128, 0, stream>>>(bins2, g2, be2, coef2);
  gemm_pass<2><<<GGRID, 256, 0, stream>>>(points, knn_i, fps_i, meanp, rstdp, alpha, beta,
                                          w1b, w2b, coef1, coef2, nullptr, out + (size_t)BB * SS * 3);
}

// Round 4
// 2228.561 us; speedup vs baseline: 1.3446x; 1.3446x over previous
//
#include <hip/hip_runtime.h>

#define DI __device__ __forceinline__

typedef __attribute__((ext_vector_type(8))) short v8s;
typedef __attribute__((ext_vector_type(4))) short v4s;
typedef __attribute__((ext_vector_type(4))) float v4f;

constexpr int BB = 16, NN = 4096, CH = 64, SS = 1024, KK = 32, DD = 128;
constexpr int LDW = 136;                 // LDS row stride in shorts (pad: 16B-aligned rows, <=2-way banks)
constexpr int GPC = 2;                   // groups per chunk in gemm passes
constexpr int NCHUNK = (BB * SS) / GPC;  // 8192
constexpr int GGRID = 512;

// ---- ws layout (bytes) ----
constexpr size_t OFF_FPSIDX = 0;         // int[16384]
constexpr size_t OFF_KNN    = 65536;     // int[524288]
constexpr size_t OFF_MEAN   = 2162688;   // float[1048576]
constexpr size_t OFF_VARB   = 6356992;   // float[1024]
constexpr size_t OFF_BINS1  = 6361088;   // float[16384]  [64][128][2]
constexpr size_t OFF_BINS2  = 6426624;   // float[16384]
constexpr size_t OFF_RSTD   = 6492160;   // float[16]
constexpr size_t OFF_COEF1  = 6492224;   // float[256]
constexpr size_t OFF_COEF2  = 6493248;   // float[256]
constexpr size_t OFF_W1BF   = 6494272;   // short[16384]
constexpr size_t OFF_W2BF   = 6527040;   // short[16384]
constexpr size_t OFF_XYZT   = 6559808;   // float[196608]  [B][3][N]
constexpr size_t MEMSET_OFF = OFF_VARB;
constexpr size_t MEMSET_LEN = 4096 + 65536 + 65536;

DI short f2bf(float f) {
  unsigned u = __float_as_uint(f);
  u = (u + 0x7fffu + ((u >> 16) & 1u)) >> 16;
  return (short)u;
}
DI float bf2f(short s) { return __uint_as_float(((unsigned)(unsigned short)s) << 16); }

// ---------------- xyz transpose: [B][N][3] -> [B][3][N] ----------------
__global__ void xpose_kernel(const float* __restrict__ xyz, float* __restrict__ xyzT) {
  int i = blockIdx.x * 256 + threadIdx.x;  // < B*N
  int b = i >> 12, n = i & 4095;
  const float* s = xyz + (size_t)i * 3;
  float* d = xyzT + (size_t)b * 3 * NN + n;
  d[0] = s[0]; d[NN] = s[1]; d[2 * NN] = s[2];
}

// ---------------- weight f32 -> bf16 ----------------
__global__ void cvtw_kernel(const float* __restrict__ w1, const float* __restrict__ w2,
                            short* __restrict__ w1b, short* __restrict__ w2b) {
  int i = blockIdx.x * 256 + threadIdx.x;  // < 16384
  w1b[i] = f2bf(w1[i]);
  w2b[i] = f2bf(w2[i]);
}

// DPP-based (value,index) max step: partner = lane ^ {1,2,7,15} within a row of 16.
// Masks {1,2,7,15} generate the full 16-lane group, so 4 stages give row max.
template <int CTRL>
DI void dpp_max_stage(float& v, int& i) {
  float ov = __int_as_float(__builtin_amdgcn_update_dpp(0, __float_as_int(v), CTRL, 0xf, 0xf, true));
  int oi = __builtin_amdgcn_update_dpp(0, i, CTRL, 0xf, 0xf, true);
  if (ov > v) { v = ov; i = oi; }
}

// ---------------- FPS v4: branchless exact-f64 chain in registers ----------------
// 16 blocks x 512 threads (8 waves), 8 points/lane (pt k -> global k*512+tid).
// Per round: unconditional f64 min-dist update (registers, no branches), reduce
// on monotone f32 images via DPP + readlane, ONE LDS partial exchange (dbuf).
// f32-image tie (rare) -> block-uniform exact f64 fallback => decisions f64-exact.
// No global memory in the round loop; outputs buffered in LDS, written after.
__global__ __launch_bounds__(512) void fps_kernel(const float* __restrict__ xyzT,
                                                  int* __restrict__ fps_idx,
                                                  float* __restrict__ out_xyz) {
  int b = blockIdx.x, tid = threadIdx.x;
  int wave = tid >> 6, lane = tid & 63;
  const float* bx = xyzT + (size_t)b * 3 * NN;
  const float* by = bx + NN;
  const float* bz = bx + 2 * NN;
  __shared__ float4 s_xyzw[NN];  // 64 KB coords broadcast
  __shared__ int s_fidx[SS];     // 4 KB selected indices
  __shared__ float s_pv[2][8];   // wave partial values (dbuf by round parity)
  __shared__ int s_px[2][8];     // wave partial idx | tie<<30
  __shared__ double s_ed[8];     // exact-fallback partials
  __shared__ int s_ei[8];

  double px64[8], py64[8], pz64[8], m64[8];
  float m32[8];
#pragma unroll
  for (int k = 0; k < 8; ++k) {
    int gi = k * 512 + tid;
    float x = bx[gi], y = by[gi], z = bz[gi];
    s_xyzw[gi] = make_float4(x, y, z, 0.f);
    px64[k] = (double)x; py64[k] = (double)y; pz64[k] = (double)z;
    m64[k] = 1e10; m32[k] = 1e10f;
  }
  if (tid == 0) s_fidx[0] = 0;
  __syncthreads();
  float4 c0 = s_xyzw[0];
  double cx = (double)c0.x, cy = (double)c0.y, cz = (double)c0.z;

  for (int j = 1; j < SS; ++j) {
    // ---- unconditional exact chain update (branchless, independent per point) ----
#pragma unroll
    for (int k = 0; k < 8; ++k) {
      double dx = px64[k] - cx, dy = py64[k] - cy, dz = pz64[k] - cz;
      double d = fma(dx, dx, fma(dy, dy, dz * dz));
      m64[k] = fmin(m64[k], d);
      m32[k] = (float)m64[k];  // monotone image
    }
    // ---- lane top1 (+ in-lane dup count of the max image) ----
    float v1 = -1.f; int i1 = 0, cnt1 = 0;
#pragma unroll
    for (int k = 0; k < 8; ++k) {
      float v = m32[k];
      if (v > v1) { v1 = v; i1 = k * 512 + tid; cnt1 = 1; }
      else if (v == v1) ++cnt1;
    }
    // ---- wave argmax: 4 DPP stages (row of 16) + readlane cross-row ----
    float wv = v1; int wi = i1;
    dpp_max_stage<0xB1>(wv, wi);   // quad_perm [1,0,3,2]  : xor 1
    dpp_max_stage<0x4E>(wv, wi);   // quad_perm [2,3,0,1]  : xor 2
    dpp_max_stage<0x141>(wv, wi);  // ROW_HALF_MIRROR      : xor 7
    dpp_max_stage<0x140>(wv, wi);  // ROW_MIRROR           : xor 15
    int vb = __float_as_int(wv);
    float r0 = __int_as_float(__builtin_amdgcn_readlane(vb, 0));
    float r1 = __int_as_float(__builtin_amdgcn_readlane(vb, 16));
    float r2 = __int_as_float(__builtin_amdgcn_readlane(vb, 32));
    float r3 = __int_as_float(__builtin_amdgcn_readlane(vb, 48));
    int q0 = __builtin_amdgcn_readlane(wi, 0);
    int q1 = __builtin_amdgcn_readlane(wi, 16);
    int q2 = __builtin_amdgcn_readlane(wi, 32);
    int q3 = __builtin_amdgcn_readlane(wi, 48);
    float fvw = r0; int fiw = q0;
    if (r1 > fvw) { fvw = r1; fiw = q1; }
    if (r2 > fvw) { fvw = r2; fiw = q2; }
    if (r3 > fvw) { fvw = r3; fiw = q3; }
    // tie at wave level: >1 lane attains max, or attainer has in-lane dup
    unsigned long long t1 = __ballot(v1 == fvw);
    unsigned long long t2 = __ballot(v1 == fvw && cnt1 > 1);
    int tiew = (__popcll(t1) > 1 || t2 != 0ull) ? 1 : 0;
    if (lane == 0) { s_pv[j & 1][wave] = fvw; s_px[j & 1][wave] = fiw | (tiew << 30); }
    __syncthreads();
    // ---- cross-wave: uniform scan of 8 partials ----
    float fv = -1.f; int fi = 0, tie = 0;
#pragma unroll
    for (int w = 0; w < 8; ++w) {
      float v = s_pv[j & 1][w];
      int xi = s_px[j & 1][w];
      if (v > fv) { fv = v; fi = xi & 0x0FFFFFFF; tie = (xi >> 30) & 1; }
      else if (v == fv) tie = 1;
    }
    if (tie) {  // block-uniform exact f64 fallback (rare)
      double bv = -1.0; int bi = 1 << 30;
#pragma unroll
      for (int k = 0; k < 8; ++k) {
        int gi = k * 512 + tid;
        if (m64[k] > bv || (m64[k] == bv && gi < bi)) { bv = m64[k]; bi = gi; }
      }
#pragma unroll
      for (int mm = 1; mm < 64; mm <<= 1) {
        double ov = __shfl_xor(bv, mm, 64);
        int oi = __shfl_xor(bi, mm, 64);
        if (ov > bv || (ov == bv && oi < bi)) { bv = ov; bi = oi; }
      }
      if (lane == 0) { s_ed[wave] = bv; s_ei[wave] = bi; }
      __syncthreads();
      double fbv = s_ed[0]; int fbi = s_ei[0];
#pragma unroll
      for (int w = 1; w < 8; ++w) {
        double v = s_ed[w]; int ii = s_ei[w];
        if (v > fbv || (v == fbv && ii < fbi)) { fbv = v; fbi = ii; }
      }
      fi = fbi;
      __syncthreads();  // protect s_ed/s_ei if next rounds also tie
    }
    float4 cw = s_xyzw[fi];  // uniform-address LDS broadcast
    cx = (double)cw.x; cy = (double)cw.y; cz = (double)cw.z;
    if (tid == 0) s_fidx[j] = fi;
  }
  __syncthreads();
  // ---- write out fps_idx + new_xyz (once, after the serial loop) ----
  for (int t = tid; t < SS; t += 512) {
    int idx = s_fidx[t];
    fps_idx[b * SS + t] = idx;
    float4 p = s_xyzw[idx];
    out_xyz[((size_t)b * SS + t) * 3 + 0] = p.x;
    out_xyz[((size_t)b * SS + t) * 3 + 1] = p.y;
    out_xyz[((size_t)b * SS + t) * 3 + 2] = p.z;
  }
}

// ---------------- kNN: one wave per query ----------------
// f32 bulk distances -> threshold (32nd smallest of per-lane minima, inflated) ->
// compact candidates to LDS with exact f64 distances -> 32 rounds exact argmin.
__global__ __launch_bounds__(256) void knn_kernel(const float* __restrict__ xyzT,
                                                  const int* __restrict__ fps_idx,
                                                  int* __restrict__ knn_idx) {
  int wave = threadIdx.x >> 6, lane = threadIdx.x & 63;
  int q = blockIdx.x * 4 + wave, b = q >> 10;
  const float* bx = xyzT + (size_t)b * 3 * NN;
  const float* by = bx + NN;
  const float* bz = bx + 2 * NN;
  int qi = fps_idx[q];
  float qx = bx[qi], qy = by[qi], qz = bz[qi];
  float d[64];
  float lmin = 1e30f;
#pragma unroll
  for (int j = 0; j < 64; ++j) {
    int n = j * 64 + lane;
    float dx = bx[n] - qx, dy = by[n] - qy, dz = bz[n] - qz;
    d[j] = fmaf(dx, dx, fmaf(dy, dy, dz * dz));
    lmin = fminf(lmin, d[j]);
  }
  // bitonic sort of per-lane minima across the wave (ascending)
  float v = lmin;
#pragma unroll
  for (int size = 2; size <= 64; size <<= 1) {
#pragma unroll
    for (int stride = size >> 1; stride > 0; stride >>= 1) {
      float o = __shfl_xor(v, stride, 64);
      bool keepmin = (((lane & size) == 0) == ((lane & stride) == 0));
      v = keepmin ? fminf(v, o) : fmaxf(v, o);
    }
  }
  float tau = __shfl(v, 31, 64) * 1.00001f + 1e-20f;  // >= true 32nd smallest, with margin

  __shared__ double cd[4][512];
  __shared__ int ci[4][512];
  int cnt = 0;
#pragma unroll
  for (int j = 0; j < 64; ++j) {
    bool pred = (d[j] <= tau);
    unsigned long long mask = __ballot(pred);
    if (pred) {
      int pos = cnt + __popcll(mask & ((1ull << lane) - 1ull));
      if (pos < 512) {
        int n = j * 64 + lane;
        double dx = (double)bx[n] - (double)qx;
        double dy = (double)by[n] - (double)qy;
        double dz = (double)bz[n] - (double)qz;
        cd[wave][pos] = fma(dx, dx, fma(dy, dy, dz * dz));
        ci[wave][pos] = n;
      }
    }
    cnt += __popcll(mask);
  }
  if (cnt > 512) cnt = 512;
  // 32 exact selection rounds (candidates are stored in ascending-n order; ties -> smaller pos = smaller n)
  for (int r = 0; r < 32; ++r) {
    double bv = 1e300; int bp = 1 << 30;
    for (int p = lane; p < cnt; p += 64) {
      double vv = cd[wave][p];
      if (vv < bv) { bv = vv; bp = p; }
    }
#pragma unroll
    for (int m = 1; m < 64; m <<= 1) {
      double ov = __shfl_xor(bv, m, 64);
      int op = __shfl_xor(bp, m, 64);
      if (ov < bv || (ov == bv && op < bp)) { bv = ov; bp = op; }
    }
    if (bp < (1 << 30) && (bp & 63) == lane) {
      knn_idx[(size_t)q * KK + r] = ci[wave][bp];
      cd[wave][bp] = 1e300;
    }
  }
}

// ---------------- per-group mean over K + per-batch sum of diff^2 ----------------
__global__ __launch_bounds__(256) void meanvar_kernel(const float* __restrict__ points,
                                                      const int* __restrict__ kidx,
                                                      float* __restrict__ mean_out,
                                                      float* __restrict__ var_bins) {
  int wave = threadIdx.x >> 6, lane = threadIdx.x & 63;
  int g = blockIdx.x * 4 + wave;  // global group
  int b = g >> 10;
  const float* pb = points + (size_t)b * NN * CH;
  const int* idx = kidx + (size_t)g * KK;
  float s1 = 0.f, s2 = 0.f;
#pragma unroll
  for (int k = 0; k < KK; ++k) {
    float x = pb[(size_t)idx[k] * CH + lane];
    s1 += x;
    s2 = fmaf(x, x, s2);
  }
  float m = s1 * (1.0f / 32.0f);
  mean_out[(size_t)g * CH + lane] = m;
  float part = s2 - s1 * m;  // sum_k (x-m)^2 (exact algebra: 32*m == s1)
#pragma unroll
  for (int mm = 1; mm < 64; mm <<= 1) part += __shfl_xor(part, mm, 64);
  if (lane == 0) atomicAdd(&var_bins[b * 64 + (g & 63)], part);
}

__global__ void fin_std_kernel(const float* __restrict__ bins, float* __restrict__ rstd) {
  int t = threadIdx.x;
  if (t < BB) {
    float s = 0.f;
    for (int i = 0; i < 64; ++i) s += bins[t * 64 + i];
    float var = s / (float)(SS * KK * CH - 1);
    rstd[t] = 1.0f / (sqrtf(var) + 1e-5f);
  }
}

__global__ void fin_bn_kernel(const float* __restrict__ bins, const float* __restrict__ g,
                              const float* __restrict__ be, float* __restrict__ coef) {
  int o = threadIdx.x;  // < 128
  float s = 0.f, qq = 0.f;
  for (int bin = 0; bin < 64; ++bin) {
    s += bins[(bin * 128 + o) * 2 + 0];
    qq += bins[(bin * 128 + o) * 2 + 1];
  }
  constexpr float invM = 1.0f / (float)(BB * SS * KK);
  float mean = s * invM;
  float var = qq * invM - mean * mean;
  if (var < 0.f) var = 0.f;
  float sc = g[o] / sqrtf(var + 1e-5f);
  coef[2 * o] = sc;
  coef[2 * o + 1] = be[o] - mean * sc;
}

// ---------------- GEMM passes ----------------
// PASS 0: X->h1, accumulate BN1 stats.
// PASS 1: X->h1->P->h2, accumulate BN2 stats.
// PASS 2: X->h1->P->h2, BN2 + residual + lrelu + maxpool -> out.
template <int PASS>
__global__ __launch_bounds__(256, 2) void gemm_pass(
    const float* __restrict__ points, const int* __restrict__ kidx, const int* __restrict__ fidx,
    const float* __restrict__ mean, const float* __restrict__ rstd,
    const float* __restrict__ alpha, const float* __restrict__ beta,
    const short* __restrict__ w1bf, const short* __restrict__ w2bf,
    const float* __restrict__ coef1, const float* __restrict__ coef2,
    float* __restrict__ bins_out, float* __restrict__ out_pooled) {
  __shared__ short Xs[GPC * 32 * LDW];
  __shared__ short Ps[(PASS >= 1) ? (GPC * 32 * LDW) : 8];
  __shared__ float sAlpha[64], sBeta[64];
  __shared__ float sCoef1[256], sCoef2[256];
  __shared__ float bnS[128], bnQ[128];

  int tid = threadIdx.x;
  int wave = tid >> 6, lane = tid & 63;
  int q4 = lane >> 4, l15 = lane & 15;
  int ohalf = wave & 1, gsel = wave >> 1;

  // W fragments -> registers
  v8s wf1[4][4];
  v8s wf2[4][4];
#pragma unroll
  for (int ot = 0; ot < 4; ++ot) {
    int row = ohalf * 64 + ot * 16 + l15;
#pragma unroll
    for (int cs = 0; cs < 4; ++cs) {
      wf1[ot][cs] = *(const v8s*)(w1bf + row * 128 + cs * 32 + q4 * 8);
      if constexpr (PASS >= 1) wf2[ot][cs] = *(const v8s*)(w2bf + row * 128 + cs * 32 + q4 * 8);
    }
  }
  if (tid < 64) { sAlpha[tid] = alpha[tid]; sBeta[tid] = beta[tid]; }
  if constexpr (PASS >= 1) sCoef1[tid] = coef1[tid];
  if constexpr (PASS == 2) sCoef2[tid] = coef2[tid];
  if constexpr (PASS <= 1) {
    if (tid < 128) { bnS[tid] = 0.f; bnQ[tid] = 0.f; }
  }
  __syncthreads();

  for (int chunk = blockIdx.x; chunk < NCHUNK; chunk += GGRID) {
    int g0 = chunk * GPC;
    // ---- stage Xs: [g][k][0:64]=normalized grouped, [64:128]=new_pts ----
    {
      int sg = tid >> 7;
      int sk = (tid >> 2) & 31;
      int qr = tid & 3;
      int ggl = g0 + sg;
      int b = ggl >> 10;
      const float* pb = points + (size_t)b * NN * CH;
      int row = (qr < 2) ? kidx[(size_t)ggl * KK + sk] : fidx[ggl];
      int ch0 = (qr & 1) * 32;
      const float* src = pb + (size_t)row * CH + ch0;
      const float* mrow = mean + (size_t)ggl * CH + ch0;
      float rs = rstd[b];
      bool norm = (qr < 2);
      v8s pack[4];
#pragma unroll
      for (int cc = 0; cc < 32; cc += 4) {
        float4 vv = *(const float4*)(src + cc);
        if (norm) {
          float4 mv = *(const float4*)(mrow + cc);
          vv.x = fmaf((vv.x - mv.x) * rs, sAlpha[ch0 + cc + 0], sBeta[ch0 + cc + 0]);
          vv.y = fmaf((vv.y - mv.y) * rs, sAlpha[ch0 + cc + 1], sBeta[ch0 + cc + 1]);
          vv.z = fmaf((vv.z - mv.z) * rs, sAlpha[ch0 + cc + 2], sBeta[ch0 + cc + 2]);
          vv.w = fmaf((vv.w - mv.w) * rs, sAlpha[ch0 + cc + 3], sBeta[ch0 + cc + 3]);
        }
        pack[cc >> 3][(cc & 7) + 0] = f2bf(vv.x);
        pack[cc >> 3][(cc & 7) + 1] = f2bf(vv.y);
        pack[cc >> 3][(cc & 7) + 2] = f2bf(vv.z);
        pack[cc >> 3][(cc & 7) + 3] = f2bf(vv.w);
      }
      short* dst = &Xs[(sg * 32 + sk) * LDW + qr * 32];
#pragma unroll
      for (int p2 = 0; p2 < 4; ++p2) *(v8s*)(dst + p2 * 8) = pack[p2];
    }
    __syncthreads();

    // ---- GEMM1: h1 = W1 * X ----
    v4f acc[4][2] = {};
#pragma unroll
    for (int cs = 0; cs < 4; ++cs) {
      v8s bfr[2];
#pragma unroll
      for (int kt = 0; kt < 2; ++kt)
        bfr[kt] = *(const v8s*)&Xs[(gsel * 32 + kt * 16 + l15) * LDW + cs * 32 + q4 * 8];
#pragma unroll
      for (int ot = 0; ot < 4; ++ot)
#pragma unroll
        for (int kt = 0; kt < 2; ++kt)
          acc[ot][kt] = __builtin_amdgcn_mfma_f32_16x16x32_bf16(wf1[ot][cs], bfr[kt], acc[ot][kt], 0, 0, 0);
    }

    if constexpr (PASS == 0) {
      // BN1 stats of h1
#pragma unroll
      for (int ot = 0; ot < 4; ++ot) {
        float sv[4], sq[4];
#pragma unroll
        for (int r = 0; r < 4; ++r) {
          float a0 = acc[ot][0][r], a1 = acc[ot][1][r];
          sv[r] = a0 + a1;
          sq[r] = fmaf(a0, a0, a1 * a1);
        }
#pragma unroll
        for (int m = 1; m < 16; m <<= 1)
#pragma unroll
          for (int r = 0; r < 4; ++r) {
            sv[r] += __shfl_xor(sv[r], m, 64);
            sq[r] += __shfl_xor(sq[r], m, 64);
          }
        if (l15 == 0) {
          int o0 = ohalf * 64 + ot * 16 + q4 * 4;
#pragma unroll
          for (int r = 0; r < 4; ++r) {
            atomicAdd(&bnS[o0 + r], sv[r]);
            atomicAdd(&bnQ[o0 + r], sq[r]);
          }
        }
      }
    } else {
      // ---- P = lrelu(bn1(h1)) -> Ps ----
#pragma unroll
      for (int ot = 0; ot < 4; ++ot) {
        int o0 = ohalf * 64 + ot * 16 + q4 * 4;
#pragma unroll
        for (int kt = 0; kt < 2; ++kt) {
          v4s pk;
#pragma unroll
          for (int r = 0; r < 4; ++r) {
            float h = fmaf(acc[ot][kt][r], sCoef1[2 * (o0 + r)], sCoef1[2 * (o0 + r) + 1]);
            h = (h >= 0.f) ? h : 0.01f * h;
            pk[r] = f2bf(h);
          }
          *(v4s*)&Ps[(gsel * 32 + kt * 16 + l15) * LDW + o0] = pk;
        }
      }
      __syncthreads();

      // ---- GEMM2: h2 = W2 * P ----
      v4f acc2[4][2] = {};
#pragma unroll
      for (int cs = 0; cs < 4; ++cs) {
        v8s pfr[2];
#pragma unroll
        for (int kt = 0; kt < 2; ++kt)
          pfr[kt] = *(const v8s*)&Ps[(gsel * 32 + kt * 16 + l15) * LDW + cs * 32 + q4 * 8];
#pragma unroll
        for (int ot = 0; ot < 4; ++ot)
#pragma unroll
          for (int kt = 0; kt < 2; ++kt)
            acc2[ot][kt] = __builtin_amdgcn_mfma_f32_16x16x32_bf16(wf2[ot][cs], pfr[kt], acc2[ot][kt], 0, 0, 0);
      }

      if constexpr (PASS == 1) {
        // BN2 stats of h2
#pragma unroll
        for (int ot = 0; ot < 4; ++ot) {
          float sv[4], sq[4];
#pragma unroll
          for (int r = 0; r < 4; ++r) {
            float a0 = acc2[ot][0][r], a1 = acc2[ot][1][r];
            sv[r] = a0 + a1;
            sq[r] = fmaf(a0, a0, a1 * a1);
          }
#pragma unroll
          for (int m = 1; m < 16; m <<= 1)
#pragma unroll
            for (int r = 0; r < 4; ++r) {
              sv[r] += __shfl_xor(sv[r], m, 64);
              sq[r] += __shfl_xor(sq[r], m, 64);
            }
          if (l15 == 0) {
            int o0 = ohalf * 64 + ot * 16 + q4 * 4;
#pragma unroll
            for (int r = 0; r < 4; ++r) {
              atomicAdd(&bnS[o0 + r], sv[r]);
              atomicAdd(&bnQ[o0 + r], sq[r]);
            }
          }
        }
      } else {
        // ---- epilogue: lrelu(bn2(h2) + X) , max over k, store ----
#pragma unroll
        for (int ot = 0; ot < 4; ++ot) {
          int o0 = ohalf * 64 + ot * 16 + q4 * 4;
          float mx[4] = {-1e30f, -1e30f, -1e30f, -1e30f};
#pragma unroll
          for (int kt = 0; kt < 2; ++kt) {
            v4s xv = *(const v4s*)&Xs[(gsel * 32 + kt * 16 + l15) * LDW + o0];
#pragma unroll
            for (int r = 0; r < 4; ++r) {
              float h = fmaf(acc2[ot][kt][r], sCoef2[2 * (o0 + r)], sCoef2[2 * (o0 + r) + 1]);
              float val = h + bf2f(xv[r]);
              val = (val >= 0.f) ? val : 0.01f * val;
              mx[r] = fmaxf(mx[r], val);
            }
          }
#pragma unroll
          for (int m = 1; m < 16; m <<= 1)
#pragma unroll
            for (int r = 0; r < 4; ++r) mx[r] = fmaxf(mx[r], __shfl_xor(mx[r], m, 64));
          if (l15 == 0) {
            float4 o4;
            o4.x = mx[0]; o4.y = mx[1]; o4.z = mx[2]; o4.w = mx[3];
            *(float4*)(out_pooled + (size_t)(g0 + gsel) * DD + o0) = o4;
          }
        }
      }
    }
    __syncthreads();
  }

  if constexpr (PASS <= 1) {
    if (tid < 128) {
      float* bb = bins_out + (((blockIdx.x & 63) * 128 + tid) << 1);
      atomicAdd(bb, bnS[tid]);
      atomicAdd(bb + 1, bnQ[tid]);
    }
  }
}

extern "C" void kernel_launch(void* const* d_in, const int* in_sizes, int n_in,
                              void* d_out, int out_size, void* d_ws, size_t ws_size,
                              hipStream_t stream) {
  const float* xyz    = (const float*)d_in[0];
  const float* points = (const float*)d_in[1];
  const float* alpha  = (const float*)d_in[2];
  const float* beta   = (const float*)d_in[3];
  const float* w1     = (const float*)d_in[4];
  const float* g1     = (const float*)d_in[6];
  const float* be1    = (const float*)d_in[7];
  const float* w2     = (const float*)d_in[8];
  const float* g2     = (const float*)d_in[10];
  const float* be2    = (const float*)d_in[11];
  float* out = (float*)d_out;

  char* w = (char*)d_ws;
  int* fps_i   = (int*)(w + OFF_FPSIDX);
  int* knn_i   = (int*)(w + OFF_KNN);
  float* meanp = (float*)(w + OFF_MEAN);
  float* varb  = (float*)(w + OFF_VARB);
  float* bins1 = (float*)(w + OFF_BINS1);
  float* bins2 = (float*)(w + OFF_BINS2);
  float* rstdp = (float*)(w + OFF_RSTD);
  float* coef1 = (float*)(w + OFF_COEF1);
  float* coef2 = (float*)(w + OFF_COEF2);
  short* w1b   = (short*)(w + OFF_W1BF);
  short* w2b   = (short*)(w + OFF_W2BF);
  float* xyzT  = (float*)(w + OFF_XYZT);

  hipMemsetAsync(w + MEMSET_OFF, 0, MEMSET_LEN, stream);
  xpose_kernel<<<256, 256, 0, stream>>>(xyz, xyzT);
  cvtw_kernel<<<64, 256, 0, stream>>>(w1, w2, w1b, w2b);
  fps_kernel<<<BB, 512, 0, stream>>>(xyzT, fps_i, out);
  knn_kernel<<<(BB * SS) / 4, 256, 0, stream>>>(xyzT, fps_i, knn_i);
  meanvar_kernel<<<(BB * SS) / 4, 256, 0, stream>>>(points, knn_i, meanp, varb);
  fin_std_kernel<<<1, 64, 0, stream>>>(varb, rstdp);
  gemm_pass<0><<<GGRID, 256, 0, stream>>>(points, knn_i, fps_i, meanp, rstdp, alpha, beta,
                                          w1b, w2b, coef1, coef2, bins1, nullptr);
  fin_bn_kernel<<<1, 128, 0, stream>>>(bins1, g1, be1, coef1);
  gemm_pass<1><<<GGRID, 256, 0, stream>>>(points, knn_i, fps_i, meanp, rstdp, alpha, beta,
                                          w1b, w2b, coef1, coef2, bins2, nullptr);
  fin_bn_kernel<<<1, 128, 0, stream>>>(bins2, g2, be2, coef2);
  gemm_pass<2><<<GGRID, 256, 0, stream>>>(points, knn_i, fps_i, meanp, rstdp, alpha, beta,
                                          w1b, w2b, coef1, coef2, nullptr, out + (size_t)BB * SS * 3);
}

// Round 5
// 1510.664 us; speedup vs baseline: 1.9837x; 1.4752x over previous
//
#include <hip/hip_runtime.h>

#define DI __device__ __forceinline__

typedef __attribute__((ext_vector_type(8))) short v8s;
typedef __attribute__((ext_vector_type(4))) short v4s;
typedef __attribute__((ext_vector_type(4))) float v4f;
typedef unsigned long long u64;

constexpr int BB = 16, NN = 4096, CH = 64, SS = 1024, KK = 32, DD = 128;
constexpr int LDW = 136;                 // LDS row stride in shorts (pad: 16B-aligned rows, <=2-way banks)
constexpr int GPC = 2;                   // groups per chunk in gemm passes
constexpr int NCHUNK = (BB * SS) / GPC;  // 8192
constexpr int GGRID = 512;

// ---- ws layout (bytes) ----
constexpr size_t OFF_FPSIDX = 0;         // int[16384]
constexpr size_t OFF_KNN    = 65536;     // int[524288]
constexpr size_t OFF_MEAN   = 2162688;   // float[1048576]
constexpr size_t OFF_VARB   = 6356992;   // float[1024]
constexpr size_t OFF_BINS1  = 6361088;   // float[16384]  [64][128][2]
constexpr size_t OFF_BINS2  = 6426624;   // float[16384]
constexpr size_t OFF_RSTD   = 6492160;   // float[16]
constexpr size_t OFF_COEF1  = 6492224;   // float[256]
constexpr size_t OFF_COEF2  = 6493248;   // float[256]
constexpr size_t OFF_W1BF   = 6494272;   // short[16384]
constexpr size_t OFF_W2BF   = 6527040;   // short[16384]
constexpr size_t OFF_XYZT   = 6559808;   // float[196608]  [B][3][N]
constexpr size_t MEMSET_OFF = OFF_VARB;
constexpr size_t MEMSET_LEN = 4096 + 65536 + 65536;

DI short f2bf(float f) {
  unsigned u = __float_as_uint(f);
  u = (u + 0x7fffu + ((u >> 16) & 1u)) >> 16;
  return (short)u;
}
DI float bf2f(short s) { return __uint_as_float(((unsigned)(unsigned short)s) << 16); }

// ---------------- xyz transpose: [B][N][3] -> [B][3][N] ----------------
__global__ void xpose_kernel(const float* __restrict__ xyz, float* __restrict__ xyzT) {
  int i = blockIdx.x * 256 + threadIdx.x;  // < B*N
  int b = i >> 12, n = i & 4095;
  const float* s = xyz + (size_t)i * 3;
  float* d = xyzT + (size_t)b * 3 * NN + n;
  d[0] = s[0]; d[NN] = s[1]; d[2 * NN] = s[2];
}

// ---------------- weight f32 -> bf16 ----------------
__global__ void cvtw_kernel(const float* __restrict__ w1, const float* __restrict__ w2,
                            short* __restrict__ w1b, short* __restrict__ w2b) {
  int i = blockIdx.x * 256 + threadIdx.x;  // < 16384
  w1b[i] = f2bf(w1[i]);
  w2b[i] = f2bf(w2[i]);
}

// 64-bit DPP shuffle within a row of 16 lanes
template <int CTRL>
DI u64 dpp_u64(u64 x) {
  int lo = __builtin_amdgcn_update_dpp(0, (int)(unsigned)x, CTRL, 0xf, 0xf, true);
  int hi = __builtin_amdgcn_update_dpp(0, (int)(unsigned)(x >> 32), CTRL, 0xf, 0xf, true);
  return ((u64)(unsigned)hi << 32) | (unsigned)lo;
}
template <int CTRL>
DI void dpp_umax_stage(u64& x) {
  u64 o = dpp_u64<CTRL>(x);
  if (o > x) x = o;
}
DI u64 readlane_u64(u64 x, int l) {
  unsigned lo = (unsigned)__builtin_amdgcn_readlane((int)(unsigned)x, l);
  unsigned hi = (unsigned)__builtin_amdgcn_readlane((int)(unsigned)(x >> 32), l);
  return ((u64)hi << 32) | lo;
}

// ---------------- FPS v5: u64-key argmax, branchless exact-f64 chain ----------------
// 16 blocks x 512 threads (8 waves), 8 points/lane (pt k -> global k*512+tid).
// Chain: dot-form f64 (clamped at 0), unconditional, registers only.
// Reduce: single u64 key = (bits(m64) & ~0xFFF) | (4095 - gi).  For positive
// doubles the bit pattern is order-monotone, so u64-max == f64-argmax with
// min-index tie-break (jnp.argmax semantics). 12-bit mantissa clobber = 2^-40
// relative quantization -- below any generic distance gap. No cvt, no ballot,
// no tie fallback. One barrier + one u64 partial exchange per round.
__global__ __launch_bounds__(512, 2) void fps_kernel(const float* __restrict__ xyzT,
                                                     int* __restrict__ fps_idx,
                                                     float* __restrict__ out_xyz) {
  int b = blockIdx.x, tid = threadIdx.x;
  int wave = tid >> 6, lane = tid & 63;
  const float* bx = xyzT + (size_t)b * 3 * NN;
  const float* by = bx + NN;
  const float* bz = bx + 2 * NN;
  __shared__ float4 s_xyzw[NN];  // 64 KB coords broadcast
  __shared__ int s_fidx[SS];     // 4 KB selected indices
  __shared__ u64 s_pk[2][8];     // wave partial keys (dbuf by round parity)

  double px64[8], py64[8], pz64[8], pp64[8], m64[8];
  int tagbase = 4095 - tid;  // tag for point k: tagbase - k*512 == 4095 - gi
#pragma unroll
  for (int k = 0; k < 8; ++k) {
    int gi = k * 512 + tid;
    float x = bx[gi], y = by[gi], z = bz[gi];
    s_xyzw[gi] = make_float4(x, y, z, 0.f);
    px64[k] = (double)x; py64[k] = (double)y; pz64[k] = (double)z;
    pp64[k] = fma(px64[k], px64[k], fma(py64[k], py64[k], pz64[k] * pz64[k]));
    m64[k] = 1e10;
  }
  if (tid == 0) s_fidx[0] = 0;
  __syncthreads();
  float4 c0 = s_xyzw[0];
  double cx = (double)c0.x, cy = (double)c0.y, cz = (double)c0.z;

  for (int j = 1; j < SS; ++j) {
    double cx2 = -2.0 * cx, cy2 = -2.0 * cy, cz2 = -2.0 * cz;
    double cc = fma(cx, cx, fma(cy, cy, cz * cz));
    u64 best = 0;
#pragma unroll
    for (int k = 0; k < 8; ++k) {
      // d = |p-c|^2 via dot-form; clamp: self-point rounds to ~±1e-15 and a
      // negative would set the sign bit and poison the key ordering.
      double d = fma(px64[k], cx2, fma(py64[k], cy2, fma(pz64[k], cz2, pp64[k] + cc)));
      d = fmax(d, 0.0);
      m64[k] = fmin(m64[k], d);
      u64 key = ((u64)__double_as_longlong(m64[k]) & ~0xFFFull) | (u64)(tagbase - k * 512);
      if (key > best) best = key;
    }
    // wave max: 4 DPP stages within row-of-16, then cross-row via readlane
    dpp_umax_stage<0xB1>(best);   // quad_perm [1,0,3,2] : xor 1
    dpp_umax_stage<0x4E>(best);   // quad_perm [2,3,0,1] : xor 2
    dpp_umax_stage<0x141>(best);  // ROW_HALF_MIRROR     : xor 7
    dpp_umax_stage<0x140>(best);  // ROW_MIRROR          : xor 15
    u64 w0 = readlane_u64(best, 0);
    u64 w1 = readlane_u64(best, 16);
    u64 w2 = readlane_u64(best, 32);
    u64 w3 = readlane_u64(best, 48);
    u64 bw = w0;
    if (w1 > bw) bw = w1;
    if (w2 > bw) bw = w2;
    if (w3 > bw) bw = w3;
    if (lane == 0) s_pk[j & 1][wave] = bw;
    __syncthreads();
    // cross-wave: uniform scan of 8 u64 partials
    u64 bk = s_pk[j & 1][0];
#pragma unroll
    for (int w = 1; w < 8; ++w) {
      u64 v = s_pk[j & 1][w];
      if (v > bk) bk = v;
    }
    int fi = 4095 - (int)(bk & 0xFFFull);
    float4 cw = s_xyzw[fi];  // uniform-address LDS broadcast
    cx = (double)cw.x; cy = (double)cw.y; cz = (double)cw.z;
    if (tid == 0) s_fidx[j] = fi;
  }
  __syncthreads();
  // ---- write out fps_idx + new_xyz (once, after the serial loop) ----
  for (int t = tid; t < SS; t += 512) {
    int idx = s_fidx[t];
    fps_idx[b * SS + t] = idx;
    float4 p = s_xyzw[idx];
    out_xyz[((size_t)b * SS + t) * 3 + 0] = p.x;
    out_xyz[((size_t)b * SS + t) * 3 + 1] = p.y;
    out_xyz[((size_t)b * SS + t) * 3 + 2] = p.z;
  }
}

// ---------------- kNN: one wave per query ----------------
// f32 bulk distances -> threshold (32nd smallest of per-lane minima, inflated) ->
// compact candidates to LDS with exact f64 distances -> 32 rounds exact argmin.
__global__ __launch_bounds__(256) void knn_kernel(const float* __restrict__ xyzT,
                                                  const int* __restrict__ fps_idx,
                                                  int* __restrict__ knn_idx) {
  int wave = threadIdx.x >> 6, lane = threadIdx.x & 63;
  int q = blockIdx.x * 4 + wave, b = q >> 10;
  const float* bx = xyzT + (size_t)b * 3 * NN;
  const float* by = bx + NN;
  const float* bz = bx + 2 * NN;
  int qi = fps_idx[q];
  float qx = bx[qi], qy = by[qi], qz = bz[qi];
  float d[64];
  float lmin = 1e30f;
#pragma unroll
  for (int j = 0; j < 64; ++j) {
    int n = j * 64 + lane;
    float dx = bx[n] - qx, dy = by[n] - qy, dz = bz[n] - qz;
    d[j] = fmaf(dx, dx, fmaf(dy, dy, dz * dz));
    lmin = fminf(lmin, d[j]);
  }
  // bitonic sort of per-lane minima across the wave (ascending)
  float v = lmin;
#pragma unroll
  for (int size = 2; size <= 64; size <<= 1) {
#pragma unroll
    for (int stride = size >> 1; stride > 0; stride >>= 1) {
      float o = __shfl_xor(v, stride, 64);
      bool keepmin = (((lane & size) == 0) == ((lane & stride) == 0));
      v = keepmin ? fminf(v, o) : fmaxf(v, o);
    }
  }
  float tau = __shfl(v, 31, 64) * 1.00001f + 1e-20f;  // >= true 32nd smallest, with margin

  __shared__ double cd[4][512];
  __shared__ int ci[4][512];
  int cnt = 0;
#pragma unroll
  for (int j = 0; j < 64; ++j) {
    bool pred = (d[j] <= tau);
    unsigned long long mask = __ballot(pred);
    if (pred) {
      int pos = cnt + __popcll(mask & ((1ull << lane) - 1ull));
      if (pos < 512) {
        int n = j * 64 + lane;
        double dx = (double)bx[n] - (double)qx;
        double dy = (double)by[n] - (double)qy;
        double dz = (double)bz[n] - (double)qz;
        cd[wave][pos] = fma(dx, dx, fma(dy, dy, dz * dz));
        ci[wave][pos] = n;
      }
    }
    cnt += __popcll(mask);
  }
  if (cnt > 512) cnt = 512;
  // 32 exact selection rounds (candidates are stored in ascending-n order; ties -> smaller pos = smaller n)
  for (int r = 0; r < 32; ++r) {
    double bv = 1e300; int bp = 1 << 30;
    for (int p = lane; p < cnt; p += 64) {
      double vv = cd[wave][p];
      if (vv < bv) { bv = vv; bp = p; }
    }
#pragma unroll
    for (int m = 1; m < 64; m <<= 1) {
      double ov = __shfl_xor(bv, m, 64);
      int op = __shfl_xor(bp, m, 64);
      if (ov < bv || (ov == bv && op < bp)) { bv = ov; bp = op; }
    }
    if (bp < (1 << 30) && (bp & 63) == lane) {
      knn_idx[(size_t)q * KK + r] = ci[wave][bp];
      cd[wave][bp] = 1e300;
    }
  }
}

// ---------------- per-group mean over K + per-batch sum of diff^2 ----------------
__global__ __launch_bounds__(256) void meanvar_kernel(const float* __restrict__ points,
                                                      const int* __restrict__ kidx,
                                                      float* __restrict__ mean_out,
                                                      float* __restrict__ var_bins) {
  int wave = threadIdx.x >> 6, lane = threadIdx.x & 63;
  int g = blockIdx.x * 4 + wave;  // global group
  int b = g >> 10;
  const float* pb = points + (size_t)b * NN * CH;
  const int* idx = kidx + (size_t)g * KK;
  float s1 = 0.f, s2 = 0.f;
#pragma unroll
  for (int k = 0; k < KK; ++k) {
    float x = pb[(size_t)idx[k] * CH + lane];
    s1 += x;
    s2 = fmaf(x, x, s2);
  }
  float m = s1 * (1.0f / 32.0f);
  mean_out[(size_t)g * CH + lane] = m;
  float part = s2 - s1 * m;  // sum_k (x-m)^2 (exact algebra: 32*m == s1)
#pragma unroll
  for (int mm = 1; mm < 64; mm <<= 1) part += __shfl_xor(part, mm, 64);
  if (lane == 0) atomicAdd(&var_bins[b * 64 + (g & 63)], part);
}

__global__ void fin_std_kernel(const float* __restrict__ bins, float* __restrict__ rstd) {
  int t = threadIdx.x;
  if (t < BB) {
    float s = 0.f;
    for (int i = 0; i < 64; ++i) s += bins[t * 64 + i];
    float var = s / (float)(SS * KK * CH - 1);
    rstd[t] = 1.0f / (sqrtf(var) + 1e-5f);
  }
}

__global__ void fin_bn_kernel(const float* __restrict__ bins, const float* __restrict__ g,
                              const float* __restrict__ be, float* __restrict__ coef) {
  int o = threadIdx.x;  // < 128
  float s = 0.f, qq = 0.f;
  for (int bin = 0; bin < 64; ++bin) {
    s += bins[(bin * 128 + o) * 2 + 0];
    qq += bins[(bin * 128 + o) * 2 + 1];
  }
  constexpr float invM = 1.0f / (float)(BB * SS * KK);
  float mean = s * invM;
  float var = qq * invM - mean * mean;
  if (var < 0.f) var = 0.f;
  float sc = g[o] / sqrtf(var + 1e-5f);
  coef[2 * o] = sc;
  coef[2 * o + 1] = be[o] - mean * sc;
}

// ---------------- GEMM passes ----------------
// PASS 0: X->h1, accumulate BN1 stats.
// PASS 1: X->h1->P->h2, accumulate BN2 stats.
// PASS 2: X->h1->P->h2, BN2 + residual + lrelu + maxpool -> out.
template <int PASS>
__global__ __launch_bounds__(256, 2) void gemm_pass(
    const float* __restrict__ points, const int* __restrict__ kidx, const int* __restrict__ fidx,
    const float* __restrict__ mean, const float* __restrict__ rstd,
    const float* __restrict__ alpha, const float* __restrict__ beta,
    const short* __restrict__ w1bf, const short* __restrict__ w2bf,
    const float* __restrict__ coef1, const float* __restrict__ coef2,
    float* __restrict__ bins_out, float* __restrict__ out_pooled) {
  __shared__ short Xs[GPC * 32 * LDW];
  __shared__ short Ps[(PASS >= 1) ? (GPC * 32 * LDW) : 8];
  __shared__ float sAlpha[64], sBeta[64];
  __shared__ float sCoef1[256], sCoef2[256];
  __shared__ float bnS[128], bnQ[128];

  int tid = threadIdx.x;
  int wave = tid >> 6, lane = tid & 63;
  int q4 = lane >> 4, l15 = lane & 15;
  int ohalf = wave & 1, gsel = wave >> 1;

  // W fragments -> registers
  v8s wf1[4][4];
  v8s wf2[4][4];
#pragma unroll
  for (int ot = 0; ot < 4; ++ot) {
    int row = ohalf * 64 + ot * 16 + l15;
#pragma unroll
    for (int cs = 0; cs < 4; ++cs) {
      wf1[ot][cs] = *(const v8s*)(w1bf + row * 128 + cs * 32 + q4 * 8);
      if constexpr (PASS >= 1) wf2[ot][cs] = *(const v8s*)(w2bf + row * 128 + cs * 32 + q4 * 8);
    }
  }
  if (tid < 64) { sAlpha[tid] = alpha[tid]; sBeta[tid] = beta[tid]; }
  if constexpr (PASS >= 1) sCoef1[tid] = coef1[tid];
  if constexpr (PASS == 2) sCoef2[tid] = coef2[tid];
  if constexpr (PASS <= 1) {
    if (tid < 128) { bnS[tid] = 0.f; bnQ[tid] = 0.f; }
  }
  __syncthreads();

  for (int chunk = blockIdx.x; chunk < NCHUNK; chunk += GGRID) {
    int g0 = chunk * GPC;
    // ---- stage Xs: [g][k][0:64]=normalized grouped, [64:128]=new_pts ----
    {
      int sg = tid >> 7;
      int sk = (tid >> 2) & 31;
      int qr = tid & 3;
      int ggl = g0 + sg;
      int b = ggl >> 10;
      const float* pb = points + (size_t)b * NN * CH;
      int row = (qr < 2) ? kidx[(size_t)ggl * KK + sk] : fidx[ggl];
      int ch0 = (qr & 1) * 32;
      const float* src = pb + (size_t)row * CH + ch0;
      const float* mrow = mean + (size_t)ggl * CH + ch0;
      float rs = rstd[b];
      bool norm = (qr < 2);
      v8s pack[4];
#pragma unroll
      for (int cc = 0; cc < 32; cc += 4) {
        float4 vv = *(const float4*)(src + cc);
        if (norm) {
          float4 mv = *(const float4*)(mrow + cc);
          vv.x = fmaf((vv.x - mv.x) * rs, sAlpha[ch0 + cc + 0], sBeta[ch0 + cc + 0]);
          vv.y = fmaf((vv.y - mv.y) * rs, sAlpha[ch0 + cc + 1], sBeta[ch0 + cc + 1]);
          vv.z = fmaf((vv.z - mv.z) * rs, sAlpha[ch0 + cc + 2], sBeta[ch0 + cc + 2]);
          vv.w = fmaf((vv.w - mv.w) * rs, sAlpha[ch0 + cc + 3], sBeta[ch0 + cc + 3]);
        }
        pack[cc >> 3][(cc & 7) + 0] = f2bf(vv.x);
        pack[cc >> 3][(cc & 7) + 1] = f2bf(vv.y);
        pack[cc >> 3][(cc & 7) + 2] = f2bf(vv.z);
        pack[cc >> 3][(cc & 7) + 3] = f2bf(vv.w);
      }
      short* dst = &Xs[(sg * 32 + sk) * LDW + qr * 32];
#pragma unroll
      for (int p2 = 0; p2 < 4; ++p2) *(v8s*)(dst + p2 * 8) = pack[p2];
    }
    __syncthreads();

    // ---- GEMM1: h1 = W1 * X ----
    v4f acc[4][2] = {};
#pragma unroll
    for (int cs = 0; cs < 4; ++cs) {
      v8s bfr[2];
#pragma unroll
      for (int kt = 0; kt < 2; ++kt)
        bfr[kt] = *(const v8s*)&Xs[(gsel * 32 + kt * 16 + l15) * LDW + cs * 32 + q4 * 8];
#pragma unroll
      for (int ot = 0; ot < 4; ++ot)
#pragma unroll
        for (int kt = 0; kt < 2; ++kt)
          acc[ot][kt] = __builtin_amdgcn_mfma_f32_16x16x32_bf16(wf1[ot][cs], bfr[kt], acc[ot][kt], 0, 0, 0);
    }

    if constexpr (PASS == 0) {
      // BN1 stats of h1
#pragma unroll
      for (int ot = 0; ot < 4; ++ot) {
        float sv[4], sq[4];
#pragma unroll
        for (int r = 0; r < 4; ++r) {
          float a0 = acc[ot][0][r], a1 = acc[ot][1][r];
          sv[r] = a0 + a1;
          sq[r] = fmaf(a0, a0, a1 * a1);
        }
#pragma unroll
        for (int m = 1; m < 16; m <<= 1)
#pragma unroll
          for (int r = 0; r < 4; ++r) {
            sv[r] += __shfl_xor(sv[r], m, 64);
            sq[r] += __shfl_xor(sq[r], m, 64);
          }
        if (l15 == 0) {
          int o0 = ohalf * 64 + ot * 16 + q4 * 4;
#pragma unroll
          for (int r = 0; r < 4; ++r) {
            atomicAdd(&bnS[o0 + r], sv[r]);
            atomicAdd(&bnQ[o0 + r], sq[r]);
          }
        }
      }
    } else {
      // ---- P = lrelu(bn1(h1)) -> Ps ----
#pragma unroll
      for (int ot = 0; ot < 4; ++ot) {
        int o0 = ohalf * 64 + ot * 16 + q4 * 4;
#pragma unroll
        for (int kt = 0; kt < 2; ++kt) {
          v4s pk;
#pragma unroll
          for (int r = 0; r < 4; ++r) {
            float h = fmaf(acc[ot][kt][r], sCoef1[2 * (o0 + r)], sCoef1[2 * (o0 + r) + 1]);
            h = (h >= 0.f) ? h : 0.01f * h;
            pk[r] = f2bf(h);
          }
          *(v4s*)&Ps[(gsel * 32 + kt * 16 + l15) * LDW + o0] = pk;
        }
      }
      __syncthreads();

      // ---- GEMM2: h2 = W2 * P ----
      v4f acc2[4][2] = {};
#pragma unroll
      for (int cs = 0; cs < 4; ++cs) {
        v8s pfr[2];
#pragma unroll
        for (int kt = 0; kt < 2; ++kt)
          pfr[kt] = *(const v8s*)&Ps[(gsel * 32 + kt * 16 + l15) * LDW + cs * 32 + q4 * 8];
#pragma unroll
        for (int ot = 0; ot < 4; ++ot)
#pragma unroll
          for (int kt = 0; kt < 2; ++kt)
            acc2[ot][kt] = __builtin_amdgcn_mfma_f32_16x16x32_bf16(wf2[ot][cs], pfr[kt], acc2[ot][kt], 0, 0, 0);
      }

      if constexpr (PASS == 1) {
        // BN2 stats of h2
#pragma unroll
        for (int ot = 0; ot < 4; ++ot) {
          float sv[4], sq[4];
#pragma unroll
          for (int r = 0; r < 4; ++r) {
            float a0 = acc2[ot][0][r], a1 = acc2[ot][1][r];
            sv[r] = a0 + a1;
            sq[r] = fmaf(a0, a0, a1 * a1);
          }
#pragma unroll
          for (int m = 1; m < 16; m <<= 1)
#pragma unroll
            for (int r = 0; r < 4; ++r) {
              sv[r] += __shfl_xor(sv[r], m, 64);
              sq[r] += __shfl_xor(sq[r], m, 64);
            }
          if (l15 == 0) {
            int o0 = ohalf * 64 + ot * 16 + q4 * 4;
#pragma unroll
            for (int r = 0; r < 4; ++r) {
              atomicAdd(&bnS[o0 + r], sv[r]);
              atomicAdd(&bnQ[o0 + r], sq[r]);
            }
          }
        }
      } else {
        // ---- epilogue: lrelu(bn2(h2) + X) , max over k, store ----
#pragma unroll
        for (int ot = 0; ot < 4; ++ot) {
          int o0 = ohalf * 64 + ot * 16 + q4 * 4;
          float mx[4] = {-1e30f, -1e30f, -1e30f, -1e30f};
#pragma unroll
          for (int kt = 0; kt < 2; ++kt) {
            v4s xv = *(const v4s*)&Xs[(gsel * 32 + kt * 16 + l15) * LDW + o0];
#pragma unroll
            for (int r = 0; r < 4; ++r) {
              float h = fmaf(acc2[ot][kt][r], sCoef2[2 * (o0 + r)], sCoef2[2 * (o0 + r) + 1]);
              float val = h + bf2f(xv[r]);
              val = (val >= 0.f) ? val : 0.01f * val;
              mx[r] = fmaxf(mx[r], val);
            }
          }
#pragma unroll
          for (int m = 1; m < 16; m <<= 1)
#pragma unroll
            for (int r = 0; r < 4; ++r) mx[r] = fmaxf(mx[r], __shfl_xor(mx[r], m, 64));
          if (l15 == 0) {
            float4 o4;
            o4.x = mx[0]; o4.y = mx[1]; o4.z = mx[2]; o4.w = mx[3];
            *(float4*)(out_pooled + (size_t)(g0 + gsel) * DD + o0) = o4;
          }
        }
      }
    }
    __syncthreads();
  }

  if constexpr (PASS <= 1) {
    if (tid < 128) {
      float* bb = bins_out + (((blockIdx.x & 63) * 128 + tid) << 1);
      atomicAdd(bb, bnS[tid]);
      atomicAdd(bb + 1, bnQ[tid]);
    }
  }
}

extern "C" void kernel_launch(void* const* d_in, const int* in_sizes, int n_in,
                              void* d_out, int out_size, void* d_ws, size_t ws_size,
                              hipStream_t stream) {
  const float* xyz    = (const float*)d_in[0];
  const float* points = (const float*)d_in[1];
  const float* alpha  = (const float*)d_in[2];
  const float* beta   = (const float*)d_in[3];
  const float* w1     = (const float*)d_in[4];
  const float* g1     = (const float*)d_in[6];
  const float* be1    = (const float*)d_in[7];
  const float* w2     = (const float*)d_in[8];
  const float* g2     = (const float*)d_in[10];
  const float* be2    = (const float*)d_in[11];
  float* out = (float*)d_out;

  char* w = (char*)d_ws;
  int* fps_i   = (int*)(w + OFF_FPSIDX);
  int* knn_i   = (int*)(w + OFF_KNN);
  float* meanp = (float*)(w + OFF_MEAN);
  float* varb  = (float*)(w + OFF_VARB);
  float* bins1 = (float*)(w + OFF_BINS1);
  float* bins2 = (float*)(w + OFF_BINS2);
  float* rstdp = (float*)(w + OFF_RSTD);
  float* coef1 = (float*)(w + OFF_COEF1);
  float* coef2 = (float*)(w + OFF_COEF2);
  short* w1b   = (short*)(w + OFF_W1BF);
  short* w2b   = (short*)(w + OFF_W2BF);
  float* xyzT  = (float*)(w + OFF_XYZT);

  hipMemsetAsync(w + MEMSET_OFF, 0, MEMSET_LEN, stream);
  xpose_kernel<<<256, 256, 0, stream>>>(xyz, xyzT);
  cvtw_kernel<<<64, 256, 0, stream>>>(w1, w2, w1b, w2b);
  fps_kernel<<<BB, 512, 0, stream>>>(xyzT, fps_i, out);
  knn_kernel<<<(BB * SS) / 4, 256, 0, stream>>>(xyzT, fps_i, knn_i);
  meanvar_kernel<<<(BB * SS) / 4, 256, 0, stream>>>(points, knn_i, meanp, varb);
  fin_std_kernel<<<1, 64, 0, stream>>>(varb, rstdp);
  gemm_pass<0><<<GGRID, 256, 0, stream>>>(points, knn_i, fps_i, meanp, rstdp, alpha, beta,
                                          w1b, w2b, coef1, coef2, bins1, nullptr);
  fin_bn_kernel<<<1, 128, 0, stream>>>(bins1, g1, be1, coef1);
  gemm_pass<1><<<GGRID, 256, 0, stream>>>(points, knn_i, fps_i, meanp, rstdp, alpha, beta,
                                          w1b, w2b, coef1, coef2, bins2, nullptr);
  fin_bn_kernel<<<1, 128, 0, stream>>>(bins2, g2, be2, coef2);
  gemm_pass<2><<<GGRID, 256, 0, stream>>>(points, knn_i, fps_i, meanp, rstdp, alpha, beta,
                                          w1b, w2b, coef1, coef2, nullptr, out + (size_t)BB * SS * 3);
}

// Round 6
// 1299.457 us; speedup vs baseline: 2.3061x; 1.1625x over previous
//
#include <hip/hip_runtime.h>

#define DI __device__ __forceinline__

typedef __attribute__((ext_vector_type(8))) short v8s;
typedef __attribute__((ext_vector_type(4))) short v4s;
typedef __attribute__((ext_vector_type(4))) float v4f;
typedef unsigned long long u64;

constexpr int BB = 16, NN = 4096, CH = 64, SS = 1024, KK = 32, DD = 128;
constexpr int LDW = 136;                 // LDS row stride in shorts (pad: 16B-aligned rows, <=2-way banks)
constexpr int GPC = 2;                   // groups per chunk in gemm passes
constexpr int NCHUNK = (BB * SS) / GPC;  // 8192
constexpr int GGRID = 512;

// ---- ws layout (bytes) ----
constexpr size_t OFF_FPSIDX = 0;         // int[16384]
constexpr size_t OFF_KNN    = 65536;     // int[524288]
constexpr size_t OFF_MEAN   = 2162688;   // float[1048576]
constexpr size_t OFF_VARB   = 6356992;   // float[1024]
constexpr size_t OFF_BINS1  = 6361088;   // float[16384]  [64][128][2]
constexpr size_t OFF_BINS2  = 6426624;   // float[16384]
constexpr size_t OFF_RSTD   = 6492160;   // float[16]
constexpr size_t OFF_COEF1  = 6492224;   // float[256]
constexpr size_t OFF_COEF2  = 6493248;   // float[256]
constexpr size_t OFF_W1BF   = 6494272;   // short[16384]
constexpr size_t OFF_W2BF   = 6527040;   // short[16384]
constexpr size_t OFF_XYZT   = 6559808;   // float[196608]  [B][3][N]
constexpr size_t MEMSET_OFF = OFF_VARB;
constexpr size_t MEMSET_LEN = 4096 + 65536 + 65536;

DI short f2bf(float f) {
  unsigned u = __float_as_uint(f);
  u = (u + 0x7fffu + ((u >> 16) & 1u)) >> 16;
  return (short)u;
}
DI float bf2f(short s) { return __uint_as_float(((unsigned)(unsigned short)s) << 16); }

// ---------------- xyz transpose: [B][N][3] -> [B][3][N] ----------------
__global__ void xpose_kernel(const float* __restrict__ xyz, float* __restrict__ xyzT) {
  int i = blockIdx.x * 256 + threadIdx.x;  // < B*N
  int b = i >> 12, n = i & 4095;
  const float* s = xyz + (size_t)i * 3;
  float* d = xyzT + (size_t)b * 3 * NN + n;
  d[0] = s[0]; d[NN] = s[1]; d[2 * NN] = s[2];
}

// ---------------- weight f32 -> bf16 ----------------
__global__ void cvtw_kernel(const float* __restrict__ w1, const float* __restrict__ w2,
                            short* __restrict__ w1b, short* __restrict__ w2b) {
  int i = blockIdx.x * 256 + threadIdx.x;  // < 16384
  w1b[i] = f2bf(w1[i]);
  w2b[i] = f2bf(w2[i]);
}

// 64-bit DPP shuffle within a row of 16 lanes
template <int CTRL>
DI u64 dpp_u64(u64 x) {
  int lo = __builtin_amdgcn_update_dpp(0, (int)(unsigned)x, CTRL, 0xf, 0xf, true);
  int hi = __builtin_amdgcn_update_dpp(0, (int)(unsigned)(x >> 32), CTRL, 0xf, 0xf, true);
  return ((u64)(unsigned)hi << 32) | (unsigned)lo;
}
template <int CTRL>
DI void dpp_umax_stage(u64& x) {
  u64 o = dpp_u64<CTRL>(x);
  if (o > x) x = o;
}
DI u64 readlane_u64(u64 x, int l) {
  unsigned lo = (unsigned)__builtin_amdgcn_readlane((int)(unsigned)x, l);
  unsigned hi = (unsigned)__builtin_amdgcn_readlane((int)(unsigned)(x >> 32), l);
  return ((u64)hi << 32) | lo;
}

// ---------------- FPS v5: u64-key argmax, branchless exact-f64 chain ----------------
// 16 blocks x 512 threads (8 waves), 8 points/lane (pt k -> global k*512+tid).
// Chain: dot-form f64 (clamped at 0), unconditional, registers only.
// Reduce: single u64 key = (bits(m64) & ~0xFFF) | (4095 - gi).  For positive
// doubles the bit pattern is order-monotone, so u64-max == f64-argmax with
// min-index tie-break (jnp.argmax semantics). 12-bit mantissa clobber = 2^-40
// relative quantization -- below any generic distance gap. No cvt, no ballot,
// no tie fallback. One barrier + one u64 partial exchange per round.
__global__ __launch_bounds__(512, 2) void fps_kernel(const float* __restrict__ xyzT,
                                                     int* __restrict__ fps_idx,
                                                     float* __restrict__ out_xyz) {
  int b = blockIdx.x, tid = threadIdx.x;
  int wave = tid >> 6, lane = tid & 63;
  const float* bx = xyzT + (size_t)b * 3 * NN;
  const float* by = bx + NN;
  const float* bz = bx + 2 * NN;
  __shared__ float4 s_xyzw[NN];  // 64 KB coords broadcast
  __shared__ int s_fidx[SS];     // 4 KB selected indices
  __shared__ u64 s_pk[2][8];     // wave partial keys (dbuf by round parity)

  double px64[8], py64[8], pz64[8], pp64[8], m64[8];
  int tagbase = 4095 - tid;  // tag for point k: tagbase - k*512 == 4095 - gi
#pragma unroll
  for (int k = 0; k < 8; ++k) {
    int gi = k * 512 + tid;
    float x = bx[gi], y = by[gi], z = bz[gi];
    s_xyzw[gi] = make_float4(x, y, z, 0.f);
    px64[k] = (double)x; py64[k] = (double)y; pz64[k] = (double)z;
    pp64[k] = fma(px64[k], px64[k], fma(py64[k], py64[k], pz64[k] * pz64[k]));
    m64[k] = 1e10;
  }
  if (tid == 0) s_fidx[0] = 0;
  __syncthreads();
  float4 c0 = s_xyzw[0];
  double cx = (double)c0.x, cy = (double)c0.y, cz = (double)c0.z;

  for (int j = 1; j < SS; ++j) {
    double cx2 = -2.0 * cx, cy2 = -2.0 * cy, cz2 = -2.0 * cz;
    double cc = fma(cx, cx, fma(cy, cy, cz * cz));
    u64 best = 0;
#pragma unroll
    for (int k = 0; k < 8; ++k) {
      // d = |p-c|^2 via dot-form; clamp: self-point rounds to ~±1e-15 and a
      // negative would set the sign bit and poison the key ordering.
      double d = fma(px64[k], cx2, fma(py64[k], cy2, fma(pz64[k], cz2, pp64[k] + cc)));
      d = fmax(d, 0.0);
      m64[k] = fmin(m64[k], d);
      u64 key = ((u64)__double_as_longlong(m64[k]) & ~0xFFFull) | (u64)(tagbase - k * 512);
      if (key > best) best = key;
    }
    // wave max: 4 DPP stages within row-of-16, then cross-row via readlane
    dpp_umax_stage<0xB1>(best);   // quad_perm [1,0,3,2] : xor 1
    dpp_umax_stage<0x4E>(best);   // quad_perm [2,3,0,1] : xor 2
    dpp_umax_stage<0x141>(best);  // ROW_HALF_MIRROR     : xor 7
    dpp_umax_stage<0x140>(best);  // ROW_MIRROR          : xor 15
    u64 w0 = readlane_u64(best, 0);
    u64 w1 = readlane_u64(best, 16);
    u64 w2 = readlane_u64(best, 32);
    u64 w3 = readlane_u64(best, 48);
    u64 bw = w0;
    if (w1 > bw) bw = w1;
    if (w2 > bw) bw = w2;
    if (w3 > bw) bw = w3;
    if (lane == 0) s_pk[j & 1][wave] = bw;
    __syncthreads();
    // cross-wave: uniform scan of 8 u64 partials
    u64 bk = s_pk[j & 1][0];
#pragma unroll
    for (int w = 1; w < 8; ++w) {
      u64 v = s_pk[j & 1][w];
      if (v > bk) bk = v;
    }
    int fi = 4095 - (int)(bk & 0xFFFull);
    float4 cw = s_xyzw[fi];  // uniform-address LDS broadcast
    cx = (double)cw.x; cy = (double)cw.y; cz = (double)cw.z;
    if (tid == 0) s_fidx[j] = fi;
  }
  __syncthreads();
  // ---- write out fps_idx + new_xyz (once, after the serial loop) ----
  for (int t = tid; t < SS; t += 512) {
    int idx = s_fidx[t];
    fps_idx[b * SS + t] = idx;
    float4 p = s_xyzw[idx];
    out_xyz[((size_t)b * SS + t) * 3 + 0] = p.x;
    out_xyz[((size_t)b * SS + t) * 3 + 1] = p.y;
    out_xyz[((size_t)b * SS + t) * 3 + 2] = p.z;
  }
}

// ---------------- kNN v2: radix tau + u64-key rank scan ----------------
// One wave per query. f32 distances; tau = exact 32nd-smallest of the 64
// per-lane minima via 31-step radix descent on float bits (monotone u32),
// inflated for f32-vs-f64 safety (superset guarantee: >=32 distinct points
// <= tau). Candidates' indices compacted to LDS; exact-f64 keys
// (bits(d64) & ~0xFFF) | n  =>  u64-min order == (d64, n) lexicographic ==
// top_k stability. Rank = #{key < mine} via broadcast LDS reads (no serial
// selection rounds, no f64 shuffles, no barriers -- wave-private LDS).
__global__ __launch_bounds__(256) void knn_kernel(const float* __restrict__ xyzT,
                                                  const int* __restrict__ fps_idx,
                                                  int* __restrict__ knn_idx) {
  int wave = threadIdx.x >> 6, lane = threadIdx.x & 63;
  int q = blockIdx.x * 4 + wave, b = q >> 10;
  const float* bx = xyzT + (size_t)b * 3 * NN;
  const float* by = bx + NN;
  const float* bz = bx + 2 * NN;
  int qi = fps_idx[q];
  float qx = bx[qi], qy = by[qi], qz = bz[qi];
  float d[64];
  float lmin = 1e30f;
#pragma unroll
  for (int j = 0; j < 64; ++j) {
    int n = j * 64 + lane;
    float dx = bx[n] - qx, dy = by[n] - qy, dz = bz[n] - qz;
    d[j] = fmaf(dx, dx, fmaf(dy, dy, dz * dz));
    lmin = fminf(lmin, d[j]);
  }
  // ---- 32nd smallest of the 64 lane minima: radix descent on float bits ----
  // res ends as the largest u with #{lmin < u} < 32, i.e. the 32nd smallest.
  unsigned lb = __float_as_uint(lmin);
  unsigned res = 0;
#pragma unroll
  for (int bit = 30; bit >= 0; --bit) {
    unsigned t = res | (1u << bit);
    int c = __popcll(__ballot(lb < t));
    res = (c < 32) ? t : res;
  }
  float tau = __uint_as_float(res) * 1.00001f + 1e-20f;  // margin covers f32 dist err

  __shared__ int ci[4][512];
  __shared__ u64 ck[4][512];
  // ---- compact candidate indices (ballot prefix) ----
  int cnt = 0;
#pragma unroll
  for (int j = 0; j < 64; ++j) {
    bool pred = (d[j] <= tau);
    unsigned long long mask = __ballot(pred);
    if (pred) {
      int pos = cnt + __popcll(mask & ((1ull << lane) - 1ull));
      if (pos < 512) ci[wave][pos] = j * 64 + lane;
    }
    cnt += __popcll(mask);
  }
  if (cnt > 512) cnt = 512;
  // ---- exact f64 keys for candidates (scattered L2 reads, ~1/lane) ----
  double qx64 = (double)qx, qy64 = (double)qy, qz64 = (double)qz;
  for (int p = lane; p < cnt; p += 64) {
    int n = ci[wave][p];
    double dx = (double)bx[n] - qx64;
    double dy = (double)by[n] - qy64;
    double dz = (double)bz[n] - qz64;
    double d64 = fma(dx, dx, fma(dy, dy, dz * dz));
    ck[wave][p] = ((u64)__double_as_longlong(d64) & ~0xFFFull) | (u64)n;
  }
  // ---- rank scan: broadcast reads, unique ranks 0..cnt-1 ----
  for (int p = lane; p < cnt; p += 64) {
    u64 mykey = ck[wave][p];
    int rank = 0;
    int r = 0;
    for (; r + 4 <= cnt; r += 4) {
      u64 k0 = ck[wave][r + 0], k1 = ck[wave][r + 1];
      u64 k2 = ck[wave][r + 2], k3 = ck[wave][r + 3];
      rank += (k0 < mykey) + (k1 < mykey) + (k2 < mykey) + (k3 < mykey);
    }
    for (; r < cnt; ++r) rank += (ck[wave][r] < mykey) ? 1 : 0;
    if (rank < KK) knn_idx[(size_t)q * KK + rank] = (int)(mykey & 0xFFFull);
  }
}

// ---------------- per-group mean over K + per-batch sum of diff^2 ----------------
__global__ __launch_bounds__(256) void meanvar_kernel(const float* __restrict__ points,
                                                      const int* __restrict__ kidx,
                                                      float* __restrict__ mean_out,
                                                      float* __restrict__ var_bins) {
  int wave = threadIdx.x >> 6, lane = threadIdx.x & 63;
  int g = blockIdx.x * 4 + wave;  // global group
  int b = g >> 10;
  const float* pb = points + (size_t)b * NN * CH;
  const int* idx = kidx + (size_t)g * KK;
  float s1 = 0.f, s2 = 0.f;
#pragma unroll
  for (int k = 0; k < KK; ++k) {
    float x = pb[(size_t)idx[k] * CH + lane];
    s1 += x;
    s2 = fmaf(x, x, s2);
  }
  float m = s1 * (1.0f / 32.0f);
  mean_out[(size_t)g * CH + lane] = m;
  float part = s2 - s1 * m;  // sum_k (x-m)^2 (exact algebra: 32*m == s1)
#pragma unroll
  for (int mm = 1; mm < 64; mm <<= 1) part += __shfl_xor(part, mm, 64);
  if (lane == 0) atomicAdd(&var_bins[b * 64 + (g & 63)], part);
}

__global__ void fin_std_kernel(const float* __restrict__ bins, float* __restrict__ rstd) {
  int t = threadIdx.x;
  if (t < BB) {
    float s = 0.f;
    for (int i = 0; i < 64; ++i) s += bins[t * 64 + i];
    float var = s / (float)(SS * KK * CH - 1);
    rstd[t] = 1.0f / (sqrtf(var) + 1e-5f);
  }
}

__global__ void fin_bn_kernel(const float* __restrict__ bins, const float* __restrict__ g,
                              const float* __restrict__ be, float* __restrict__ coef) {
  int o = threadIdx.x;  // < 128
  float s = 0.f, qq = 0.f;
  for (int bin = 0; bin < 64; ++bin) {
    s += bins[(bin * 128 + o) * 2 + 0];
    qq += bins[(bin * 128 + o) * 2 + 1];
  }
  constexpr float invM = 1.0f / (float)(BB * SS * KK);
  float mean = s * invM;
  float var = qq * invM - mean * mean;
  if (var < 0.f) var = 0.f;
  float sc = g[o] / sqrtf(var + 1e-5f);
  coef[2 * o] = sc;
  coef[2 * o + 1] = be[o] - mean * sc;
}

// ---------------- GEMM passes ----------------
// PASS 0: X->h1, accumulate BN1 stats.
// PASS 1: X->h1->P->h2, accumulate BN2 stats.
// PASS 2: X->h1->P->h2, BN2 + residual + lrelu + maxpool -> out.
template <int PASS>
__global__ __launch_bounds__(256, 2) void gemm_pass(
    const float* __restrict__ points, const int* __restrict__ kidx, const int* __restrict__ fidx,
    const float* __restrict__ mean, const float* __restrict__ rstd,
    const float* __restrict__ alpha, const float* __restrict__ beta,
    const short* __restrict__ w1bf, const short* __restrict__ w2bf,
    const float* __restrict__ coef1, const float* __restrict__ coef2,
    float* __restrict__ bins_out, float* __restrict__ out_pooled) {
  __shared__ short Xs[GPC * 32 * LDW];
  __shared__ short Ps[(PASS >= 1) ? (GPC * 32 * LDW) : 8];
  __shared__ float sAlpha[64], sBeta[64];
  __shared__ float sCoef1[256], sCoef2[256];
  __shared__ float bnS[128], bnQ[128];

  int tid = threadIdx.x;
  int wave = tid >> 6, lane = tid & 63;
  int q4 = lane >> 4, l15 = lane & 15;
  int ohalf = wave & 1, gsel = wave >> 1;

  // W fragments -> registers
  v8s wf1[4][4];
  v8s wf2[4][4];
#pragma unroll
  for (int ot = 0; ot < 4; ++ot) {
    int row = ohalf * 64 + ot * 16 + l15;
#pragma unroll
    for (int cs = 0; cs < 4; ++cs) {
      wf1[ot][cs] = *(const v8s*)(w1bf + row * 128 + cs * 32 + q4 * 8);
      if constexpr (PASS >= 1) wf2[ot][cs] = *(const v8s*)(w2bf + row * 128 + cs * 32 + q4 * 8);
    }
  }
  if (tid < 64) { sAlpha[tid] = alpha[tid]; sBeta[tid] = beta[tid]; }
  if constexpr (PASS >= 1) sCoef1[tid] = coef1[tid];
  if constexpr (PASS == 2) sCoef2[tid] = coef2[tid];
  if constexpr (PASS <= 1) {
    if (tid < 128) { bnS[tid] = 0.f; bnQ[tid] = 0.f; }
  }
  __syncthreads();

  for (int chunk = blockIdx.x; chunk < NCHUNK; chunk += GGRID) {
    int g0 = chunk * GPC;
    // ---- stage Xs: [g][k][0:64]=normalized grouped, [64:128]=new_pts ----
    {
      int sg = tid >> 7;
      int sk = (tid >> 2) & 31;
      int qr = tid & 3;
      int ggl = g0 + sg;
      int b = ggl >> 10;
      const float* pb = points + (size_t)b * NN * CH;
      int row = (qr < 2) ? kidx[(size_t)ggl * KK + sk] : fidx[ggl];
      int ch0 = (qr & 1) * 32;
      const float* src = pb + (size_t)row * CH + ch0;
      const float* mrow = mean + (size_t)ggl * CH + ch0;
      float rs = rstd[b];
      bool norm = (qr < 2);
      v8s pack[4];
#pragma unroll
      for (int cc = 0; cc < 32; cc += 4) {
        float4 vv = *(const float4*)(src + cc);
        if (norm) {
          float4 mv = *(const float4*)(mrow + cc);
          vv.x = fmaf((vv.x - mv.x) * rs, sAlpha[ch0 + cc + 0], sBeta[ch0 + cc + 0]);
          vv.y = fmaf((vv.y - mv.y) * rs, sAlpha[ch0 + cc + 1], sBeta[ch0 + cc + 1]);
          vv.z = fmaf((vv.z - mv.z) * rs, sAlpha[ch0 + cc + 2], sBeta[ch0 + cc + 2]);
          vv.w = fmaf((vv.w - mv.w) * rs, sAlpha[ch0 + cc + 3], sBeta[ch0 + cc + 3]);
        }
        pack[cc >> 3][(cc & 7) + 0] = f2bf(vv.x);
        pack[cc >> 3][(cc & 7) + 1] = f2bf(vv.y);
        pack[cc >> 3][(cc & 7) + 2] = f2bf(vv.z);
        pack[cc >> 3][(cc & 7) + 3] = f2bf(vv.w);
      }
      short* dst = &Xs[(sg * 32 + sk) * LDW + qr * 32];
#pragma unroll
      for (int p2 = 0; p2 < 4; ++p2) *(v8s*)(dst + p2 * 8) = pack[p2];
    }
    __syncthreads();

    // ---- GEMM1: h1 = W1 * X ----
    v4f acc[4][2] = {};
#pragma unroll
    for (int cs = 0; cs < 4; ++cs) {
      v8s bfr[2];
#pragma unroll
      for (int kt = 0; kt < 2; ++kt)
        bfr[kt] = *(const v8s*)&Xs[(gsel * 32 + kt * 16 + l15) * LDW + cs * 32 + q4 * 8];
#pragma unroll
      for (int ot = 0; ot < 4; ++ot)
#pragma unroll
        for (int kt = 0; kt < 2; ++kt)
          acc[ot][kt] = __builtin_amdgcn_mfma_f32_16x16x32_bf16(wf1[ot][cs], bfr[kt], acc[ot][kt], 0, 0, 0);
    }

    if constexpr (PASS == 0) {
      // BN1 stats of h1
#pragma unroll
      for (int ot = 0; ot < 4; ++ot) {
        float sv[4], sq[4];
#pragma unroll
        for (int r = 0; r < 4; ++r) {
          float a0 = acc[ot][0][r], a1 = acc[ot][1][r];
          sv[r] = a0 + a1;
          sq[r] = fmaf(a0, a0, a1 * a1);
        }
#pragma unroll
        for (int m = 1; m < 16; m <<= 1)
#pragma unroll
          for (int r = 0; r < 4; ++r) {
            sv[r] += __shfl_xor(sv[r], m, 64);
            sq[r] += __shfl_xor(sq[r], m, 64);
          }
        if (l15 == 0) {
          int o0 = ohalf * 64 + ot * 16 + q4 * 4;
#pragma unroll
          for (int r = 0; r < 4; ++r) {
            atomicAdd(&bnS[o0 + r], sv[r]);
            atomicAdd(&bnQ[o0 + r], sq[r]);
          }
        }
      }
    } else {
      // ---- P = lrelu(bn1(h1)) -> Ps ----
#pragma unroll
      for (int ot = 0; ot < 4; ++ot) {
        int o0 = ohalf * 64 + ot * 16 + q4 * 4;
#pragma unroll
        for (int kt = 0; kt < 2; ++kt) {
          v4s pk;
#pragma unroll
          for (int r = 0; r < 4; ++r) {
            float h = fmaf(acc[ot][kt][r], sCoef1[2 * (o0 + r)], sCoef1[2 * (o0 + r) + 1]);
            h = (h >= 0.f) ? h : 0.01f * h;
            pk[r] = f2bf(h);
          }
          *(v4s*)&Ps[(gsel * 32 + kt * 16 + l15) * LDW + o0] = pk;
        }
      }
      __syncthreads();

      // ---- GEMM2: h2 = W2 * P ----
      v4f acc2[4][2] = {};
#pragma unroll
      for (int cs = 0; cs < 4; ++cs) {
        v8s pfr[2];
#pragma unroll
        for (int kt = 0; kt < 2; ++kt)
          pfr[kt] = *(const v8s*)&Ps[(gsel * 32 + kt * 16 + l15) * LDW + cs * 32 + q4 * 8];
#pragma unroll
        for (int ot = 0; ot < 4; ++ot)
#pragma unroll
          for (int kt = 0; kt < 2; ++kt)
            acc2[ot][kt] = __builtin_amdgcn_mfma_f32_16x16x32_bf16(wf2[ot][cs], pfr[kt], acc2[ot][kt], 0, 0, 0);
      }

      if constexpr (PASS == 1) {
        // BN2 stats of h2
#pragma unroll
        for (int ot = 0; ot < 4; ++ot) {
          float sv[4], sq[4];
#pragma unroll
          for (int r = 0; r < 4; ++r) {
            float a0 = acc2[ot][0][r], a1 = acc2[ot][1][r];
            sv[r] = a0 + a1;
            sq[r] = fmaf(a0, a0, a1 * a1);
          }
#pragma unroll
          for (int m = 1; m < 16; m <<= 1)
#pragma unroll
            for (int r = 0; r < 4; ++r) {
              sv[r] += __shfl_xor(sv[r], m, 64);
              sq[r] += __shfl_xor(sq[r], m, 64);
            }
          if (l15 == 0) {
            int o0 = ohalf * 64 + ot * 16 + q4 * 4;
#pragma unroll
            for (int r = 0; r < 4; ++r) {
              atomicAdd(&bnS[o0 + r], sv[r]);
              atomicAdd(&bnQ[o0 + r], sq[r]);
            }
          }
        }
      } else {
        // ---- epilogue: lrelu(bn2(h2) + X) , max over k, store ----
#pragma unroll
        for (int ot = 0; ot < 4; ++ot) {
          int o0 = ohalf * 64 + ot * 16 + q4 * 4;
          float mx[4] = {-1e30f, -1e30f, -1e30f, -1e30f};
#pragma unroll
          for (int kt = 0; kt < 2; ++kt) {
            v4s xv = *(const v4s*)&Xs[(gsel * 32 + kt * 16 + l15) * LDW + o0];
#pragma unroll
            for (int r = 0; r < 4; ++r) {
              float h = fmaf(acc2[ot][kt][r], sCoef2[2 * (o0 + r)], sCoef2[2 * (o0 + r) + 1]);
              float val = h + bf2f(xv[r]);
              val = (val >= 0.f) ? val : 0.01f * val;
              mx[r] = fmaxf(mx[r], val);
            }
          }
#pragma unroll
          for (int m = 1; m < 16; m <<= 1)
#pragma unroll
            for (int r = 0; r < 4; ++r) mx[r] = fmaxf(mx[r], __shfl_xor(mx[r], m, 64));
          if (l15 == 0) {
            float4 o4;
            o4.x = mx[0]; o4.y = mx[1]; o4.z = mx[2]; o4.w = mx[3];
            *(float4*)(out_pooled + (size_t)(g0 + gsel) * DD + o0) = o4;
          }
        }
      }
    }
    __syncthreads();
  }

  if constexpr (PASS <= 1) {
    if (tid < 128) {
      float* bb = bins_out + (((blockIdx.x & 63) * 128 + tid) << 1);
      atomicAdd(bb, bnS[tid]);
      atomicAdd(bb + 1, bnQ[tid]);
    }
  }
}

extern "C" void kernel_launch(void* const* d_in, const int* in_sizes, int n_in,
                              void* d_out, int out_size, void* d_ws, size_t ws_size,
                              hipStream_t stream) {
  const float* xyz    = (const float*)d_in[0];
  const float* points = (const float*)d_in[1];
  const float* alpha  = (const float*)d_in[2];
  const float* beta   = (const float*)d_in[3];
  const float* w1     = (const float*)d_in[4];
  const float* g1     = (const float*)d_in[6];
  const float* be1    = (const float*)d_in[7];
  const float* w2     = (const float*)d_in[8];
  const float* g2     = (const float*)d_in[10];
  const float* be2    = (const float*)d_in[11];
  float* out = (float*)d_out;

  char* w = (char*)d_ws;
  int* fps_i   = (int*)(w + OFF_FPSIDX);
  int* knn_i   = (int*)(w + OFF_KNN);
  float* meanp = (float*)(w + OFF_MEAN);
  float* varb  = (float*)(w + OFF_VARB);
  float* bins1 = (float*)(w + OFF_BINS1);
  float* bins2 = (float*)(w + OFF_BINS2);
  float* rstdp = (float*)(w + OFF_RSTD);
  float* coef1 = (float*)(w + OFF_COEF1);
  float* coef2 = (float*)(w + OFF_COEF2);
  short* w1b   = (short*)(w + OFF_W1BF);
  short* w2b   = (short*)(w + OFF_W2BF);
  float* xyzT  = (float*)(w + OFF_XYZT);

  hipMemsetAsync(w + MEMSET_OFF, 0, MEMSET_LEN, stream);
  xpose_kernel<<<256, 256, 0, stream>>>(xyz, xyzT);
  cvtw_kernel<<<64, 256, 0, stream>>>(w1, w2, w1b, w2b);
  fps_kernel<<<BB, 512, 0, stream>>>(xyzT, fps_i, out);
  knn_kernel<<<(BB * SS) / 4, 256, 0, stream>>>(xyzT, fps_i, knn_i);
  meanvar_kernel<<<(BB * SS) / 4, 256, 0, stream>>>(points, knn_i, meanp, varb);
  fin_std_kernel<<<1, 64, 0, stream>>>(varb, rstdp);
  gemm_pass<0><<<GGRID, 256, 0, stream>>>(points, knn_i, fps_i, meanp, rstdp, alpha, beta,
                                          w1b, w2b, coef1, coef2, bins1, nullptr);
  fin_bn_kernel<<<1, 128, 0, stream>>>(bins1, g1, be1, coef1);
  gemm_pass<1><<<GGRID, 256, 0, stream>>>(points, knn_i, fps_i, meanp, rstdp, alpha, beta,
                                          w1b, w2b, coef1, coef2, bins2, nullptr);
  fin_bn_kernel<<<1, 128, 0, stream>>>(bins2, g2, be2, coef2);
  gemm_pass<2><<<GGRID, 256, 0, stream>>>(points, knn_i, fps_i, meanp, rstdp, alpha, beta,
                                          w1b, w2b, coef1, coef2, nullptr, out + (size_t)BB * SS * 3);
}

// Round 7
// 1275.330 us; speedup vs baseline: 2.3497x; 1.0189x over previous
//
#include <hip/hip_runtime.h>

#define DI __device__ __forceinline__

typedef __attribute__((ext_vector_type(8))) short v8s;
typedef __attribute__((ext_vector_type(4))) short v4s;
typedef __attribute__((ext_vector_type(4))) float v4f;
typedef unsigned long long u64;

constexpr int BB = 16, NN = 4096, CH = 64, SS = 1024, KK = 32, DD = 128;
constexpr int LDW = 136;                 // LDS row stride in shorts (pad: 16B-aligned rows, <=2-way banks)
constexpr int GPC = 2;                   // groups per chunk in gemm passes
constexpr int GGRID = 512;

// ---- ws layout (bytes) ----
constexpr size_t OFF_FPSIDX = 0;         // int[16384]
constexpr size_t OFF_KNN    = 65536;     // int[524288]
constexpr size_t OFF_MEAN   = 2162688;   // float[1048576]
constexpr size_t OFF_VARB   = 6356992;   // float[1024]
constexpr size_t OFF_BINS1  = 6361088;   // float[16384]  [64][128][2]
constexpr size_t OFF_BINS2  = 6426624;   // float[16384]
constexpr size_t OFF_RSTD   = 6492160;   // float[16]
constexpr size_t OFF_COEF1  = 6492224;   // float[256]
constexpr size_t OFF_COEF2  = 6493248;   // float[256]
constexpr size_t OFF_W1BF   = 6494272;   // short[16384]
constexpr size_t OFF_W2BF   = 6527040;   // short[16384]
constexpr size_t OFF_XYZT   = 6559808;   // float[196608]  [B][3][N]
constexpr size_t MEMSET_OFF = OFF_VARB;
constexpr size_t MEMSET_LEN = 4096 + 65536 + 65536;

DI short f2bf(float f) {
  unsigned u = __float_as_uint(f);
  u = (u + 0x7fffu + ((u >> 16) & 1u)) >> 16;
  return (short)u;
}
DI float bf2f(short s) { return __uint_as_float(((unsigned)(unsigned short)s) << 16); }

// ---------------- xyz transpose: [B][N][3] -> [B][3][N] ----------------
__global__ void xpose_kernel(const float* __restrict__ xyz, float* __restrict__ xyzT) {
  int i = blockIdx.x * 256 + threadIdx.x;  // < B*N
  int b = i >> 12, n = i & 4095;
  const float* s = xyz + (size_t)i * 3;
  float* d = xyzT + (size_t)b * 3 * NN + n;
  d[0] = s[0]; d[NN] = s[1]; d[2 * NN] = s[2];
}

// ---------------- weight f32 -> bf16 ----------------
__global__ void cvtw_kernel(const float* __restrict__ w1, const float* __restrict__ w2,
                            short* __restrict__ w1b, short* __restrict__ w2b) {
  int i = blockIdx.x * 256 + threadIdx.x;  // < 16384
  w1b[i] = f2bf(w1[i]);
  w2b[i] = f2bf(w2[i]);
}

// 64-bit DPP shuffle within a row of 16 lanes
template <int CTRL>
DI u64 dpp_u64(u64 x) {
  int lo = __builtin_amdgcn_update_dpp(0, (int)(unsigned)x, CTRL, 0xf, 0xf, true);
  int hi = __builtin_amdgcn_update_dpp(0, (int)(unsigned)(x >> 32), CTRL, 0xf, 0xf, true);
  return ((u64)(unsigned)hi << 32) | (unsigned)lo;
}
template <int CTRL>
DI void dpp_umax_stage(u64& x) {
  u64 o = dpp_u64<CTRL>(x);
  if (o > x) x = o;
}
DI u64 readlane_u64(u64 x, int l) {
  unsigned lo = (unsigned)__builtin_amdgcn_readlane((int)(unsigned)x, l);
  unsigned hi = (unsigned)__builtin_amdgcn_readlane((int)(unsigned)(x >> 32), l);
  return ((u64)hi << 32) | lo;
}

// ---------------- FPS v5: u64-key argmax, branchless exact-f64 chain ----------------
// 16 blocks x 512 threads (8 waves), 8 points/lane (pt k -> global k*512+tid).
// Chain: dot-form f64 (clamped at 0), unconditional, registers only.
// Reduce: single u64 key = (bits(m64) & ~0xFFF) | (4095 - gi).  For positive
// doubles the bit pattern is order-monotone, so u64-max == f64-argmax with
// min-index tie-break (jnp.argmax semantics). 12-bit mantissa clobber = 2^-40
// relative quantization -- below any generic distance gap. No cvt, no ballot,
// no tie fallback. One barrier + one u64 partial exchange per round.
__global__ __launch_bounds__(512, 2) void fps_kernel(const float* __restrict__ xyzT,
                                                     int* __restrict__ fps_idx,
                                                     float* __restrict__ out_xyz) {
  int b = blockIdx.x, tid = threadIdx.x;
  int wave = tid >> 6, lane = tid & 63;
  const float* bx = xyzT + (size_t)b * 3 * NN;
  const float* by = bx + NN;
  const float* bz = bx + 2 * NN;
  __shared__ float4 s_xyzw[NN];  // 64 KB coords broadcast
  __shared__ int s_fidx[SS];     // 4 KB selected indices
  __shared__ u64 s_pk[2][8];     // wave partial keys (dbuf by round parity)

  double px64[8], py64[8], pz64[8], pp64[8], m64[8];
  int tagbase = 4095 - tid;  // tag for point k: tagbase - k*512 == 4095 - gi
#pragma unroll
  for (int k = 0; k < 8; ++k) {
    int gi = k * 512 + tid;
    float x = bx[gi], y = by[gi], z = bz[gi];
    s_xyzw[gi] = make_float4(x, y, z, 0.f);
    px64[k] = (double)x; py64[k] = (double)y; pz64[k] = (double)z;
    pp64[k] = fma(px64[k], px64[k], fma(py64[k], py64[k], pz64[k] * pz64[k]));
    m64[k] = 1e10;
  }
  if (tid == 0) s_fidx[0] = 0;
  __syncthreads();
  float4 c0 = s_xyzw[0];
  double cx = (double)c0.x, cy = (double)c0.y, cz = (double)c0.z;

  for (int j = 1; j < SS; ++j) {
    double cx2 = -2.0 * cx, cy2 = -2.0 * cy, cz2 = -2.0 * cz;
    double cc = fma(cx, cx, fma(cy, cy, cz * cz));
    u64 best = 0;
#pragma unroll
    for (int k = 0; k < 8; ++k) {
      // d = |p-c|^2 via dot-form; clamp: self-point rounds to ~±1e-15 and a
      // negative would set the sign bit and poison the key ordering.
      double d = fma(px64[k], cx2, fma(py64[k], cy2, fma(pz64[k], cz2, pp64[k] + cc)));
      d = fmax(d, 0.0);
      m64[k] = fmin(m64[k], d);
      u64 key = ((u64)__double_as_longlong(m64[k]) & ~0xFFFull) | (u64)(tagbase - k * 512);
      if (key > best) best = key;
    }
    // wave max: 4 DPP stages within row-of-16, then cross-row via readlane
    dpp_umax_stage<0xB1>(best);   // quad_perm [1,0,3,2] : xor 1
    dpp_umax_stage<0x4E>(best);   // quad_perm [2,3,0,1] : xor 2
    dpp_umax_stage<0x141>(best);  // ROW_HALF_MIRROR     : xor 7
    dpp_umax_stage<0x140>(best);  // ROW_MIRROR          : xor 15
    u64 w0 = readlane_u64(best, 0);
    u64 w1 = readlane_u64(best, 16);
    u64 w2 = readlane_u64(best, 32);
    u64 w3 = readlane_u64(best, 48);
    u64 bw = w0;
    if (w1 > bw) bw = w1;
    if (w2 > bw) bw = w2;
    if (w3 > bw) bw = w3;
    if (lane == 0) s_pk[j & 1][wave] = bw;
    __syncthreads();
    // cross-wave: uniform scan of 8 u64 partials
    u64 bk = s_pk[j & 1][0];
#pragma unroll
    for (int w = 1; w < 8; ++w) {
      u64 v = s_pk[j & 1][w];
      if (v > bk) bk = v;
    }
    int fi = 4095 - (int)(bk & 0xFFFull);
    float4 cw = s_xyzw[fi];  // uniform-address LDS broadcast
    cx = (double)cw.x; cy = (double)cw.y; cz = (double)cw.z;
    if (tid == 0) s_fidx[j] = fi;
  }
  __syncthreads();
  // ---- write out fps_idx + new_xyz (once, after the serial loop) ----
  for (int t = tid; t < SS; t += 512) {
    int idx = s_fidx[t];
    fps_idx[b * SS + t] = idx;
    float4 p = s_xyzw[idx];
    out_xyz[((size_t)b * SS + t) * 3 + 0] = p.x;
    out_xyz[((size_t)b * SS + t) * 3 + 1] = p.y;
    out_xyz[((size_t)b * SS + t) * 3 + 2] = p.z;
  }
}

// ---------------- kNN v2: radix tau + u64-key rank scan ----------------
__global__ __launch_bounds__(256) void knn_kernel(const float* __restrict__ xyzT,
                                                  const int* __restrict__ fps_idx,
                                                  int* __restrict__ knn_idx) {
  int wave = threadIdx.x >> 6, lane = threadIdx.x & 63;
  int q = blockIdx.x * 4 + wave, b = q >> 10;
  const float* bx = xyzT + (size_t)b * 3 * NN;
  const float* by = bx + NN;
  const float* bz = bx + 2 * NN;
  int qi = fps_idx[q];
  float qx = bx[qi], qy = by[qi], qz = bz[qi];
  float d[64];
  float lmin = 1e30f;
#pragma unroll
  for (int j = 0; j < 64; ++j) {
    int n = j * 64 + lane;
    float dx = bx[n] - qx, dy = by[n] - qy, dz = bz[n] - qz;
    d[j] = fmaf(dx, dx, fmaf(dy, dy, dz * dz));
    lmin = fminf(lmin, d[j]);
  }
  // ---- 32nd smallest of the 64 lane minima: radix descent on float bits ----
  unsigned lb = __float_as_uint(lmin);
  unsigned res = 0;
#pragma unroll
  for (int bit = 30; bit >= 0; --bit) {
    unsigned t = res | (1u << bit);
    int c = __popcll(__ballot(lb < t));
    res = (c < 32) ? t : res;
  }
  float tau = __uint_as_float(res) * 1.00001f + 1e-20f;  // margin covers f32 dist err

  __shared__ int ci[4][512];
  __shared__ u64 ck[4][512];
  // ---- compact candidate indices (ballot prefix) ----
  int cnt = 0;
#pragma unroll
  for (int j = 0; j < 64; ++j) {
    bool pred = (d[j] <= tau);
    unsigned long long mask = __ballot(pred);
    if (pred) {
      int pos = cnt + __popcll(mask & ((1ull << lane) - 1ull));
      if (pos < 512) ci[wave][pos] = j * 64 + lane;
    }
    cnt += __popcll(mask);
  }
  if (cnt > 512) cnt = 512;
  // ---- exact f64 keys for candidates ----
  double qx64 = (double)qx, qy64 = (double)qy, qz64 = (double)qz;
  for (int p = lane; p < cnt; p += 64) {
    int n = ci[wave][p];
    double dx = (double)bx[n] - qx64;
    double dy = (double)by[n] - qy64;
    double dz = (double)bz[n] - qz64;
    double d64 = fma(dx, dx, fma(dy, dy, dz * dz));
    ck[wave][p] = ((u64)__double_as_longlong(d64) & ~0xFFFull) | (u64)n;
  }
  // ---- rank scan: broadcast reads, unique ranks 0..cnt-1 ----
  for (int p = lane; p < cnt; p += 64) {
    u64 mykey = ck[wave][p];
    int rank = 0;
    int r = 0;
    for (; r + 4 <= cnt; r += 4) {
      u64 k0 = ck[wave][r + 0], k1 = ck[wave][r + 1];
      u64 k2 = ck[wave][r + 2], k3 = ck[wave][r + 3];
      rank += (k0 < mykey) + (k1 < mykey) + (k2 < mykey) + (k3 < mykey);
    }
    for (; r < cnt; ++r) rank += (ck[wave][r] < mykey) ? 1 : 0;
    if (rank < KK) knn_idx[(size_t)q * KK + rank] = (int)(mykey & 0xFFFull);
  }
}

// ---------------- per-group mean over K + per-batch sum of diff^2 ----------------
// XCD-partitioned: blockIdx%8 = XCD owns batches {x, x+8} -> per-XCD L2 working
// set = one batch's points (1.05 MB) instead of 8x duplication.
__global__ __launch_bounds__(256) void meanvar_kernel(const float* __restrict__ points,
                                                      const int* __restrict__ kidx,
                                                      float* __restrict__ mean_out,
                                                      float* __restrict__ var_bins) {
  int wave = threadIdx.x >> 6, lane = threadIdx.x & 63;
  int xcd = blockIdx.x & 7, slot = blockIdx.x >> 3;  // slot 0..511
  int b = xcd + ((slot >> 8) << 3);                  // batches {xcd, xcd+8}
  int g = b * SS + (slot & 255) * 4 + wave;
  const float* pb = points + (size_t)b * NN * CH;
  const int* idx = kidx + (size_t)g * KK;
  float s1 = 0.f, s2 = 0.f;
#pragma unroll
  for (int k = 0; k < KK; ++k) {
    float x = pb[(size_t)idx[k] * CH + lane];
    s1 += x;
    s2 = fmaf(x, x, s2);
  }
  float m = s1 * (1.0f / 32.0f);
  mean_out[(size_t)g * CH + lane] = m;
  float part = s2 - s1 * m;  // sum_k (x-m)^2 (exact algebra: 32*m == s1)
#pragma unroll
  for (int mm = 1; mm < 64; mm <<= 1) part += __shfl_xor(part, mm, 64);
  if (lane == 0) atomicAdd(&var_bins[b * 64 + (g & 63)], part);
}

__global__ void fin_std_kernel(const float* __restrict__ bins, float* __restrict__ rstd) {
  int t = threadIdx.x;
  if (t < BB) {
    float s = 0.f;
    for (int i = 0; i < 64; ++i) s += bins[t * 64 + i];
    float var = s / (float)(SS * KK * CH - 1);
    rstd[t] = 1.0f / (sqrtf(var) + 1e-5f);
  }
}

__global__ void fin_bn_kernel(const float* __restrict__ bins, const float* __restrict__ g,
                              const float* __restrict__ be, float* __restrict__ coef) {
  int o = threadIdx.x;  // < 128
  float s = 0.f, qq = 0.f;
  for (int bin = 0; bin < 64; ++bin) {
    s += bins[(bin * 128 + o) * 2 + 0];
    qq += bins[(bin * 128 + o) * 2 + 1];
  }
  constexpr float invM = 1.0f / (float)(BB * SS * KK);
  float mean = s * invM;
  float var = qq * invM - mean * mean;
  if (var < 0.f) var = 0.f;
  float sc = g[o] / sqrtf(var + 1e-5f);
  coef[2 * o] = sc;
  coef[2 * o + 1] = be[o] - mean * sc;
}

// ---------------- GEMM passes ----------------
// PASS 0: X->h1, accumulate BN1 stats.
// PASS 1: X->h1->P->h2, accumulate BN2 stats.
// PASS 2: X->h1->P->h2, BN2 + residual + lrelu + maxpool -> out.
// XCD-partitioned chunk mapping: blockIdx%8 = XCD owns batches {x, x+8};
// per-XCD L2 working set = one batch's points (1.05 MB, fits 4 MB L2).
template <int PASS>
__global__ __launch_bounds__(256, 2) void gemm_pass(
    const float* __restrict__ points, const int* __restrict__ kidx, const int* __restrict__ fidx,
    const float* __restrict__ mean, const float* __restrict__ rstd,
    const float* __restrict__ alpha, const float* __restrict__ beta,
    const short* __restrict__ w1bf, const short* __restrict__ w2bf,
    const float* __restrict__ coef1, const float* __restrict__ coef2,
    float* __restrict__ bins_out, float* __restrict__ out_pooled) {
  __shared__ short Xs[GPC * 32 * LDW];
  __shared__ short Ps[(PASS >= 1) ? (GPC * 32 * LDW) : 8];
  __shared__ float sAlpha[64], sBeta[64];
  __shared__ float sCoef1[256], sCoef2[256];
  __shared__ float bnS[128], bnQ[128];

  int tid = threadIdx.x;
  int wave = tid >> 6, lane = tid & 63;
  int q4 = lane >> 4, l15 = lane & 15;
  int ohalf = wave & 1, gsel = wave >> 1;

  // W fragments -> registers
  v8s wf1[4][4];
  v8s wf2[4][4];
#pragma unroll
  for (int ot = 0; ot < 4; ++ot) {
    int row = ohalf * 64 + ot * 16 + l15;
#pragma unroll
    for (int cs = 0; cs < 4; ++cs) {
      wf1[ot][cs] = *(const v8s*)(w1bf + row * 128 + cs * 32 + q4 * 8);
      if constexpr (PASS >= 1) wf2[ot][cs] = *(const v8s*)(w2bf + row * 128 + cs * 32 + q4 * 8);
    }
  }
  if (tid < 64) { sAlpha[tid] = alpha[tid]; sBeta[tid] = beta[tid]; }
  if constexpr (PASS >= 1) sCoef1[tid] = coef1[tid];
  if constexpr (PASS == 2) sCoef2[tid] = coef2[tid];
  if constexpr (PASS <= 1) {
    if (tid < 128) { bnS[tid] = 0.f; bnQ[tid] = 0.f; }
  }
  __syncthreads();

  int xcd = blockIdx.x & 7, slot = blockIdx.x >> 3;  // slot 0..63
  for (int t = slot; t < 1024; t += 64) {
    int batch = xcd + ((t >> 9) << 3);       // batches {xcd, xcd+8}
    int g0 = batch * SS + (t & 511) * GPC;   // chunk within batch
    // ---- stage Xs: [g][k][0:64]=normalized grouped, [64:128]=new_pts ----
    {
      int sg = tid >> 7;
      int sk = (tid >> 2) & 31;
      int qr = tid & 3;
      int ggl = g0 + sg;
      int b = batch;
      const float* pb = points + (size_t)b * NN * CH;
      int row = (qr < 2) ? kidx[(size_t)ggl * KK + sk] : fidx[ggl];
      int ch0 = (qr & 1) * 32;
      const float* src = pb + (size_t)row * CH + ch0;
      const float* mrow = mean + (size_t)ggl * CH + ch0;
      float rs = rstd[b];
      bool norm = (qr < 2);
      v8s pack[4];
#pragma unroll
      for (int cc = 0; cc < 32; cc += 4) {
        float4 vv = *(const float4*)(src + cc);
        if (norm) {
          float4 mv = *(const float4*)(mrow + cc);
          vv.x = fmaf((vv.x - mv.x) * rs, sAlpha[ch0 + cc + 0], sBeta[ch0 + cc + 0]);
          vv.y = fmaf((vv.y - mv.y) * rs, sAlpha[ch0 + cc + 1], sBeta[ch0 + cc + 1]);
          vv.z = fmaf((vv.z - mv.z) * rs, sAlpha[ch0 + cc + 2], sBeta[ch0 + cc + 2]);
          vv.w = fmaf((vv.w - mv.w) * rs, sAlpha[ch0 + cc + 3], sBeta[ch0 + cc + 3]);
        }
        pack[cc >> 3][(cc & 7) + 0] = f2bf(vv.x);
        pack[cc >> 3][(cc & 7) + 1] = f2bf(vv.y);
        pack[cc >> 3][(cc & 7) + 2] = f2bf(vv.z);
        pack[cc >> 3][(cc & 7) + 3] = f2bf(vv.w);
      }
      short* dst = &Xs[(sg * 32 + sk) * LDW + qr * 32];
#pragma unroll
      for (int p2 = 0; p2 < 4; ++p2) *(v8s*)(dst + p2 * 8) = pack[p2];
    }
    __syncthreads();

    // ---- GEMM1: h1 = W1 * X ----
    v4f acc[4][2] = {};
#pragma unroll
    for (int cs = 0; cs < 4; ++cs) {
      v8s bfr[2];
#pragma unroll
      for (int kt = 0; kt < 2; ++kt)
        bfr[kt] = *(const v8s*)&Xs[(gsel * 32 + kt * 16 + l15) * LDW + cs * 32 + q4 * 8];
#pragma unroll
      for (int ot = 0; ot < 4; ++ot)
#pragma unroll
        for (int kt = 0; kt < 2; ++kt)
          acc[ot][kt] = __builtin_amdgcn_mfma_f32_16x16x32_bf16(wf1[ot][cs], bfr[kt], acc[ot][kt], 0, 0, 0);
    }

    if constexpr (PASS == 0) {
      // BN1 stats of h1
#pragma unroll
      for (int ot = 0; ot < 4; ++ot) {
        float sv[4], sq[4];
#pragma unroll
        for (int r = 0; r < 4; ++r) {
          float a0 = acc[ot][0][r], a1 = acc[ot][1][r];
          sv[r] = a0 + a1;
          sq[r] = fmaf(a0, a0, a1 * a1);
        }
#pragma unroll
        for (int m = 1; m < 16; m <<= 1)
#pragma unroll
          for (int r = 0; r < 4; ++r) {
            sv[r] += __shfl_xor(sv[r], m, 64);
            sq[r] += __shfl_xor(sq[r], m, 64);
          }
        if (l15 == 0) {
          int o0 = ohalf * 64 + ot * 16 + q4 * 4;
#pragma unroll
          for (int r = 0; r < 4; ++r) {
            atomicAdd(&bnS[o0 + r], sv[r]);
            atomicAdd(&bnQ[o0 + r], sq[r]);
          }
        }
      }
    } else {
      // ---- P = lrelu(bn1(h1)) -> Ps ----
#pragma unroll
      for (int ot = 0; ot < 4; ++ot) {
        int o0 = ohalf * 64 + ot * 16 + q4 * 4;
#pragma unroll
        for (int kt = 0; kt < 2; ++kt) {
          v4s pk;
#pragma unroll
          for (int r = 0; r < 4; ++r) {
            float h = fmaf(acc[ot][kt][r], sCoef1[2 * (o0 + r)], sCoef1[2 * (o0 + r) + 1]);
            h = (h >= 0.f) ? h : 0.01f * h;
            pk[r] = f2bf(h);
          }
          *(v4s*)&Ps[(gsel * 32 + kt * 16 + l15) * LDW + o0] = pk;
        }
      }
      __syncthreads();

      // ---- GEMM2: h2 = W2 * P ----
      v4f acc2[4][2] = {};
#pragma unroll
      for (int cs = 0; cs < 4; ++cs) {
        v8s pfr[2];
#pragma unroll
        for (int kt = 0; kt < 2; ++kt)
          pfr[kt] = *(const v8s*)&Ps[(gsel * 32 + kt * 16 + l15) * LDW + cs * 32 + q4 * 8];
#pragma unroll
        for (int ot = 0; ot < 4; ++ot)
#pragma unroll
          for (int kt = 0; kt < 2; ++kt)
            acc2[ot][kt] = __builtin_amdgcn_mfma_f32_16x16x32_bf16(wf2[ot][cs], pfr[kt], acc2[ot][kt], 0, 0, 0);
      }

      if constexpr (PASS == 1) {
        // BN2 stats of h2
#pragma unroll
        for (int ot = 0; ot < 4; ++ot) {
          float sv[4], sq[4];
#pragma unroll
          for (int r = 0; r < 4; ++r) {
            float a0 = acc2[ot][0][r], a1 = acc2[ot][1][r];
            sv[r] = a0 + a1;
            sq[r] = fmaf(a0, a0, a1 * a1);
          }
#pragma unroll
          for (int m = 1; m < 16; m <<= 1)
#pragma unroll
            for (int r = 0; r < 4; ++r) {
              sv[r] += __shfl_xor(sv[r], m, 64);
              sq[r] += __shfl_xor(sq[r], m, 64);
            }
          if (l15 == 0) {
            int o0 = ohalf * 64 + ot * 16 + q4 * 4;
#pragma unroll
            for (int r = 0; r < 4; ++r) {
              atomicAdd(&bnS[o0 + r], sv[r]);
              atomicAdd(&bnQ[o0 + r], sq[r]);
            }
          }
        }
      } else {
        // ---- epilogue: lrelu(bn2(h2) + X) , max over k, store ----
#pragma unroll
        for (int ot = 0; ot < 4; ++ot) {
          int o0 = ohalf * 64 + ot * 16 + q4 * 4;
          float mx[4] = {-1e30f, -1e30f, -1e30f, -1e30f};
#pragma unroll
          for (int kt = 0; kt < 2; ++kt) {
            v4s xv = *(const v4s*)&Xs[(gsel * 32 + kt * 16 + l15) * LDW + o0];
#pragma unroll
            for (int r = 0; r < 4; ++r) {
              float h = fmaf(acc2[ot][kt][r], sCoef2[2 * (o0 + r)], sCoef2[2 * (o0 + r) + 1]);
              float val = h + bf2f(xv[r]);
              val = (val >= 0.f) ? val : 0.01f * val;
              mx[r] = fmaxf(mx[r], val);
            }
          }
#pragma unroll
          for (int m = 1; m < 16; m <<= 1)
#pragma unroll
            for (int r = 0; r < 4; ++r) mx[r] = fmaxf(mx[r], __shfl_xor(mx[r], m, 64));
          if (l15 == 0) {
            float4 o4;
            o4.x = mx[0]; o4.y = mx[1]; o4.z = mx[2]; o4.w = mx[3];
            *(float4*)(out_pooled + (size_t)(g0 + gsel) * DD + o0) = o4;
          }
        }
      }
    }
    __syncthreads();
  }

  if constexpr (PASS <= 1) {
    if (tid < 128) {
      float* bb = bins_out + (((blockIdx.x & 63) * 128 + tid) << 1);
      atomicAdd(bb, bnS[tid]);
      atomicAdd(bb + 1, bnQ[tid]);
    }
  }
}

extern "C" void kernel_launch(void* const* d_in, const int* in_sizes, int n_in,
                              void* d_out, int out_size, void* d_ws, size_t ws_size,
                              hipStream_t stream) {
  const float* xyz    = (const float*)d_in[0];
  const float* points = (const float*)d_in[1];
  const float* alpha  = (const float*)d_in[2];
  const float* beta   = (const float*)d_in[3];
  const float* w1     = (const float*)d_in[4];
  const float* g1     = (const float*)d_in[6];
  const float* be1    = (const float*)d_in[7];
  const float* w2     = (const float*)d_in[8];
  const float* g2     = (const float*)d_in[10];
  const float* be2    = (const float*)d_in[11];
  float* out = (float*)d_out;

  char* w = (char*)d_ws;
  int* fps_i   = (int*)(w + OFF_FPSIDX);
  int* knn_i   = (int*)(w + OFF_KNN);
  float* meanp = (float*)(w + OFF_MEAN);
  float* varb  = (float*)(w + OFF_VARB);
  float* bins1 = (float*)(w + OFF_BINS1);
  float* bins2 = (float*)(w + OFF_BINS2);
  float* rstdp = (float*)(w + OFF_RSTD);
  float* coef1 = (float*)(w + OFF_COEF1);
  float* coef2 = (float*)(w + OFF_COEF2);
  short* w1b   = (short*)(w + OFF_W1BF);
  short* w2b   = (short*)(w + OFF_W2BF);
  float* xyzT  = (float*)(w + OFF_XYZT);

  hipMemsetAsync(w + MEMSET_OFF, 0, MEMSET_LEN, stream);
  xpose_kernel<<<256, 256, 0, stream>>>(xyz, xyzT);
  cvtw_kernel<<<64, 256, 0, stream>>>(w1, w2, w1b, w2b);
  fps_kernel<<<BB, 512, 0, stream>>>(xyzT, fps_i, out);
  knn_kernel<<<(BB * SS) / 4, 256, 0, stream>>>(xyzT, fps_i, knn_i);
  meanvar_kernel<<<(BB * SS) / 4, 256, 0, stream>>>(points, knn_i, meanp, varb);
  fin_std_kernel<<<1, 64, 0, stream>>>(varb, rstdp);
  gemm_pass<0><<<GGRID, 256, 0, stream>>>(points, knn_i, fps_i, meanp, rstdp, alpha, beta,
                                          w1b, w2b, coef1, coef2, bins1, nullptr);
  fin_bn_kernel<<<1, 128, 0, stream>>>(bins1, g1, be1, coef1);
  gemm_pass<1><<<GGRID, 256, 0, stream>>>(points, knn_i, fps_i, meanp, rstdp, alpha, beta,
                                          w1b, w2b, coef1, coef2, bins2, nullptr);
  fin_bn_kernel<<<1, 128, 0, stream>>>(bins2, g2, be2, coef2);
  gemm_pass<2><<<GGRID, 256, 0, stream>>>(points, knn_i, fps_i, meanp, rstdp, alpha, beta,
                                          w1b, w2b, coef1, coef2, nullptr, out + (size_t)BB * SS * 3);
}

// Round 8
// 1222.095 us; speedup vs baseline: 2.4520x; 1.0436x over previous
//
#include <hip/hip_runtime.h>

#define DI __device__ __forceinline__

typedef __attribute__((ext_vector_type(8))) short v8s;
typedef __attribute__((ext_vector_type(4))) short v4s;
typedef __attribute__((ext_vector_type(4))) float v4f;
typedef unsigned long long u64;

constexpr int BB = 16, NN = 4096, CH = 64, SS = 1024, KK = 32, DD = 128;
constexpr int LDW = 136;                 // LDS row stride in shorts (pad: 16B-aligned rows, <=2-way banks)
constexpr int GPC = 2;                   // groups per chunk in gemm passes
constexpr int GGRID = 512;

// ---- ws layout (bytes) ----
constexpr size_t OFF_FPSIDX = 0;         // int[16384]
constexpr size_t OFF_KNN    = 65536;     // int[524288]
constexpr size_t OFF_MEAN   = 2162688;   // float[1048576]
constexpr size_t OFF_VARB   = 6356992;   // float[1024]
constexpr size_t OFF_BINS1  = 6361088;   // float[16384]  [64][128][2]
constexpr size_t OFF_BINS2  = 6426624;   // float[16384]
constexpr size_t OFF_RSTD   = 6492160;   // float[16]
constexpr size_t OFF_COEF1  = 6492224;   // float[256]
constexpr size_t OFF_COEF2  = 6493248;   // float[256]
constexpr size_t OFF_W1BF   = 6494272;   // short[16384]
constexpr size_t OFF_W2BF   = 6527040;   // short[16384]
constexpr size_t OFF_XYZT   = 6559808;   // float[196608]  [B][3][N]
constexpr size_t MEMSET_OFF = OFF_VARB;
constexpr size_t MEMSET_LEN = 4096 + 65536 + 65536;

DI short f2bf(float f) {
  unsigned u = __float_as_uint(f);
  u = (u + 0x7fffu + ((u >> 16) & 1u)) >> 16;
  return (short)u;
}
DI float bf2f(short s) { return __uint_as_float(((unsigned)(unsigned short)s) << 16); }

// ---------------- xyz transpose: [B][N][3] -> [B][3][N] ----------------
__global__ void xpose_kernel(const float* __restrict__ xyz, float* __restrict__ xyzT) {
  int i = blockIdx.x * 256 + threadIdx.x;  // < B*N
  int b = i >> 12, n = i & 4095;
  const float* s = xyz + (size_t)i * 3;
  float* d = xyzT + (size_t)b * 3 * NN + n;
  d[0] = s[0]; d[NN] = s[1]; d[2 * NN] = s[2];
}

// ---------------- weight f32 -> bf16 ----------------
__global__ void cvtw_kernel(const float* __restrict__ w1, const float* __restrict__ w2,
                            short* __restrict__ w1b, short* __restrict__ w2b) {
  int i = blockIdx.x * 256 + threadIdx.x;  // < 16384
  w1b[i] = f2bf(w1[i]);
  w2b[i] = f2bf(w2[i]);
}

// 64-bit DPP shuffle within a row of 16 lanes
template <int CTRL>
DI u64 dpp_u64(u64 x) {
  int lo = __builtin_amdgcn_update_dpp(0, (int)(unsigned)x, CTRL, 0xf, 0xf, true);
  int hi = __builtin_amdgcn_update_dpp(0, (int)(unsigned)(x >> 32), CTRL, 0xf, 0xf, true);
  return ((u64)(unsigned)hi << 32) | (unsigned)lo;
}
template <int CTRL>
DI void dpp_umax_stage(u64& x) {
  u64 o = dpp_u64<CTRL>(x);
  if (o > x) x = o;
}
DI u64 readlane_u64(u64 x, int l) {
  unsigned lo = (unsigned)__builtin_amdgcn_readlane((int)(unsigned)x, l);
  unsigned hi = (unsigned)__builtin_amdgcn_readlane((int)(unsigned)(x >> 32), l);
  return ((u64)hi << 32) | lo;
}

// DPP row rotate (within 16-lane row) for f32 reductions -- no LDS traffic.
template <int N>
DI float dpp_ror_f(float v) {
  return __int_as_float(__builtin_amdgcn_update_dpp(0, __float_as_int(v), 0x120 + N, 0xf, 0xf, true));
}
DI float sum16(float v) {  // rotation butterfly: every lane gets the 16-lane sum
  v += dpp_ror_f<1>(v);
  v += dpp_ror_f<2>(v);
  v += dpp_ror_f<4>(v);
  v += dpp_ror_f<8>(v);
  return v;
}
DI float max16(float v) {
  v = fmaxf(v, dpp_ror_f<1>(v));
  v = fmaxf(v, dpp_ror_f<2>(v));
  v = fmaxf(v, dpp_ror_f<4>(v));
  v = fmaxf(v, dpp_ror_f<8>(v));
  return v;
}

// ---------------- FPS v5: u64-key argmax, branchless exact-f64 chain ----------------
__global__ __launch_bounds__(512, 2) void fps_kernel(const float* __restrict__ xyzT,
                                                     int* __restrict__ fps_idx,
                                                     float* __restrict__ out_xyz) {
  int b = blockIdx.x, tid = threadIdx.x;
  int wave = tid >> 6, lane = tid & 63;
  const float* bx = xyzT + (size_t)b * 3 * NN;
  const float* by = bx + NN;
  const float* bz = bx + 2 * NN;
  __shared__ float4 s_xyzw[NN];  // 64 KB coords broadcast
  __shared__ int s_fidx[SS];     // 4 KB selected indices
  __shared__ u64 s_pk[2][8];     // wave partial keys (dbuf by round parity)

  double px64[8], py64[8], pz64[8], pp64[8], m64[8];
  int tagbase = 4095 - tid;  // tag for point k: tagbase - k*512 == 4095 - gi
#pragma unroll
  for (int k = 0; k < 8; ++k) {
    int gi = k * 512 + tid;
    float x = bx[gi], y = by[gi], z = bz[gi];
    s_xyzw[gi] = make_float4(x, y, z, 0.f);
    px64[k] = (double)x; py64[k] = (double)y; pz64[k] = (double)z;
    pp64[k] = fma(px64[k], px64[k], fma(py64[k], py64[k], pz64[k] * pz64[k]));
    m64[k] = 1e10;
  }
  if (tid == 0) s_fidx[0] = 0;
  __syncthreads();
  float4 c0 = s_xyzw[0];
  double cx = (double)c0.x, cy = (double)c0.y, cz = (double)c0.z;

  for (int j = 1; j < SS; ++j) {
    double cx2 = -2.0 * cx, cy2 = -2.0 * cy, cz2 = -2.0 * cz;
    double cc = fma(cx, cx, fma(cy, cy, cz * cz));
    u64 best = 0;
#pragma unroll
    for (int k = 0; k < 8; ++k) {
      double d = fma(px64[k], cx2, fma(py64[k], cy2, fma(pz64[k], cz2, pp64[k] + cc)));
      d = fmax(d, 0.0);
      m64[k] = fmin(m64[k], d);
      u64 key = ((u64)__double_as_longlong(m64[k]) & ~0xFFFull) | (u64)(tagbase - k * 512);
      if (key > best) best = key;
    }
    dpp_umax_stage<0xB1>(best);   // quad_perm [1,0,3,2] : xor 1
    dpp_umax_stage<0x4E>(best);   // quad_perm [2,3,0,1] : xor 2
    dpp_umax_stage<0x141>(best);  // ROW_HALF_MIRROR     : xor 7
    dpp_umax_stage<0x140>(best);  // ROW_MIRROR          : xor 15
    u64 w0 = readlane_u64(best, 0);
    u64 w1 = readlane_u64(best, 16);
    u64 w2 = readlane_u64(best, 32);
    u64 w3 = readlane_u64(best, 48);
    u64 bw = w0;
    if (w1 > bw) bw = w1;
    if (w2 > bw) bw = w2;
    if (w3 > bw) bw = w3;
    if (lane == 0) s_pk[j & 1][wave] = bw;
    __syncthreads();
    u64 bk = s_pk[j & 1][0];
#pragma unroll
    for (int w = 1; w < 8; ++w) {
      u64 v = s_pk[j & 1][w];
      if (v > bk) bk = v;
    }
    int fi = 4095 - (int)(bk & 0xFFFull);
    float4 cw = s_xyzw[fi];  // uniform-address LDS broadcast
    cx = (double)cw.x; cy = (double)cw.y; cz = (double)cw.z;
    if (tid == 0) s_fidx[j] = fi;
  }
  __syncthreads();
  for (int t = tid; t < SS; t += 512) {
    int idx = s_fidx[t];
    fps_idx[b * SS + t] = idx;
    float4 p = s_xyzw[idx];
    out_xyz[((size_t)b * SS + t) * 3 + 0] = p.x;
    out_xyz[((size_t)b * SS + t) * 3 + 1] = p.y;
    out_xyz[((size_t)b * SS + t) * 3 + 2] = p.z;
  }
}

// ---------------- kNN v2: radix tau + u64-key rank scan ----------------
__global__ __launch_bounds__(256) void knn_kernel(const float* __restrict__ xyzT,
                                                  const int* __restrict__ fps_idx,
                                                  int* __restrict__ knn_idx) {
  int wave = threadIdx.x >> 6, lane = threadIdx.x & 63;
  int q = blockIdx.x * 4 + wave, b = q >> 10;
  const float* bx = xyzT + (size_t)b * 3 * NN;
  const float* by = bx + NN;
  const float* bz = bx + 2 * NN;
  int qi = fps_idx[q];
  float qx = bx[qi], qy = by[qi], qz = bz[qi];
  float d[64];
  float lmin = 1e30f;
#pragma unroll
  for (int j = 0; j < 64; ++j) {
    int n = j * 64 + lane;
    float dx = bx[n] - qx, dy = by[n] - qy, dz = bz[n] - qz;
    d[j] = fmaf(dx, dx, fmaf(dy, dy, dz * dz));
    lmin = fminf(lmin, d[j]);
  }
  unsigned lb = __float_as_uint(lmin);
  unsigned res = 0;
#pragma unroll
  for (int bit = 30; bit >= 0; --bit) {
    unsigned t = res | (1u << bit);
    int c = __popcll(__ballot(lb < t));
    res = (c < 32) ? t : res;
  }
  float tau = __uint_as_float(res) * 1.00001f + 1e-20f;  // margin covers f32 dist err

  __shared__ int ci[4][512];
  __shared__ u64 ck[4][512];
  int cnt = 0;
#pragma unroll
  for (int j = 0; j < 64; ++j) {
    bool pred = (d[j] <= tau);
    unsigned long long mask = __ballot(pred);
    if (pred) {
      int pos = cnt + __popcll(mask & ((1ull << lane) - 1ull));
      if (pos < 512) ci[wave][pos] = j * 64 + lane;
    }
    cnt += __popcll(mask);
  }
  if (cnt > 512) cnt = 512;
  double qx64 = (double)qx, qy64 = (double)qy, qz64 = (double)qz;
  for (int p = lane; p < cnt; p += 64) {
    int n = ci[wave][p];
    double dx = (double)bx[n] - qx64;
    double dy = (double)by[n] - qy64;
    double dz = (double)bz[n] - qz64;
    double d64 = fma(dx, dx, fma(dy, dy, dz * dz));
    ck[wave][p] = ((u64)__double_as_longlong(d64) & ~0xFFFull) | (u64)n;
  }
  for (int p = lane; p < cnt; p += 64) {
    u64 mykey = ck[wave][p];
    int rank = 0;
    int r = 0;
    for (; r + 4 <= cnt; r += 4) {
      u64 k0 = ck[wave][r + 0], k1 = ck[wave][r + 1];
      u64 k2 = ck[wave][r + 2], k3 = ck[wave][r + 3];
      rank += (k0 < mykey) + (k1 < mykey) + (k2 < mykey) + (k3 < mykey);
    }
    for (; r < cnt; ++r) rank += (ck[wave][r] < mykey) ? 1 : 0;
    if (rank < KK) knn_idx[(size_t)q * KK + rank] = (int)(mykey & 0xFFFull);
  }
}

// ---------------- per-group mean over K + per-batch sum of diff^2 ----------------
__global__ __launch_bounds__(256) void meanvar_kernel(const float* __restrict__ points,
                                                      const int* __restrict__ kidx,
                                                      float* __restrict__ mean_out,
                                                      float* __restrict__ var_bins) {
  int wave = threadIdx.x >> 6, lane = threadIdx.x & 63;
  int xcd = blockIdx.x & 7, slot = blockIdx.x >> 3;  // slot 0..511
  int b = xcd + ((slot >> 8) << 3);                  // batches {xcd, xcd+8}
  int g = b * SS + (slot & 255) * 4 + wave;
  const float* pb = points + (size_t)b * NN * CH;
  const int* idx = kidx + (size_t)g * KK;
  float s1 = 0.f, s2 = 0.f;
#pragma unroll
  for (int k = 0; k < KK; ++k) {
    float x = pb[(size_t)idx[k] * CH + lane];
    s1 += x;
    s2 = fmaf(x, x, s2);
  }
  float m = s1 * (1.0f / 32.0f);
  mean_out[(size_t)g * CH + lane] = m;
  float part = s2 - s1 * m;  // sum_k (x-m)^2 (exact algebra: 32*m == s1)
#pragma unroll
  for (int mm = 1; mm < 64; mm <<= 1) part += __shfl_xor(part, mm, 64);
  if (lane == 0) atomicAdd(&var_bins[b * 64 + (g & 63)], part);
}

__global__ void fin_std_kernel(const float* __restrict__ bins, float* __restrict__ rstd) {
  int t = threadIdx.x;
  if (t < BB) {
    float s = 0.f;
    for (int i = 0; i < 64; ++i) s += bins[t * 64 + i];
    float var = s / (float)(SS * KK * CH - 1);
    rstd[t] = 1.0f / (sqrtf(var) + 1e-5f);
  }
}

__global__ void fin_bn_kernel(const float* __restrict__ bins, const float* __restrict__ g,
                              const float* __restrict__ be, float* __restrict__ coef) {
  int o = threadIdx.x;  // < 128
  float s = 0.f, qq = 0.f;
  for (int bin = 0; bin < 64; ++bin) {
    s += bins[(bin * 128 + o) * 2 + 0];
    qq += bins[(bin * 128 + o) * 2 + 1];
  }
  constexpr float invM = 1.0f / (float)(BB * SS * KK);
  float mean = s * invM;
  float var = qq * invM - mean * mean;
  if (var < 0.f) var = 0.f;
  float sc = g[o] / sqrtf(var + 1e-5f);
  coef[2 * o] = sc;
  coef[2 * o + 1] = be[o] - mean * sc;
}

// ---------------- GEMM passes (software-pipelined staging + DPP reductions) ----------------
// PASS 0: X->h1, accumulate BN1 stats.
// PASS 1: X->h1->P->h2, accumulate BN2 stats.
// PASS 2: X->h1->P->h2, BN2 + residual + lrelu + maxpool -> out.
// XCD-partitioned chunk mapping; per iteration: stage chunk t from registers
// (prefetched last iteration), barrier, GEMM1, issue t+1's gather (hidden
// behind GEMM2/stats), PASS work, barrier.
template <int PASS>
__global__ __launch_bounds__(256, 2) void gemm_pass(
    const float* __restrict__ points, const int* __restrict__ kidx, const int* __restrict__ fidx,
    const float* __restrict__ mean, const float* __restrict__ rstd,
    const float* __restrict__ alpha, const float* __restrict__ beta,
    const short* __restrict__ w1bf, const short* __restrict__ w2bf,
    const float* __restrict__ coef1, const float* __restrict__ coef2,
    float* __restrict__ bins_out, float* __restrict__ out_pooled) {
  __shared__ short Xs[GPC * 32 * LDW];
  __shared__ short Ps[(PASS >= 1) ? (GPC * 32 * LDW) : 8];
  __shared__ float sAlpha[64], sBeta[64];
  __shared__ float sCoef1[256], sCoef2[256];
  __shared__ float bnS[128], bnQ[128];

  int tid = threadIdx.x;
  int wave = tid >> 6, lane = tid & 63;
  int q4 = lane >> 4, l15 = lane & 15;
  int ohalf = wave & 1, gsel = wave >> 1;

  // W fragments -> registers
  v8s wf1[4][4];
  v8s wf2[4][4];
#pragma unroll
  for (int ot = 0; ot < 4; ++ot) {
    int row = ohalf * 64 + ot * 16 + l15;
#pragma unroll
    for (int cs = 0; cs < 4; ++cs) {
      wf1[ot][cs] = *(const v8s*)(w1bf + row * 128 + cs * 32 + q4 * 8);
      if constexpr (PASS >= 1) wf2[ot][cs] = *(const v8s*)(w2bf + row * 128 + cs * 32 + q4 * 8);
    }
  }
  if (tid < 64) { sAlpha[tid] = alpha[tid]; sBeta[tid] = beta[tid]; }
  if constexpr (PASS >= 1) sCoef1[tid] = coef1[tid];
  if constexpr (PASS == 2) sCoef2[tid] = coef2[tid];
  if constexpr (PASS <= 1) {
    if (tid < 128) { bnS[tid] = 0.f; bnQ[tid] = 0.f; }
  }
  __syncthreads();

  int xcd = blockIdx.x & 7, slot = blockIdx.x >> 3;  // slot 0..63
  int sg = tid >> 7, sk = (tid >> 2) & 31, qr = tid & 3;
  int ch0 = (qr & 1) * 32;
  bool norm = (qr < 2);

  // ---- pipeline preamble: prefetch chunk(slot) gather into registers ----
  float4 ldv[8], mdv[8];
  {
    int t = slot;
    int batch = xcd + ((t >> 9) << 3);
    int g0 = batch * SS + (t & 511) * GPC;
    int ggl = g0 + sg;
    int row = norm ? kidx[(size_t)ggl * KK + sk] : fidx[ggl];
    const float* src = points + (size_t)batch * NN * CH + (size_t)row * CH + ch0;
#pragma unroll
    for (int u = 0; u < 8; ++u) ldv[u] = *(const float4*)(src + u * 4);
    if (norm) {
      const float* mrow = mean + (size_t)ggl * CH + ch0;
#pragma unroll
      for (int u = 0; u < 8; ++u) mdv[u] = *(const float4*)(mrow + u * 4);
    }
  }

  for (int it = 0; it < 16; ++it) {
    int t = slot + it * 64;
    int batch = xcd + ((t >> 9) << 3);
    int g0 = batch * SS + (t & 511) * GPC;
    int tn = (it < 15) ? t + 64 : t;
    int batch_n = xcd + ((tn >> 9) << 3);
    int g0_n = batch_n * SS + (tn & 511) * GPC;
    int ggl_n = g0_n + sg;
    // issue next-chunk index load now (waited after GEMM1)
    int row_n = norm ? kidx[(size_t)ggl_n * KK + sk] : fidx[ggl_n];

    // ---- stage chunk t from prefetched registers ----
    {
      float rs = rstd[batch];
      v8s pack[4];
#pragma unroll
      for (int u = 0; u < 8; ++u) {
        float4 vv = ldv[u];
        if (norm) {
          float4 mv = mdv[u];
          float4 av = *(const float4*)&sAlpha[ch0 + u * 4];
          float4 bv = *(const float4*)&sBeta[ch0 + u * 4];
          vv.x = fmaf((vv.x - mv.x) * rs, av.x, bv.x);
          vv.y = fmaf((vv.y - mv.y) * rs, av.y, bv.y);
          vv.z = fmaf((vv.z - mv.z) * rs, av.z, bv.z);
          vv.w = fmaf((vv.w - mv.w) * rs, av.w, bv.w);
        }
        pack[u >> 1][(u & 1) * 4 + 0] = f2bf(vv.x);
        pack[u >> 1][(u & 1) * 4 + 1] = f2bf(vv.y);
        pack[u >> 1][(u & 1) * 4 + 2] = f2bf(vv.z);
        pack[u >> 1][(u & 1) * 4 + 3] = f2bf(vv.w);
      }
      short* dst = &Xs[(sg * 32 + sk) * LDW + qr * 32];
#pragma unroll
      for (int p2 = 0; p2 < 4; ++p2) *(v8s*)(dst + p2 * 8) = pack[p2];
    }
    __syncthreads();

    // ---- GEMM1: h1 = W1 * X ----
    v4f acc[4][2] = {};
#pragma unroll
    for (int cs = 0; cs < 4; ++cs) {
      v8s bfr[2];
#pragma unroll
      for (int kt = 0; kt < 2; ++kt)
        bfr[kt] = *(const v8s*)&Xs[(gsel * 32 + kt * 16 + l15) * LDW + cs * 32 + q4 * 8];
#pragma unroll
      for (int ot = 0; ot < 4; ++ot)
#pragma unroll
        for (int kt = 0; kt < 2; ++kt)
          acc[ot][kt] = __builtin_amdgcn_mfma_f32_16x16x32_bf16(wf1[ot][cs], bfr[kt], acc[ot][kt], 0, 0, 0);
    }

    // ---- issue next-chunk gather (row_n ready); hides behind GEMM2/stats ----
    {
      const float* src = points + (size_t)batch_n * NN * CH + (size_t)row_n * CH + ch0;
#pragma unroll
      for (int u = 0; u < 8; ++u) ldv[u] = *(const float4*)(src + u * 4);
      if (norm) {
        const float* mrow = mean + (size_t)ggl_n * CH + ch0;
#pragma unroll
        for (int u = 0; u < 8; ++u) mdv[u] = *(const float4*)(mrow + u * 4);
      }
    }

    if constexpr (PASS == 0) {
      // BN1 stats of h1 (DPP 16-lane sums)
#pragma unroll
      for (int ot = 0; ot < 4; ++ot) {
        float sv[4], sq[4];
#pragma unroll
        for (int r = 0; r < 4; ++r) {
          float a0 = acc[ot][0][r], a1 = acc[ot][1][r];
          sv[r] = sum16(a0 + a1);
          sq[r] = sum16(fmaf(a0, a0, a1 * a1));
        }
        if (l15 == 0) {
          int o0 = ohalf * 64 + ot * 16 + q4 * 4;
#pragma unroll
          for (int r = 0; r < 4; ++r) {
            atomicAdd(&bnS[o0 + r], sv[r]);
            atomicAdd(&bnQ[o0 + r], sq[r]);
          }
        }
      }
    } else {
      // ---- P = lrelu(bn1(h1)) -> Ps ----
#pragma unroll
      for (int ot = 0; ot < 4; ++ot) {
        int o0 = ohalf * 64 + ot * 16 + q4 * 4;
#pragma unroll
        for (int kt = 0; kt < 2; ++kt) {
          v4s pk;
#pragma unroll
          for (int r = 0; r < 4; ++r) {
            float h = fmaf(acc[ot][kt][r], sCoef1[2 * (o0 + r)], sCoef1[2 * (o0 + r) + 1]);
            h = (h >= 0.f) ? h : 0.01f * h;
            pk[r] = f2bf(h);
          }
          *(v4s*)&Ps[(gsel * 32 + kt * 16 + l15) * LDW + o0] = pk;
        }
      }
      __syncthreads();

      // ---- GEMM2: h2 = W2 * P ----
      v4f acc2[4][2] = {};
#pragma unroll
      for (int cs = 0; cs < 4; ++cs) {
        v8s pfr[2];
#pragma unroll
        for (int kt = 0; kt < 2; ++kt)
          pfr[kt] = *(const v8s*)&Ps[(gsel * 32 + kt * 16 + l15) * LDW + cs * 32 + q4 * 8];
#pragma unroll
        for (int ot = 0; ot < 4; ++ot)
#pragma unroll
          for (int kt = 0; kt < 2; ++kt)
            acc2[ot][kt] = __builtin_amdgcn_mfma_f32_16x16x32_bf16(wf2[ot][cs], pfr[kt], acc2[ot][kt], 0, 0, 0);
      }

      if constexpr (PASS == 1) {
        // BN2 stats of h2 (DPP 16-lane sums)
#pragma unroll
        for (int ot = 0; ot < 4; ++ot) {
          float sv[4], sq[4];
#pragma unroll
          for (int r = 0; r < 4; ++r) {
            float a0 = acc2[ot][0][r], a1 = acc2[ot][1][r];
            sv[r] = sum16(a0 + a1);
            sq[r] = sum16(fmaf(a0, a0, a1 * a1));
          }
          if (l15 == 0) {
            int o0 = ohalf * 64 + ot * 16 + q4 * 4;
#pragma unroll
            for (int r = 0; r < 4; ++r) {
              atomicAdd(&bnS[o0 + r], sv[r]);
              atomicAdd(&bnQ[o0 + r], sq[r]);
            }
          }
        }
      } else {
        // ---- epilogue: lrelu(bn2(h2) + X) , max over k (DPP), store ----
#pragma unroll
        for (int ot = 0; ot < 4; ++ot) {
          int o0 = ohalf * 64 + ot * 16 + q4 * 4;
          float mx[4] = {-1e30f, -1e30f, -1e30f, -1e30f};
#pragma unroll
          for (int kt = 0; kt < 2; ++kt) {
            v4s xv = *(const v4s*)&Xs[(gsel * 32 + kt * 16 + l15) * LDW + o0];
#pragma unroll
            for (int r = 0; r < 4; ++r) {
              float h = fmaf(acc2[ot][kt][r], sCoef2[2 * (o0 + r)], sCoef2[2 * (o0 + r) + 1]);
              float val = h + bf2f(xv[r]);
              val = (val >= 0.f) ? val : 0.01f * val;
              mx[r] = fmaxf(mx[r], val);
            }
          }
#pragma unroll
          for (int r = 0; r < 4; ++r) mx[r] = max16(mx[r]);
          if (l15 == 0) {
            float4 o4;
            o4.x = mx[0]; o4.y = mx[1]; o4.z = mx[2]; o4.w = mx[3];
            *(float4*)(out_pooled + (size_t)(g0 + gsel) * DD + o0) = o4;
          }
        }
      }
    }
    __syncthreads();
  }

  if constexpr (PASS <= 1) {
    if (tid < 128) {
      float* bb = bins_out + (((blockIdx.x & 63) * 128 + tid) << 1);
      atomicAdd(bb, bnS[tid]);
      atomicAdd(bb + 1, bnQ[tid]);
    }
  }
}

extern "C" void kernel_launch(void* const* d_in, const int* in_sizes, int n_in,
                              void* d_out, int out_size, void* d_ws, size_t ws_size,
                              hipStream_t stream) {
  const float* xyz    = (const float*)d_in[0];
  const float* points = (const float*)d_in[1];
  const float* alpha  = (const float*)d_in[2];
  const float* beta   = (const float*)d_in[3];
  const float* w1     = (const float*)d_in[4];
  const float* g1     = (const float*)d_in[6];
  const float* be1    = (const float*)d_in[7];
  const float* w2     = (const float*)d_in[8];
  const float* g2     = (const float*)d_in[10];
  const float* be2    = (const float*)d_in[11];
  float* out = (float*)d_out;

  char* w = (char*)d_ws;
  int* fps_i   = (int*)(w + OFF_FPSIDX);
  int* knn_i   = (int*)(w + OFF_KNN);
  float* meanp = (float*)(w + OFF_MEAN);
  float* varb  = (float*)(w + OFF_VARB);
  float* bins1 = (float*)(w + OFF_BINS1);
  float* bins2 = (float*)(w + OFF_BINS2);
  float* rstdp = (float*)(w + OFF_RSTD);
  float* coef1 = (float*)(w + OFF_COEF1);
  float* coef2 = (float*)(w + OFF_COEF2);
  short* w1b   = (short*)(w + OFF_W1BF);
  short* w2b   = (short*)(w + OFF_W2BF);
  float* xyzT  = (float*)(w + OFF_XYZT);

  hipMemsetAsync(w + MEMSET_OFF, 0, MEMSET_LEN, stream);
  xpose_kernel<<<256, 256, 0, stream>>>(xyz, xyzT);
  cvtw_kernel<<<64, 256, 0, stream>>>(w1, w2, w1b, w2b);
  fps_kernel<<<BB, 512, 0, stream>>>(xyzT, fps_i, out);
  knn_kernel<<<(BB * SS) / 4, 256, 0, stream>>>(xyzT, fps_i, knn_i);
  meanvar_kernel<<<(BB * SS) / 4, 256, 0, stream>>>(points, knn_i, meanp, varb);
  fin_std_kernel<<<1, 64, 0, stream>>>(varb, rstdp);
  gemm_pass<0><<<GGRID, 256, 0, stream>>>(points, knn_i, fps_i, meanp, rstdp, alpha, beta,
                                          w1b, w2b, coef1, coef2, bins1, nullptr);
  fin_bn_kernel<<<1, 128, 0, stream>>>(bins1, g1, be1, coef1);
  gemm_pass<1><<<GGRID, 256, 0, stream>>>(points, knn_i, fps_i, meanp, rstdp, alpha, beta,
                                          w1b, w2b, coef1, coef2, bins2, nullptr);
  fin_bn_kernel<<<1, 128, 0, stream>>>(bins2, g2, be2, coef2);
  gemm_pass<2><<<GGRID, 256, 0, stream>>>(points, knn_i, fps_i, meanp, rstdp, alpha, beta,
                                          w1b, w2b, coef1, coef2, nullptr, out + (size_t)BB * SS * 3);
}

// Round 9
// 1054.993 us; speedup vs baseline: 2.8404x; 1.1584x over previous
//
#include <hip/hip_runtime.h>

#define DI __device__ __forceinline__

typedef __attribute__((ext_vector_type(8))) short v8s;
typedef __attribute__((ext_vector_type(4))) short v4s;
typedef __attribute__((ext_vector_type(4))) float v4f;
typedef unsigned long long u64;

constexpr int BB = 16, NN = 4096, CH = 64, SS = 1024, KK = 32, DD = 128;
constexpr int LDW = 136;                 // LDS row stride in shorts (pad: 16B-aligned rows, <=2-way banks)
constexpr int GPC = 2;                   // groups per chunk in gemm passes
constexpr int GGRID = 512;

// ---- ws layout (bytes) ----
constexpr size_t OFF_FPSIDX = 0;         // int[16384]
constexpr size_t OFF_KNN    = 65536;     // int[524288]
constexpr size_t OFF_MEAN   = 2162688;   // float[1048576]
constexpr size_t OFF_VARB   = 6356992;   // float[1024]
constexpr size_t OFF_BINS1  = 6361088;   // float[16384]  [64][128][2]
constexpr size_t OFF_BINS2  = 6426624;   // float[16384]
constexpr size_t OFF_RSTD   = 6492160;   // float[16]
constexpr size_t OFF_COEF1  = 6492224;   // float[256]
constexpr size_t OFF_COEF2  = 6493248;   // float[256]
constexpr size_t OFF_W1BF   = 6494272;   // short[16384]
constexpr size_t OFF_W2BF   = 6527040;   // short[16384]
constexpr size_t OFF_XYZT   = 6559808;   // float[196608]  [B][3][N]
constexpr size_t MEMSET_OFF = OFF_VARB;
constexpr size_t MEMSET_LEN = 4096 + 65536 + 65536;

DI short f2bf(float f) {
  unsigned u = __float_as_uint(f);
  u = (u + 0x7fffu + ((u >> 16) & 1u)) >> 16;
  return (short)u;
}
DI float bf2f(short s) { return __uint_as_float(((unsigned)(unsigned short)s) << 16); }

// ---------------- prep: xyz transpose + weight cvt (merged launch) ----------------
__global__ void prep_kernel(const float* __restrict__ xyz, float* __restrict__ xyzT,
                            const float* __restrict__ w1, const float* __restrict__ w2,
                            short* __restrict__ w1b, short* __restrict__ w2b) {
  int bid = blockIdx.x;
  if (bid < 256) {
    int i = bid * 256 + threadIdx.x;  // < B*N
    int b = i >> 12, n = i & 4095;
    const float* s = xyz + (size_t)i * 3;
    float* d = xyzT + (size_t)b * 3 * NN + n;
    d[0] = s[0]; d[NN] = s[1]; d[2 * NN] = s[2];
  } else {
    int i = (bid - 256) * 256 + threadIdx.x;  // < 16384
    w1b[i] = f2bf(w1[i]);
    w2b[i] = f2bf(w2[i]);
  }
}

// tag low 12 bits of a positive double (monotone quantization per fixed tag)
DI double tag12(double d, int tag) {
  u64 b = (u64)__double_as_longlong(d);
  b = (b & ~0xFFFull) | (u64)(unsigned)tag;
  return __longlong_as_double((long long)b);
}
// 64-bit DPP fmax within a row of 16 lanes
template <int CTRL>
DI double dpp_fmax64(double x) {
  u64 b = (u64)__double_as_longlong(x);
  int lo = __builtin_amdgcn_update_dpp(0, (int)(unsigned)b, CTRL, 0xf, 0xf, true);
  int hi = __builtin_amdgcn_update_dpp(0, (int)(unsigned)(b >> 32), CTRL, 0xf, 0xf, true);
  double o = __longlong_as_double((long long)(((u64)(unsigned)hi << 32) | (unsigned)lo));
  return fmax(x, o);
}
DI double readlane_f64(double x, int l) {
  u64 b = (u64)__double_as_longlong(x);
  unsigned lo = (unsigned)__builtin_amdgcn_readlane((int)(unsigned)b, l);
  unsigned hi = (unsigned)__builtin_amdgcn_readlane((int)(unsigned)(b >> 32), l);
  return __longlong_as_double((long long)(((u64)hi << 32) | lo));
}

// DPP row rotate (within 16-lane row) for f32 reductions -- no LDS traffic.
template <int N>
DI float dpp_ror_f(float v) {
  return __int_as_float(__builtin_amdgcn_update_dpp(0, __float_as_int(v), 0x120 + N, 0xf, 0xf, true));
}
DI float sum16(float v) {
  v += dpp_ror_f<1>(v);
  v += dpp_ror_f<2>(v);
  v += dpp_ror_f<4>(v);
  v += dpp_ror_f<8>(v);
  return v;
}
DI float max16(float v) {
  v = fmaxf(v, dpp_ror_f<1>(v));
  v = fmaxf(v, dpp_ror_f<2>(v));
  v = fmaxf(v, dpp_ror_f<4>(v));
  v = fmaxf(v, dpp_ror_f<8>(v));
  return v;
}

// ---------------- FPS v6: tagged-f64 keys, v_max_f64 reduce ----------------
// 16 blocks x 512 threads (8 waves), 8 points/lane.
// m64[k] carries its tag (4095-gi) in the low 12 mantissa bits permanently:
// quantization is monotone per fixed tag, so m64[k] == tag12(exact running min)
// and fmax-reduce on these doubles is bit-identical to the u64-key max of v5
// (positive-double order == u64 bit order). fmin/fmax do compare+select in one
// instruction -- no cmp/cselect pairs anywhere in chain or reduce.
__global__ __launch_bounds__(512, 2) void fps_kernel(const float* __restrict__ xyzT,
                                                     int* __restrict__ fps_idx,
                                                     float* __restrict__ out_xyz) {
  int b = blockIdx.x, tid = threadIdx.x;
  int wave = tid >> 6, lane = tid & 63;
  const float* bx = xyzT + (size_t)b * 3 * NN;
  const float* by = bx + NN;
  const float* bz = bx + 2 * NN;
  __shared__ float4 s_xyzw[NN];   // 64 KB coords broadcast
  __shared__ int s_fidx[SS];      // 4 KB selected indices
  __shared__ double s_pd[2][8];   // wave partial keys (dbuf by round parity)

  double px64[8], py64[8], pz64[8], pp64[8], m64[8];
  int tagbase = 4095 - tid;  // tag for point k: tagbase - k*512 == 4095 - gi
#pragma unroll
  for (int k = 0; k < 8; ++k) {
    int gi = k * 512 + tid;
    float x = bx[gi], y = by[gi], z = bz[gi];
    s_xyzw[gi] = make_float4(x, y, z, 0.f);
    px64[k] = (double)x; py64[k] = (double)y; pz64[k] = (double)z;
    pp64[k] = fma(px64[k], px64[k], fma(py64[k], py64[k], pz64[k] * pz64[k]));
    m64[k] = tag12(1e10, tagbase - k * 512);
  }
  if (tid == 0) s_fidx[0] = 0;
  __syncthreads();
  float4 c0 = s_xyzw[0];
  double cx = (double)c0.x, cy = (double)c0.y, cz = (double)c0.z;

  for (int j = 1; j < SS; ++j) {
    double cx2 = -2.0 * cx, cy2 = -2.0 * cy, cz2 = -2.0 * cz;
    double cc = fma(cx, cx, fma(cy, cy, cz * cz));
    double best;
#pragma unroll
    for (int k = 0; k < 8; ++k) {
      // d = |p-c|^2 dot-form; clamp (self-point rounds to ~±1e-15; negative
      // would flip sign bit and poison ordering), then tag low 12 bits.
      double d = fma(px64[k], cx2, fma(py64[k], cy2, fma(pz64[k], cz2, pp64[k] + cc)));
      d = fmax(d, 0.0);
      d = tag12(d, tagbase - k * 512);
      m64[k] = fmin(m64[k], d);
      best = (k == 0) ? m64[0] : fmax(best, m64[k]);
    }
    // wave max: 4 DPP stages within row-of-16, then cross-row via readlane
    best = dpp_fmax64<0xB1>(best);   // quad_perm [1,0,3,2] : xor 1
    best = dpp_fmax64<0x4E>(best);   // quad_perm [2,3,0,1] : xor 2
    best = dpp_fmax64<0x141>(best);  // ROW_HALF_MIRROR     : xor 7
    best = dpp_fmax64<0x140>(best);  // ROW_MIRROR          : xor 15
    double r0 = readlane_f64(best, 0);
    double r1 = readlane_f64(best, 16);
    double r2 = readlane_f64(best, 32);
    double r3 = readlane_f64(best, 48);
    double bw = fmax(fmax(r0, r1), fmax(r2, r3));
    if (lane == 0) s_pd[j & 1][wave] = bw;
    __syncthreads();
    // cross-wave: uniform fmax scan of 8 partials
    double bk = s_pd[j & 1][0];
#pragma unroll
    for (int w = 1; w < 8; ++w) bk = fmax(bk, s_pd[j & 1][w]);
    int fi = 4095 - (int)((u64)__double_as_longlong(bk) & 0xFFFull);
    float4 cw = s_xyzw[fi];  // uniform-address LDS broadcast
    cx = (double)cw.x; cy = (double)cw.y; cz = (double)cw.z;
    if (tid == 0) s_fidx[j] = fi;
  }
  __syncthreads();
  for (int t = tid; t < SS; t += 512) {
    int idx = s_fidx[t];
    fps_idx[b * SS + t] = idx;
    float4 p = s_xyzw[idx];
    out_xyz[((size_t)b * SS + t) * 3 + 0] = p.x;
    out_xyz[((size_t)b * SS + t) * 3 + 1] = p.y;
    out_xyz[((size_t)b * SS + t) * 3 + 2] = p.z;
  }
}

// ---------------- kNN v2: radix tau + u64-key rank scan ----------------
__global__ __launch_bounds__(256) void knn_kernel(const float* __restrict__ xyzT,
                                                  const int* __restrict__ fps_idx,
                                                  int* __restrict__ knn_idx) {
  int wave = threadIdx.x >> 6, lane = threadIdx.x & 63;
  int q = blockIdx.x * 4 + wave, b = q >> 10;
  const float* bx = xyzT + (size_t)b * 3 * NN;
  const float* by = bx + NN;
  const float* bz = bx + 2 * NN;
  int qi = fps_idx[q];
  float qx = bx[qi], qy = by[qi], qz = bz[qi];
  float d[64];
  float lmin = 1e30f;
#pragma unroll
  for (int j = 0; j < 64; ++j) {
    int n = j * 64 + lane;
    float dx = bx[n] - qx, dy = by[n] - qy, dz = bz[n] - qz;
    d[j] = fmaf(dx, dx, fmaf(dy, dy, dz * dz));
    lmin = fminf(lmin, d[j]);
  }
  unsigned lb = __float_as_uint(lmin);
  unsigned res = 0;
#pragma unroll
  for (int bit = 30; bit >= 0; --bit) {
    unsigned t = res | (1u << bit);
    int c = __popcll(__ballot(lb < t));
    res = (c < 32) ? t : res;
  }
  float tau = __uint_as_float(res) * 1.00001f + 1e-20f;  // margin covers f32 dist err

  __shared__ int ci[4][512];
  __shared__ u64 ck[4][512];
  int cnt = 0;
#pragma unroll
  for (int j = 0; j < 64; ++j) {
    bool pred = (d[j] <= tau);
    unsigned long long mask = __ballot(pred);
    if (pred) {
      int pos = cnt + __popcll(mask & ((1ull << lane) - 1ull));
      if (pos < 512) ci[wave][pos] = j * 64 + lane;
    }
    cnt += __popcll(mask);
  }
  if (cnt > 512) cnt = 512;
  double qx64 = (double)qx, qy64 = (double)qy, qz64 = (double)qz;
  for (int p = lane; p < cnt; p += 64) {
    int n = ci[wave][p];
    double dx = (double)bx[n] - qx64;
    double dy = (double)by[n] - qy64;
    double dz = (double)bz[n] - qz64;
    double d64 = fma(dx, dx, fma(dy, dy, dz * dz));
    ck[wave][p] = ((u64)__double_as_longlong(d64) & ~0xFFFull) | (u64)n;
  }
  for (int p = lane; p < cnt; p += 64) {
    u64 mykey = ck[wave][p];
    int rank = 0;
    int r = 0;
    for (; r + 4 <= cnt; r += 4) {
      u64 k0 = ck[wave][r + 0], k1 = ck[wave][r + 1];
      u64 k2 = ck[wave][r + 2], k3 = ck[wave][r + 3];
      rank += (k0 < mykey) + (k1 < mykey) + (k2 < mykey) + (k3 < mykey);
    }
    for (; r < cnt; ++r) rank += (ck[wave][r] < mykey) ? 1 : 0;
    if (rank < KK) knn_idx[(size_t)q * KK + rank] = (int)(mykey & 0xFFFull);
  }
}

// ---------------- per-group mean over K + per-batch sum of diff^2 ----------------
__global__ __launch_bounds__(256) void meanvar_kernel(const float* __restrict__ points,
                                                      const int* __restrict__ kidx,
                                                      float* __restrict__ mean_out,
                                                      float* __restrict__ var_bins) {
  int wave = threadIdx.x >> 6, lane = threadIdx.x & 63;
  int xcd = blockIdx.x & 7, slot = blockIdx.x >> 3;  // slot 0..511
  int b = xcd + ((slot >> 8) << 3);                  // batches {xcd, xcd+8}
  int g = b * SS + (slot & 255) * 4 + wave;
  const float* pb = points + (size_t)b * NN * CH;
  const int* idx = kidx + (size_t)g * KK;
  float s1 = 0.f, s2 = 0.f;
#pragma unroll
  for (int k = 0; k < KK; ++k) {
    float x = pb[(size_t)idx[k] * CH + lane];
    s1 += x;
    s2 = fmaf(x, x, s2);
  }
  float m = s1 * (1.0f / 32.0f);
  mean_out[(size_t)g * CH + lane] = m;
  float part = s2 - s1 * m;  // sum_k (x-m)^2 (exact algebra: 32*m == s1)
#pragma unroll
  for (int mm = 1; mm < 64; mm <<= 1) part += __shfl_xor(part, mm, 64);
  if (lane == 0) atomicAdd(&var_bins[b * 64 + (g & 63)], part);
}

__global__ void fin_std_kernel(const float* __restrict__ bins, float* __restrict__ rstd) {
  int t = threadIdx.x;
  if (t < BB) {
    float s = 0.f;
    for (int i = 0; i < 64; ++i) s += bins[t * 64 + i];
    float var = s / (float)(SS * KK * CH - 1);
    rstd[t] = 1.0f / (sqrtf(var) + 1e-5f);
  }
}

__global__ void fin_bn_kernel(const float* __restrict__ bins, const float* __restrict__ g,
                              const float* __restrict__ be, float* __restrict__ coef) {
  int o = threadIdx.x;  // < 128
  float s = 0.f, qq = 0.f;
  for (int bin = 0; bin < 64; ++bin) {
    s += bins[(bin * 128 + o) * 2 + 0];
    qq += bins[(bin * 128 + o) * 2 + 1];
  }
  constexpr float invM = 1.0f / (float)(BB * SS * KK);
  float mean = s * invM;
  float var = qq * invM - mean * mean;
  if (var < 0.f) var = 0.f;
  float sc = g[o] / sqrtf(var + 1e-5f);
  coef[2 * o] = sc;
  coef[2 * o + 1] = be[o] - mean * sc;
}

// ---------------- GEMM passes ----------------
// PASS 0: X->h1, BN1 stats.  PASS 1: X->h1->P->h2, BN2 stats.
// PASS 2: X->h1->P->h2, BN2 + residual + lrelu + maxpool -> out.
// XCD-partitioned; software-pipelined gather (points in regs, mean in
// double-buffered LDS tile); BN stats accumulate in registers across all 16
// chunks (sum16 is linear), one LDS/global merge per block at the end.
template <int PASS>
__global__ __launch_bounds__(256, 2) void gemm_pass(
    const float* __restrict__ points, const int* __restrict__ kidx, const int* __restrict__ fidx,
    const float* __restrict__ mean, const float* __restrict__ rstd,
    const float* __restrict__ alpha, const float* __restrict__ beta,
    const short* __restrict__ w1bf, const short* __restrict__ w2bf,
    const float* __restrict__ coef1, const float* __restrict__ coef2,
    float* __restrict__ bins_out, float* __restrict__ out_pooled) {
  __shared__ short Xs[GPC * 32 * LDW];
  __shared__ short Ps[(PASS >= 1) ? (GPC * 32 * LDW) : 8];
  __shared__ float sMean[2][GPC][64];
  __shared__ float sAlpha[64], sBeta[64];
  __shared__ float sCoef1[256], sCoef2[256];
  __shared__ float bnS[128], bnQ[128];

  int tid = threadIdx.x;
  int wave = tid >> 6, lane = tid & 63;
  int q4 = lane >> 4, l15 = lane & 15;
  int ohalf = wave & 1, gsel = wave >> 1;

  // W fragments -> registers
  v8s wf1[4][4];
  v8s wf2[4][4];
#pragma unroll
  for (int ot = 0; ot < 4; ++ot) {
    int row = ohalf * 64 + ot * 16 + l15;
#pragma unroll
    for (int cs = 0; cs < 4; ++cs) {
      wf1[ot][cs] = *(const v8s*)(w1bf + row * 128 + cs * 32 + q4 * 8);
      if constexpr (PASS >= 1) wf2[ot][cs] = *(const v8s*)(w2bf + row * 128 + cs * 32 + q4 * 8);
    }
  }
  if (tid < 64) { sAlpha[tid] = alpha[tid]; sBeta[tid] = beta[tid]; }
  if constexpr (PASS >= 1) sCoef1[tid] = coef1[tid];
  if constexpr (PASS == 2) sCoef2[tid] = coef2[tid];
  if constexpr (PASS <= 1) {
    if (tid < 128) { bnS[tid] = 0.f; bnQ[tid] = 0.f; }
  }

  int xcd = blockIdx.x & 7, slot = blockIdx.x >> 3;  // slot 0..63
  int sg = tid >> 7, sk = (tid >> 2) & 31, qr = tid & 3;
  int ch0 = (qr & 1) * 32;
  bool norm = (qr < 2);
  float rsA = rstd[xcd], rsB = rstd[xcd + 8];

  float svA[4][4] = {}, sqA[4][4] = {};  // register BN-stat accumulators (PASS<=1)

  // ---- pipeline preamble: chunk(slot) points->regs, mean->sMean[0] ----
  float4 ldv[8];
  {
    int t = slot;
    int batch = xcd + ((t >> 9) << 3);
    int g0 = batch * SS + (t & 511) * GPC;
    int ggl = g0 + sg;
    int row = norm ? kidx[(size_t)ggl * KK + sk] : fidx[ggl];
    const float* src = points + (size_t)batch * NN * CH + (size_t)row * CH + ch0;
#pragma unroll
    for (int u = 0; u < 8; ++u) ldv[u] = *(const float4*)(src + u * 4);
    if (tid < 32) {
      int sg2 = tid >> 4, off = (tid & 15) << 2;
      float4 mv = *(const float4*)(mean + (size_t)(g0 + sg2) * CH + off);
      *(float4*)&sMean[0][sg2][off] = mv;
    }
  }
  __syncthreads();

  for (int it = 0; it < 16; ++it) {
    int t = slot + it * 64;
    int batch = xcd + ((t >> 9) << 3);
    int g0 = batch * SS + (t & 511) * GPC;
    int tn = (it < 15) ? t + 64 : t;
    int batch_n = xcd + ((tn >> 9) << 3);
    int g0_n = batch_n * SS + (tn & 511) * GPC;
    int ggl_n = g0_n + sg;
    int row_n = norm ? kidx[(size_t)ggl_n * KK + sk] : fidx[ggl_n];

    // ---- stage chunk t: prefetched regs + sMean tile -> Xs ----
    {
      float rs = (t >> 9) ? rsB : rsA;
      v8s pack[4];
#pragma unroll
      for (int u = 0; u < 8; ++u) {
        float4 vv = ldv[u];
        if (norm) {
          float4 mv = *(const float4*)&sMean[it & 1][sg][ch0 + u * 4];
          float4 av = *(const float4*)&sAlpha[ch0 + u * 4];
          float4 bv = *(const float4*)&sBeta[ch0 + u * 4];
          vv.x = fmaf((vv.x - mv.x) * rs, av.x, bv.x);
          vv.y = fmaf((vv.y - mv.y) * rs, av.y, bv.y);
          vv.z = fmaf((vv.z - mv.z) * rs, av.z, bv.z);
          vv.w = fmaf((vv.w - mv.w) * rs, av.w, bv.w);
        }
        pack[u >> 1][(u & 1) * 4 + 0] = f2bf(vv.x);
        pack[u >> 1][(u & 1) * 4 + 1] = f2bf(vv.y);
        pack[u >> 1][(u & 1) * 4 + 2] = f2bf(vv.z);
        pack[u >> 1][(u & 1) * 4 + 3] = f2bf(vv.w);
      }
      short* dst = &Xs[(sg * 32 + sk) * LDW + qr * 32];
#pragma unroll
      for (int p2 = 0; p2 < 4; ++p2) *(v8s*)(dst + p2 * 8) = pack[p2];
    }
    __syncthreads();

    // ---- GEMM1: h1 = W1 * X ----
    v4f acc[4][2] = {};
#pragma unroll
    for (int cs = 0; cs < 4; ++cs) {
      v8s bfr[2];
#pragma unroll
      for (int kt = 0; kt < 2; ++kt)
        bfr[kt] = *(const v8s*)&Xs[(gsel * 32 + kt * 16 + l15) * LDW + cs * 32 + q4 * 8];
#pragma unroll
      for (int ot = 0; ot < 4; ++ot)
#pragma unroll
        for (int kt = 0; kt < 2; ++kt)
          acc[ot][kt] = __builtin_amdgcn_mfma_f32_16x16x32_bf16(wf1[ot][cs], bfr[kt], acc[ot][kt], 0, 0, 0);
    }

    // ---- issue next-chunk gather (hidden behind GEMM2/stats) ----
    float4 mpre;
    {
      const float* src = points + (size_t)batch_n * NN * CH + (size_t)row_n * CH + ch0;
#pragma unroll
      for (int u = 0; u < 8; ++u) ldv[u] = *(const float4*)(src + u * 4);
      if (tid < 32) {
        int sg2 = tid >> 4, off = (tid & 15) << 2;
        mpre = *(const float4*)(mean + (size_t)(g0_n + sg2) * CH + off);
      }
    }

    if constexpr (PASS == 0) {
      // BN1 stats of h1 -> registers (deferred reduction)
#pragma unroll
      for (int ot = 0; ot < 4; ++ot)
#pragma unroll
        for (int r = 0; r < 4; ++r) {
          float a0 = acc[ot][0][r], a1 = acc[ot][1][r];
          svA[ot][r] += a0 + a1;
          sqA[ot][r] = fmaf(a0, a0, fmaf(a1, a1, sqA[ot][r]));
        }
    } else {
      // ---- P = lrelu(bn1(h1)) -> Ps ----
#pragma unroll
      for (int ot = 0; ot < 4; ++ot) {
        int o0 = ohalf * 64 + ot * 16 + q4 * 4;
#pragma unroll
        for (int kt = 0; kt < 2; ++kt) {
          v4s pk;
#pragma unroll
          for (int r = 0; r < 4; ++r) {
            float h = fmaf(acc[ot][kt][r], sCoef1[2 * (o0 + r)], sCoef1[2 * (o0 + r) + 1]);
            h = (h >= 0.f) ? h : 0.01f * h;
            pk[r] = f2bf(h);
          }
          *(v4s*)&Ps[(gsel * 32 + kt * 16 + l15) * LDW + o0] = pk;
        }
      }
      __syncthreads();

      // ---- GEMM2: h2 = W2 * P ----
      v4f acc2[4][2] = {};
#pragma unroll
      for (int cs = 0; cs < 4; ++cs) {
        v8s pfr[2];
#pragma unroll
        for (int kt = 0; kt < 2; ++kt)
          pfr[kt] = *(const v8s*)&Ps[(gsel * 32 + kt * 16 + l15) * LDW + cs * 32 + q4 * 8];
#pragma unroll
        for (int ot = 0; ot < 4; ++ot)
#pragma unroll
          for (int kt = 0; kt < 2; ++kt)
            acc2[ot][kt] = __builtin_amdgcn_mfma_f32_16x16x32_bf16(wf2[ot][cs], pfr[kt], acc2[ot][kt], 0, 0, 0);
      }

      if constexpr (PASS == 1) {
        // BN2 stats of h2 -> registers
#pragma unroll
        for (int ot = 0; ot < 4; ++ot)
#pragma unroll
          for (int r = 0; r < 4; ++r) {
            float a0 = acc2[ot][0][r], a1 = acc2[ot][1][r];
            svA[ot][r] += a0 + a1;
            sqA[ot][r] = fmaf(a0, a0, fmaf(a1, a1, sqA[ot][r]));
          }
      } else {
        // ---- epilogue: lrelu(bn2(h2) + X) , max over k (DPP), store ----
#pragma unroll
        for (int ot = 0; ot < 4; ++ot) {
          int o0 = ohalf * 64 + ot * 16 + q4 * 4;
          float mx[4] = {-1e30f, -1e30f, -1e30f, -1e30f};
#pragma unroll
          for (int kt = 0; kt < 2; ++kt) {
            v4s xv = *(const v4s*)&Xs[(gsel * 32 + kt * 16 + l15) * LDW + o0];
#pragma unroll
            for (int r = 0; r < 4; ++r) {
              float h = fmaf(acc2[ot][kt][r], sCoef2[2 * (o0 + r)], sCoef2[2 * (o0 + r) + 1]);
              float val = h + bf2f(xv[r]);
              val = (val >= 0.f) ? val : 0.01f * val;
              mx[r] = fmaxf(mx[r], val);
            }
          }
#pragma unroll
          for (int r = 0; r < 4; ++r) mx[r] = max16(mx[r]);
          if (l15 == 0) {
            float4 o4;
            o4.x = mx[0]; o4.y = mx[1]; o4.z = mx[2]; o4.w = mx[3];
            *(float4*)(out_pooled + (size_t)(g0 + gsel) * DD + o0) = o4;
          }
        }
      }
    }
    // publish next chunk's mean tile, then end-of-iteration barrier
    if (tid < 32) *(float4*)&sMean[(it + 1) & 1][tid >> 4][(tid & 15) << 2] = mpre;
    __syncthreads();
  }

  if constexpr (PASS <= 1) {
    // one reduction per block: sum16 over lane rows -> LDS -> global bins
#pragma unroll
    for (int ot = 0; ot < 4; ++ot)
#pragma unroll
      for (int r = 0; r < 4; ++r) {
        float sv = sum16(svA[ot][r]);
        float sq = sum16(sqA[ot][r]);
        if (l15 == 0) {
          int o0 = ohalf * 64 + ot * 16 + q4 * 4;
          atomicAdd(&bnS[o0 + r], sv);
          atomicAdd(&bnQ[o0 + r], sq);
        }
      }
    __syncthreads();
    if (tid < 128) {
      float* bb = bins_out + (((blockIdx.x & 63) * 128 + tid) << 1);
      atomicAdd(bb, bnS[tid]);
      atomicAdd(bb + 1, bnQ[tid]);
    }
  }
}

extern "C" void kernel_launch(void* const* d_in, const int* in_sizes, int n_in,
                              void* d_out, int out_size, void* d_ws, size_t ws_size,
                              hipStream_t stream) {
  const float* xyz    = (const float*)d_in[0];
  const float* points = (const float*)d_in[1];
  const float* alpha  = (const float*)d_in[2];
  const float* beta   = (const float*)d_in[3];
  const float* w1     = (const float*)d_in[4];
  const float* g1     = (const float*)d_in[6];
  const float* be1    = (const float*)d_in[7];
  const float* w2     = (const float*)d_in[8];
  const float* g2     = (const float*)d_in[10];
  const float* be2    = (const float*)d_in[11];
  float* out = (float*)d_out;

  char* w = (char*)d_ws;
  int* fps_i   = (int*)(w + OFF_FPSIDX);
  int* knn_i   = (int*)(w + OFF_KNN);
  float* meanp = (float*)(w + OFF_MEAN);
  float* varb  = (float*)(w + OFF_VARB);
  float* bins1 = (float*)(w + OFF_BINS1);
  float* bins2 = (float*)(w + OFF_BINS2);
  float* rstdp = (float*)(w + OFF_RSTD);
  float* coef1 = (float*)(w + OFF_COEF1);
  float* coef2 = (float*)(w + OFF_COEF2);
  short* w1b   = (short*)(w + OFF_W1BF);
  short* w2b   = (short*)(w + OFF_W2BF);
  float* xyzT  = (float*)(w + OFF_XYZT);

  hipMemsetAsync(w + MEMSET_OFF, 0, MEMSET_LEN, stream);
  prep_kernel<<<320, 256, 0, stream>>>(xyz, xyzT, w1, w2, w1b, w2b);
  fps_kernel<<<BB, 512, 0, stream>>>(xyzT, fps_i, out);
  knn_kernel<<<(BB * SS) / 4, 256, 0, stream>>>(xyzT, fps_i, knn_i);
  meanvar_kernel<<<(BB * SS) / 4, 256, 0, stream>>>(points, knn_i, meanp, varb);
  fin_std_kernel<<<1, 64, 0, stream>>>(varb, rstdp);
  gemm_pass<0><<<GGRID, 256, 0, stream>>>(points, knn_i, fps_i, meanp, rstdp, alpha, beta,
                                          w1b, w2b, coef1, coef2, bins1, nullptr);
  fin_bn_kernel<<<1, 128, 0, stream>>>(bins1, g1, be1, coef1);
  gemm_pass<1><<<GGRID, 256, 0, stream>>>(points, knn_i, fps_i, meanp, rstdp, alpha, beta,
                                          w1b, w2b, coef1, coef2, bins2, nullptr);
  fin_bn_kernel<<<1, 128, 0, stream>>>(bins2, g2, be2, coef2);
  gemm_pass<2><<<GGRID, 256, 0, stream>>>(points, knn_i, fps_i, meanp, rstdp, alpha, beta,
                                          w1b, w2b, coef1, coef2, nullptr, out + (size_t)BB * SS * 3);
}

// Round 10
// 967.243 us; speedup vs baseline: 3.0981x; 1.0907x over previous
//
#include <hip/hip_runtime.h>

#define DI __device__ __forceinline__

typedef __attribute__((ext_vector_type(8))) short v8s;
typedef __attribute__((ext_vector_type(4))) short v4s;
typedef __attribute__((ext_vector_type(4))) float v4f;
typedef unsigned long long u64;

constexpr int BB = 16, NN = 4096, CH = 64, SS = 1024, KK = 32, DD = 128;
constexpr int LDW = 136;                 // LDS row stride in shorts (pad: 16B-aligned rows, <=2-way banks)
constexpr int GPC = 2;                   // groups per chunk in gemm passes
constexpr int GGRID = 512;

// ---- ws layout (bytes) ----
constexpr size_t OFF_FPSIDX = 0;         // int[16384]
constexpr size_t OFF_KNN    = 65536;     // int[524288]
constexpr size_t OFF_MEAN   = 2162688;   // float[1048576]
constexpr size_t OFF_VARB   = 6356992;   // float[1024]
constexpr size_t OFF_BINS1  = 6361088;   // float[16384]  [64][128][2]
constexpr size_t OFF_BINS2  = 6426624;   // float[16384]
constexpr size_t OFF_RSTD   = 6492160;   // float[16]
constexpr size_t OFF_COEF1  = 6492224;   // float[256]
constexpr size_t OFF_COEF2  = 6493248;   // float[256]
constexpr size_t OFF_W1BF   = 6494272;   // short[16384]
constexpr size_t OFF_W2BF   = 6527040;   // short[16384]
constexpr size_t OFF_XYZT   = 6559808;   // float[196608]  [B][3][N]
constexpr size_t MEMSET_OFF = OFF_VARB;
constexpr size_t MEMSET_LEN = 4096 + 65536 + 65536;

DI short f2bf(float f) {
  unsigned u = __float_as_uint(f);
  u = (u + 0x7fffu + ((u >> 16) & 1u)) >> 16;
  return (short)u;
}
DI float bf2f(short s) { return __uint_as_float(((unsigned)(unsigned short)s) << 16); }

// packed 2x f32 -> 2x bf16 (RNE); HW packed cvt if available
DI unsigned pkbf(float a, float b) {
#if __has_builtin(__builtin_amdgcn_cvt_pk_bf16_f32)
  typedef __attribute__((ext_vector_type(2))) __bf16 bf2_t;
  bf2_t r = __builtin_amdgcn_cvt_pk_bf16_f32(a, b);
  return *(unsigned*)&r;
#else
  return (unsigned)(unsigned short)f2bf(a) | ((unsigned)(unsigned short)f2bf(b) << 16);
#endif
}

// ---------------- prep: xyz transpose + weight cvt (merged launch) ----------------
__global__ void prep_kernel(const float* __restrict__ xyz, float* __restrict__ xyzT,
                            const float* __restrict__ w1, const float* __restrict__ w2,
                            short* __restrict__ w1b, short* __restrict__ w2b) {
  int bid = blockIdx.x;
  if (bid < 256) {
    int i = bid * 256 + threadIdx.x;  // < B*N
    int b = i >> 12, n = i & 4095;
    const float* s = xyz + (size_t)i * 3;
    float* d = xyzT + (size_t)b * 3 * NN + n;
    d[0] = s[0]; d[NN] = s[1]; d[2 * NN] = s[2];
  } else {
    int i = (bid - 256) * 256 + threadIdx.x;  // < 16384
    w1b[i] = f2bf(w1[i]);
    w2b[i] = f2bf(w2[i]);
  }
}

// tag low 12 bits of a double (monotone quantization per fixed tag)
DI double tag12(double d, int tag) {
  u64 b = (u64)__double_as_longlong(d);
  b = (b & ~0xFFFull) | (u64)(unsigned)tag;
  return __longlong_as_double((long long)b);
}
// 64-bit DPP fmax within a row of 16 lanes
template <int CTRL>
DI double dpp_fmax64(double x) {
  u64 b = (u64)__double_as_longlong(x);
  int lo = __builtin_amdgcn_update_dpp(0, (int)(unsigned)b, CTRL, 0xf, 0xf, true);
  int hi = __builtin_amdgcn_update_dpp(0, (int)(unsigned)(b >> 32), CTRL, 0xf, 0xf, true);
  double o = __longlong_as_double((long long)(((u64)(unsigned)hi << 32) | (unsigned)lo));
  return fmax(x, o);
}
DI double readlane_f64(double x, int l) {
  u64 b = (u64)__double_as_longlong(x);
  unsigned lo = (unsigned)__builtin_amdgcn_readlane((int)(unsigned)b, l);
  unsigned hi = (unsigned)__builtin_amdgcn_readlane((int)(unsigned)(b >> 32), l);
  return __longlong_as_double((long long)(((u64)hi << 32) | lo));
}

// DPP row rotate (within 16-lane row) for f32 reductions -- no LDS traffic.
template <int N>
DI float dpp_ror_f(float v) {
  return __int_as_float(__builtin_amdgcn_update_dpp(0, __float_as_int(v), 0x120 + N, 0xf, 0xf, true));
}
DI float sum16(float v) {
  v += dpp_ror_f<1>(v);
  v += dpp_ror_f<2>(v);
  v += dpp_ror_f<4>(v);
  v += dpp_ror_f<8>(v);
  return v;
}
DI float max16(float v) {
  v = fmaxf(v, dpp_ror_f<1>(v));
  v = fmaxf(v, dpp_ror_f<2>(v));
  v = fmaxf(v, dpp_ror_f<4>(v));
  v = fmaxf(v, dpp_ror_f<8>(v));
  return v;
}

// ---------------- FPS v7: 256 threads (4 waves, 1/SIMD), 16 pts/lane ----------------
// Tagged-f64 keys as v6 (fmax-reduce bit-identical to u64-key argmax with
// min-index tie-break). Rationale for 256thr: FPS rounds are lockstep, so waves
// can't cover each other's stalls -- fewer waves = less reduce issue, smaller
// partial scan (4), cheaper barrier; chain issue per SIMD is invariant.
// Clamp dropped: with true f64 fmax ordering the self-point's ~±1e-15 dot-form
// noise is numerically ordered correctly and never wins the argmax.
__global__ __launch_bounds__(256, 1) void fps_kernel(const float* __restrict__ xyzT,
                                                     int* __restrict__ fps_idx,
                                                     float* __restrict__ out_xyz) {
  int b = blockIdx.x, tid = threadIdx.x;
  int wave = tid >> 6, lane = tid & 63;
  const float* bx = xyzT + (size_t)b * 3 * NN;
  const float* by = bx + NN;
  const float* bz = bx + 2 * NN;
  __shared__ float4 s_xyzw[NN];   // 64 KB coords broadcast
  __shared__ int s_fidx[SS];      // 4 KB selected indices
  __shared__ double s_pd[2][4];   // wave partial keys (dbuf by round parity)

  double px64[16], py64[16], pz64[16], pp64[16], m64[16];
  int tagbase = 4095 - tid;  // tag for point k: tagbase - k*256 == 4095 - gi
#pragma unroll
  for (int k = 0; k < 16; ++k) {
    int gi = k * 256 + tid;
    float x = bx[gi], y = by[gi], z = bz[gi];
    s_xyzw[gi] = make_float4(x, y, z, 0.f);
    px64[k] = (double)x; py64[k] = (double)y; pz64[k] = (double)z;
    pp64[k] = fma(px64[k], px64[k], fma(py64[k], py64[k], pz64[k] * pz64[k]));
    m64[k] = tag12(1e10, tagbase - k * 256);
  }
  if (tid == 0) s_fidx[0] = 0;
  __syncthreads();
  float4 c0 = s_xyzw[0];
  double cx = (double)c0.x, cy = (double)c0.y, cz = (double)c0.z;

  for (int j = 1; j < SS; ++j) {
    double cx2 = -2.0 * cx, cy2 = -2.0 * cy, cz2 = -2.0 * cz;
    double cc = fma(cx, cx, fma(cy, cy, cz * cz));
    double best;
#pragma unroll
    for (int k = 0; k < 16; ++k) {
      double d = fma(px64[k], cx2, fma(py64[k], cy2, fma(pz64[k], cz2, pp64[k] + cc)));
      d = tag12(d, tagbase - k * 256);
      m64[k] = fmin(m64[k], d);
      best = (k == 0) ? m64[0] : fmax(best, m64[k]);
    }
    // wave max: 4 DPP stages within row-of-16, then cross-row via readlane
    best = dpp_fmax64<0xB1>(best);   // quad_perm [1,0,3,2] : xor 1
    best = dpp_fmax64<0x4E>(best);   // quad_perm [2,3,0,1] : xor 2
    best = dpp_fmax64<0x141>(best);  // ROW_HALF_MIRROR     : xor 7
    best = dpp_fmax64<0x140>(best);  // ROW_MIRROR          : xor 15
    double r0 = readlane_f64(best, 0);
    double r1 = readlane_f64(best, 16);
    double r2 = readlane_f64(best, 32);
    double r3 = readlane_f64(best, 48);
    double bw = fmax(fmax(r0, r1), fmax(r2, r3));
    if (lane == 0) s_pd[j & 1][wave] = bw;
    __syncthreads();
    // cross-wave: uniform fmax scan of 4 partials
    double bk = fmax(fmax(s_pd[j & 1][0], s_pd[j & 1][1]),
                     fmax(s_pd[j & 1][2], s_pd[j & 1][3]));
    int fi = 4095 - (int)((u64)__double_as_longlong(bk) & 0xFFFull);
    float4 cw = s_xyzw[fi];  // uniform-address LDS broadcast
    cx = (double)cw.x; cy = (double)cw.y; cz = (double)cw.z;
    if (tid == 0) s_fidx[j] = fi;
  }
  __syncthreads();
  for (int t = tid; t < SS; t += 256) {
    int idx = s_fidx[t];
    fps_idx[b * SS + t] = idx;
    float4 p = s_xyzw[idx];
    out_xyz[((size_t)b * SS + t) * 3 + 0] = p.x;
    out_xyz[((size_t)b * SS + t) * 3 + 1] = p.y;
    out_xyz[((size_t)b * SS + t) * 3 + 2] = p.z;
  }
}

// ---------------- kNN v3: radix tau + u64-key rank scan + fused mean/var ----------------
// One wave per query. After ranking, the 32 selected indices are parked in
// ci[wave][rank] (rank order == knn_idx order), then mean over K and the
// per-batch diff^2 partial are computed right here (same summation order as
// the old meanvar kernel -> bit-identical mean_out).
__global__ __launch_bounds__(256) void knn_kernel(const float* __restrict__ xyzT,
                                                  const int* __restrict__ fps_idx,
                                                  int* __restrict__ knn_idx,
                                                  const float* __restrict__ points,
                                                  float* __restrict__ mean_out,
                                                  float* __restrict__ var_bins) {
  int wave = threadIdx.x >> 6, lane = threadIdx.x & 63;
  int q = blockIdx.x * 4 + wave, b = q >> 10;
  const float* bx = xyzT + (size_t)b * 3 * NN;
  const float* by = bx + NN;
  const float* bz = bx + 2 * NN;
  int qi = fps_idx[q];
  float qx = bx[qi], qy = by[qi], qz = bz[qi];
  float d[64];
  float lmin = 1e30f;
#pragma unroll
  for (int j = 0; j < 64; ++j) {
    int n = j * 64 + lane;
    float dx = bx[n] - qx, dy = by[n] - qy, dz = bz[n] - qz;
    d[j] = fmaf(dx, dx, fmaf(dy, dy, dz * dz));
    lmin = fminf(lmin, d[j]);
  }
  unsigned lb = __float_as_uint(lmin);
  unsigned res = 0;
#pragma unroll
  for (int bit = 30; bit >= 0; --bit) {
    unsigned t = res | (1u << bit);
    int c = __popcll(__ballot(lb < t));
    res = (c < 32) ? t : res;
  }
  float tau = __uint_as_float(res) * 1.00001f + 1e-20f;  // margin covers f32 dist err

  __shared__ int ci[4][512];
  __shared__ u64 ck[4][512];
  int cnt = 0;
#pragma unroll
  for (int j = 0; j < 64; ++j) {
    bool pred = (d[j] <= tau);
    unsigned long long mask = __ballot(pred);
    if (pred) {
      int pos = cnt + __popcll(mask & ((1ull << lane) - 1ull));
      if (pos < 512) ci[wave][pos] = j * 64 + lane;
    }
    cnt += __popcll(mask);
  }
  if (cnt > 512) cnt = 512;
  double qx64 = (double)qx, qy64 = (double)qy, qz64 = (double)qz;
  for (int p = lane; p < cnt; p += 64) {
    int n = ci[wave][p];
    double dx = (double)bx[n] - qx64;
    double dy = (double)by[n] - qy64;
    double dz = (double)bz[n] - qz64;
    double d64 = fma(dx, dx, fma(dy, dy, dz * dz));
    ck[wave][p] = ((u64)__double_as_longlong(d64) & ~0xFFFull) | (u64)n;
  }
  for (int p = lane; p < cnt; p += 64) {
    u64 mykey = ck[wave][p];
    int rank = 0;
    int r = 0;
    for (; r + 4 <= cnt; r += 4) {
      u64 k0 = ck[wave][r + 0], k1 = ck[wave][r + 1];
      u64 k2 = ck[wave][r + 2], k3 = ck[wave][r + 3];
      rank += (k0 < mykey) + (k1 < mykey) + (k2 < mykey) + (k3 < mykey);
    }
    for (; r < cnt; ++r) rank += (ck[wave][r] < mykey) ? 1 : 0;
    if (rank < KK) {
      int n = (int)(mykey & 0xFFFull);
      knn_idx[(size_t)q * KK + rank] = n;
      ci[wave][rank] = n;  // park for fused mean/var (ci no longer read above)
    }
  }
  // ---- fused mean over K + per-batch sum of diff^2 (lane = channel) ----
  const float* pb = points + (size_t)b * NN * CH;
  float s1 = 0.f, s2 = 0.f;
#pragma unroll
  for (int k = 0; k < KK; ++k) {
    float x = pb[(size_t)ci[wave][k] * CH + lane];
    s1 += x;
    s2 = fmaf(x, x, s2);
  }
  float m = s1 * (1.0f / 32.0f);
  mean_out[(size_t)q * CH + lane] = m;
  float part = s2 - s1 * m;
#pragma unroll
  for (int mm = 1; mm < 64; mm <<= 1) part += __shfl_xor(part, mm, 64);
  if (lane == 0) atomicAdd(&var_bins[b * 64 + (q & 63)], part);
}

__global__ void fin_std_kernel(const float* __restrict__ bins, float* __restrict__ rstd) {
  int t = threadIdx.x;
  if (t < BB) {
    float s = 0.f;
    for (int i = 0; i < 64; ++i) s += bins[t * 64 + i];
    float var = s / (float)(SS * KK * CH - 1);
    rstd[t] = 1.0f / (sqrtf(var) + 1e-5f);
  }
}

__global__ void fin_bn_kernel(const float* __restrict__ bins, const float* __restrict__ g,
                              const float* __restrict__ be, float* __restrict__ coef) {
  int o = threadIdx.x;  // < 128
  float s = 0.f, qq = 0.f;
  for (int bin = 0; bin < 64; ++bin) {
    s += bins[(bin * 128 + o) * 2 + 0];
    qq += bins[(bin * 128 + o) * 2 + 1];
  }
  constexpr float invM = 1.0f / (float)(BB * SS * KK);
  float mean = s * invM;
  float var = qq * invM - mean * mean;
  if (var < 0.f) var = 0.f;
  float sc = g[o] / sqrtf(var + 1e-5f);
  coef[2 * o] = sc;
  coef[2 * o + 1] = be[o] - mean * sc;
}

// ---------------- GEMM passes ----------------
// PASS 0: X->h1, BN1 stats.  PASS 1: X->h1->P->h2, BN2 stats.
// PASS 2: X->h1->P->h2, BN2 + residual + lrelu + maxpool -> out.
// XCD-partitioned; software-pipelined gather; packed bf16 cvt; BN stats in
// registers across all chunks, one merge per block.
template <int PASS>
__global__ __launch_bounds__(256, 2) void gemm_pass(
    const float* __restrict__ points, const int* __restrict__ kidx, const int* __restrict__ fidx,
    const float* __restrict__ mean, const float* __restrict__ rstd,
    const float* __restrict__ alpha, const float* __restrict__ beta,
    const short* __restrict__ w1bf, const short* __restrict__ w2bf,
    const float* __restrict__ coef1, const float* __restrict__ coef2,
    float* __restrict__ bins_out, float* __restrict__ out_pooled) {
  __shared__ short Xs[GPC * 32 * LDW];
  __shared__ short Ps[(PASS >= 1) ? (GPC * 32 * LDW) : 8];
  __shared__ float sMean[2][GPC][64];
  __shared__ float sAlpha[64], sBeta[64];
  __shared__ float sCoef1[256], sCoef2[256];
  __shared__ float bnS[128], bnQ[128];

  int tid = threadIdx.x;
  int wave = tid >> 6, lane = tid & 63;
  int q4 = lane >> 4, l15 = lane & 15;
  int ohalf = wave & 1, gsel = wave >> 1;

  // W fragments -> registers
  v8s wf1[4][4];
  v8s wf2[4][4];
#pragma unroll
  for (int ot = 0; ot < 4; ++ot) {
    int row = ohalf * 64 + ot * 16 + l15;
#pragma unroll
    for (int cs = 0; cs < 4; ++cs) {
      wf1[ot][cs] = *(const v8s*)(w1bf + row * 128 + cs * 32 + q4 * 8);
      if constexpr (PASS >= 1) wf2[ot][cs] = *(const v8s*)(w2bf + row * 128 + cs * 32 + q4 * 8);
    }
  }
  if (tid < 64) { sAlpha[tid] = alpha[tid]; sBeta[tid] = beta[tid]; }
  if constexpr (PASS >= 1) sCoef1[tid] = coef1[tid];
  if constexpr (PASS == 2) sCoef2[tid] = coef2[tid];
  if constexpr (PASS <= 1) {
    if (tid < 128) { bnS[tid] = 0.f; bnQ[tid] = 0.f; }
  }

  int xcd = blockIdx.x & 7, slot = blockIdx.x >> 3;  // slot 0..63
  int sg = tid >> 7, sk = (tid >> 2) & 31, qr = tid & 3;
  int ch0 = (qr & 1) * 32;
  bool norm = (qr < 2);
  float rsA = rstd[xcd], rsB = rstd[xcd + 8];

  float svA[4][4] = {}, sqA[4][4] = {};  // register BN-stat accumulators (PASS<=1)

  // ---- pipeline preamble: chunk(slot) points->regs, mean->sMean[0] ----
  float4 ldv[8];
  {
    int t = slot;
    int batch = xcd + ((t >> 9) << 3);
    int g0 = batch * SS + (t & 511) * GPC;
    int ggl = g0 + sg;
    int row = norm ? kidx[(size_t)ggl * KK + sk] : fidx[ggl];
    const float* src = points + (size_t)batch * NN * CH + (size_t)row * CH + ch0;
#pragma unroll
    for (int u = 0; u < 8; ++u) ldv[u] = *(const float4*)(src + u * 4);
    if (tid < 32) {
      int sg2 = tid >> 4, off = (tid & 15) << 2;
      float4 mv = *(const float4*)(mean + (size_t)(g0 + sg2) * CH + off);
      *(float4*)&sMean[0][sg2][off] = mv;
    }
  }
  __syncthreads();

  for (int it = 0; it < 16; ++it) {
    int t = slot + it * 64;
    int batch = xcd + ((t >> 9) << 3);
    int g0 = batch * SS + (t & 511) * GPC;
    int tn = (it < 15) ? t + 64 : t;
    int batch_n = xcd + ((tn >> 9) << 3);
    int g0_n = batch_n * SS + (tn & 511) * GPC;
    int ggl_n = g0_n + sg;
    int row_n = norm ? kidx[(size_t)ggl_n * KK + sk] : fidx[ggl_n];

    // ---- stage chunk t: prefetched regs + sMean tile -> Xs ----
    {
      float rs = (t >> 9) ? rsB : rsA;
      unsigned pks[16];
#pragma unroll
      for (int u = 0; u < 8; ++u) {
        float4 vv = ldv[u];
        if (norm) {
          float4 mv = *(const float4*)&sMean[it & 1][sg][ch0 + u * 4];
          float4 av = *(const float4*)&sAlpha[ch0 + u * 4];
          float4 bv = *(const float4*)&sBeta[ch0 + u * 4];
          vv.x = fmaf((vv.x - mv.x) * rs, av.x, bv.x);
          vv.y = fmaf((vv.y - mv.y) * rs, av.y, bv.y);
          vv.z = fmaf((vv.z - mv.z) * rs, av.z, bv.z);
          vv.w = fmaf((vv.w - mv.w) * rs, av.w, bv.w);
        }
        pks[2 * u + 0] = pkbf(vv.x, vv.y);
        pks[2 * u + 1] = pkbf(vv.z, vv.w);
      }
      short* dst = &Xs[(sg * 32 + sk) * LDW + qr * 32];
#pragma unroll
      for (int p2 = 0; p2 < 4; ++p2) *(uint4*)(dst + p2 * 8) = ((uint4*)pks)[p2];
    }
    __syncthreads();

    // ---- GEMM1: h1 = W1 * X ----
    v4f acc[4][2] = {};
#pragma unroll
    for (int cs = 0; cs < 4; ++cs) {
      v8s bfr[2];
#pragma unroll
      for (int kt = 0; kt < 2; ++kt)
        bfr[kt] = *(const v8s*)&Xs[(gsel * 32 + kt * 16 + l15) * LDW + cs * 32 + q4 * 8];
#pragma unroll
      for (int ot = 0; ot < 4; ++ot)
#pragma unroll
        for (int kt = 0; kt < 2; ++kt)
          acc[ot][kt] = __builtin_amdgcn_mfma_f32_16x16x32_bf16(wf1[ot][cs], bfr[kt], acc[ot][kt], 0, 0, 0);
    }

    // ---- issue next-chunk gather (hidden behind GEMM2/stats) ----
    float4 mpre;
    {
      const float* src = points + (size_t)batch_n * NN * CH + (size_t)row_n * CH + ch0;
#pragma unroll
      for (int u = 0; u < 8; ++u) ldv[u] = *(const float4*)(src + u * 4);
      if (tid < 32) {
        int sg2 = tid >> 4, off = (tid & 15) << 2;
        mpre = *(const float4*)(mean + (size_t)(g0_n + sg2) * CH + off);
      }
    }

    if constexpr (PASS == 0) {
#pragma unroll
      for (int ot = 0; ot < 4; ++ot)
#pragma unroll
        for (int r = 0; r < 4; ++r) {
          float a0 = acc[ot][0][r], a1 = acc[ot][1][r];
          svA[ot][r] += a0 + a1;
          sqA[ot][r] = fmaf(a0, a0, fmaf(a1, a1, sqA[ot][r]));
        }
    } else {
      // ---- P = lrelu(bn1(h1)) -> Ps ----
#pragma unroll
      for (int ot = 0; ot < 4; ++ot) {
        int o0 = ohalf * 64 + ot * 16 + q4 * 4;
#pragma unroll
        for (int kt = 0; kt < 2; ++kt) {
          float hv[4];
#pragma unroll
          for (int r = 0; r < 4; ++r) {
            float h = fmaf(acc[ot][kt][r], sCoef1[2 * (o0 + r)], sCoef1[2 * (o0 + r) + 1]);
            hv[r] = (h >= 0.f) ? h : 0.01f * h;
          }
          *(uint2*)&Ps[(gsel * 32 + kt * 16 + l15) * LDW + o0] =
              make_uint2(pkbf(hv[0], hv[1]), pkbf(hv[2], hv[3]));
        }
      }
      __syncthreads();

      // ---- GEMM2: h2 = W2 * P ----
      v4f acc2[4][2] = {};
#pragma unroll
      for (int cs = 0; cs < 4; ++cs) {
        v8s pfr[2];
#pragma unroll
        for (int kt = 0; kt < 2; ++kt)
          pfr[kt] = *(const v8s*)&Ps[(gsel * 32 + kt * 16 + l15) * LDW + cs * 32 + q4 * 8];
#pragma unroll
        for (int ot = 0; ot < 4; ++ot)
#pragma unroll
          for (int kt = 0; kt < 2; ++kt)
            acc2[ot][kt] = __builtin_amdgcn_mfma_f32_16x16x32_bf16(wf2[ot][cs], pfr[kt], acc2[ot][kt], 0, 0, 0);
      }

      if constexpr (PASS == 1) {
#pragma unroll
        for (int ot = 0; ot < 4; ++ot)
#pragma unroll
          for (int r = 0; r < 4; ++r) {
            float a0 = acc2[ot][0][r], a1 = acc2[ot][1][r];
            svA[ot][r] += a0 + a1;
            sqA[ot][r] = fmaf(a0, a0, fmaf(a1, a1, sqA[ot][r]));
          }
      } else {
        // ---- epilogue: lrelu(bn2(h2) + X) , max over k (DPP), store ----
#pragma unroll
        for (int ot = 0; ot < 4; ++ot) {
          int o0 = ohalf * 64 + ot * 16 + q4 * 4;
          float mx[4] = {-1e30f, -1e30f, -1e30f, -1e30f};
#pragma unroll
          for (int kt = 0; kt < 2; ++kt) {
            v4s xv = *(const v4s*)&Xs[(gsel * 32 + kt * 16 + l15) * LDW + o0];
#pragma unroll
            for (int r = 0; r < 4; ++r) {
              float h = fmaf(acc2[ot][kt][r], sCoef2[2 * (o0 + r)], sCoef2[2 * (o0 + r) + 1]);
              float val = h + bf2f(xv[r]);
              val = (val >= 0.f) ? val : 0.01f * val;
              mx[r] = fmaxf(mx[r], val);
            }
          }
#pragma unroll
          for (int r = 0; r < 4; ++r) mx[r] = max16(mx[r]);
          if (l15 == 0) {
            float4 o4;
            o4.x = mx[0]; o4.y = mx[1]; o4.z = mx[2]; o4.w = mx[3];
            *(float4*)(out_pooled + (size_t)(g0 + gsel) * DD + o0) = o4;
          }
        }
      }
    }
    if (tid < 32) *(float4*)&sMean[(it + 1) & 1][tid >> 4][(tid & 15) << 2] = mpre;
    __syncthreads();
  }

  if constexpr (PASS <= 1) {
#pragma unroll
    for (int ot = 0; ot < 4; ++ot)
#pragma unroll
      for (int r = 0; r < 4; ++r) {
        float sv = sum16(svA[ot][r]);
        float sq = sum16(sqA[ot][r]);
        if (l15 == 0) {
          int o0 = ohalf * 64 + ot * 16 + q4 * 4;
          atomicAdd(&bnS[o0 + r], sv);
          atomicAdd(&bnQ[o0 + r], sq);
        }
      }
    __syncthreads();
    if (tid < 128) {
      float* bb = bins_out + (((blockIdx.x & 63) * 128 + tid) << 1);
      atomicAdd(bb, bnS[tid]);
      atomicAdd(bb + 1, bnQ[tid]);
    }
  }
}

extern "C" void kernel_launch(void* const* d_in, const int* in_sizes, int n_in,
                              void* d_out, int out_size, void* d_ws, size_t ws_size,
                              hipStream_t stream) {
  const float* xyz    = (const float*)d_in[0];
  const float* points = (const float*)d_in[1];
  const float* alpha  = (const float*)d_in[2];
  const float* beta   = (const float*)d_in[3];
  const float* w1     = (const float*)d_in[4];
  const float* g1     = (const float*)d_in[6];
  const float* be1    = (const float*)d_in[7];
  const float* w2     = (const float*)d_in[8];
  const float* g2     = (const float*)d_in[10];
  const float* be2    = (const float*)d_in[11];
  float* out = (float*)d_out;

  char* w = (char*)d_ws;
  int* fps_i   = (int*)(w + OFF_FPSIDX);
  int* knn_i   = (int*)(w + OFF_KNN);
  float* meanp = (float*)(w + OFF_MEAN);
  float* varb  = (float*)(w + OFF_VARB);
  float* bins1 = (float*)(w + OFF_BINS1);
  float* bins2 = (float*)(w + OFF_BINS2);
  float* rstdp = (float*)(w + OFF_RSTD);
  float* coef1 = (float*)(w + OFF_COEF1);
  float* coef2 = (float*)(w + OFF_COEF2);
  short* w1b   = (short*)(w + OFF_W1BF);
  short* w2b   = (short*)(w + OFF_W2BF);
  float* xyzT  = (float*)(w + OFF_XYZT);

  hipMemsetAsync(w + MEMSET_OFF, 0, MEMSET_LEN, stream);
  prep_kernel<<<320, 256, 0, stream>>>(xyz, xyzT, w1, w2, w1b, w2b);
  fps_kernel<<<BB, 256, 0, stream>>>(xyzT, fps_i, out);
  knn_kernel<<<(BB * SS) / 4, 256, 0, stream>>>(xyzT, fps_i, knn_i, points, meanp, varb);
  fin_std_kernel<<<1, 64, 0, stream>>>(varb, rstdp);
  gemm_pass<0><<<GGRID, 256, 0, stream>>>(points, knn_i, fps_i, meanp, rstdp, alpha, beta,
                                          w1b, w2b, coef1, coef2, bins1, nullptr);
  fin_bn_kernel<<<1, 128, 0, stream>>>(bins1, g1, be1, coef1);
  gemm_pass<1><<<GGRID, 256, 0, stream>>>(points, knn_i, fps_i, meanp, rstdp, alpha, beta,
                                          w1b, w2b, coef1, coef2, bins2, nullptr);
  fin_bn_kernel<<<1, 128, 0, stream>>>(bins2, g2, be2, coef2);
  gemm_pass<2><<<GGRID, 256, 0, stream>>>(points, knn_i, fps_i, meanp, rstdp, alpha, beta,
                                          w1b, w2b, coef1, coef2, nullptr, out + (size_t)BB * SS * 3);
}